// Round 2
// baseline (23375.185 us; speedup 1.0000x reference)
//
#include <hip/hip_runtime.h>
#include <hip/hip_bf16.h>

typedef __attribute__((ext_vector_type(8))) short short8;
typedef __attribute__((ext_vector_type(4))) float f32x4;

#define NLAYER 12
#define NTOK   6304
#define MPAD   6400
#define CONVM  6272

// plane strides (elements); lo plane lives at base + PL_*
#define PL_PATCH ((size_t)CONVM*1024)
#define PL_WP    ((size_t)768*1024)
#define PL_QKV   ((size_t)2304*768)
#define PL_WO    ((size_t)768*768)
#define PL_W12   ((size_t)4096*768)
#define PL_W3    ((size_t)768*2048)
#define PL_ACTA  ((size_t)MPAD*768)
#define PL_ACTB  ((size_t)MPAD*2048)

static constexpr size_t AL(size_t x){ return (x + 511) & ~(size_t)511; }
static constexpr size_t B_COS    = 0;
static constexpr size_t B_SIN    = AL(B_COS    + (size_t)197*32*4);
static constexpr size_t B_WPT    = AL(B_SIN    + (size_t)197*32*4);
static constexpr size_t B_APATCH = AL(B_WPT    + PL_WP*4);
static constexpr size_t B_WQKVT  = AL(B_APATCH + PL_PATCH*4);
static constexpr size_t B_WOT    = AL(B_WQKVT  + PL_QKV*4);
static constexpr size_t B_W12T   = AL(B_WOT    + PL_WO*4);
static constexpr size_t B_W3T    = AL(B_W12T   + PL_W12*4);
static constexpr size_t B_TOK    = AL(B_W3T    + PL_W3*4);
static constexpr size_t B_ACTA   = AL(B_TOK    + (size_t)NTOK*768*4);
static constexpr size_t B_ACTB   = AL(B_ACTA   + PL_ACTA*4);
static constexpr size_t B_GOUT   = AL(B_ACTB   + PL_ACTB*4);
static constexpr size_t B_QR     = AL(B_GOUT   + (size_t)MPAD*4096*4);
static constexpr size_t B_QT     = AL(B_QR     + (size_t)384*197*64*4);
static constexpr size_t B_KT     = AL(B_QT     + (size_t)384*197*4);
static constexpr size_t B_VF     = AL(B_KT     + (size_t)384*65*208*4);
static constexpr size_t B_END    = AL(B_VF     + (size_t)384*197*65*4);

// ---------------- helpers ----------------
__device__ __forceinline__ float bsum(float v, float* red) {
  #pragma unroll
  for (int m = 32; m; m >>= 1) v += __shfl_xor(v, m, 64);
  __syncthreads();
  if ((threadIdx.x & 63) == 0) red[threadIdx.x >> 6] = v;
  __syncthreads();
  return red[0] + red[1] + red[2] + red[3];
}

__device__ __forceinline__ void wsplit(float v, __hip_bfloat16* hi, __hip_bfloat16* lo) {
  __hip_bfloat16 h = __float2bfloat16(v);
  *hi = h;
  *lo = __float2bfloat16(v - __bfloat162float(h));
}

// ---------------- RoPE tables ----------------
__global__ void k_rope_tab(float* __restrict__ cosb, float* __restrict__ sinb) {
  int idx = blockIdx.x * 256 + threadIdx.x;
  if (idx >= 197 * 32) return;
  int p = idx >> 5, j = idx & 31;
  float cv, sv;
  if (p == 0) { cv = 1.f; sv = 0.f; }
  else {
    int pp = p - 1;
    int iy = pp / 14, ix = pp - iy * 14;
    int pos = (j < 16) ? iy : ix;
    int f   = (j < 16) ? j  : j - 16;
    float inv = powf(100.f, -(float)f / 16.f);
    float a = (float)pos * inv;
    cv = cosf(a); sv = sinf(a);
  }
  cosb[idx] = cv; sinb[idx] = sv;
}

// ---------------- transpose + split-cast f32 -> bf16 hi/lo, dst[n][k], zero-pad ----------------
__global__ __launch_bounds__(256) void k_tcast2(const float* __restrict__ src, __hip_bfloat16* __restrict__ dst,
                                                int K, int N, int Kp, int Np, size_t plane) {
  size_t idx = (size_t)blockIdx.x * 256 + threadIdx.x;
  if (idx >= (size_t)Np * Kp) return;
  int n = (int)(idx / Kp), k = (int)(idx % Kp);
  float v = (k < K && n < N) ? src[(size_t)k * N + n] : 0.f;
  wsplit(v, &dst[idx], &dst[plane + idx]);
}

// ---------------- im2col with Lorentz time channel, split ----------------
__global__ __launch_bounds__(256) void k_im2col(const float* __restrict__ x, __hip_bfloat16* __restrict__ ap) {
  int r = blockIdx.x;                 // 0..6271
  int b = r / 196, pi = r - b * 196;
  int py = pi / 14, px = pi - py * 14;
  int t = threadIdx.x;
  int ph = t >> 4, pw = t & 15;
  int iy = py * 16 + ph, ix = px * 16 + pw;
  size_t base = ((size_t)b * 3 * 224 + iy) * 224 + ix;
  float x0 = x[base];
  float x1 = x[base + 224 * 224];
  float x2 = x[base + 2 * 224 * 224];
  float tv = sqrtf(fmaxf(x0 * x0 + x1 * x1 + x2 * x2 + 1.f, 1e-6f));
  size_t o = (size_t)r * 1024 + t * 4;
  wsplit(tv, &ap[o],     &ap[PL_PATCH + o]);
  wsplit(x0, &ap[o + 1], &ap[PL_PATCH + o + 1]);
  wsplit(x1, &ap[o + 2], &ap[PL_PATCH + o + 2]);
  wsplit(x2, &ap[o + 3], &ap[PL_PATCH + o + 3]);
}

// ---------------- GEMM: C[M][N] = (Ahi+Alo)[M][K] * (Bhi+Blo)[N][K]^T, 3-product split ----------------
__global__ __launch_bounds__(256) void k_gemm3(const ushort* __restrict__ A, const ushort* __restrict__ Bt,
                                               float* __restrict__ C, int N, int K,
                                               size_t aPl, size_t bPl) {
  __shared__ ushort sAh[128 * 32];
  __shared__ ushort sAl[128 * 32];
  __shared__ ushort sBh[128 * 32];
  __shared__ ushort sBl[128 * 32];
  int m0 = blockIdx.x * 128, n0 = blockIdx.y * 128;
  int t = threadIdx.x;
  int w = t >> 6, l = t & 63;
  int wm = (w >> 1) * 64, wn = (w & 1) * 64;
  int lr = l & 15, lk = (l >> 4) * 8;
  f32x4 acc[4][4] = {};
  for (int k0 = 0; k0 < K; k0 += 32) {
    #pragma unroll
    for (int i = 0; i < 2; ++i) {
      int fl = i * 256 + t;           // 16B chunk id, 512 per plane
      int r = fl >> 2, kk = (fl & 3) * 8;
      size_t ao = (size_t)(m0 + r) * K + k0 + kk;
      size_t bo = (size_t)(n0 + r) * K + k0 + kk;
      *(int4*)(&sAh[fl * 8]) = *(const int4*)(&A[ao]);
      *(int4*)(&sAl[fl * 8]) = *(const int4*)(&A[aPl + ao]);
      *(int4*)(&sBh[fl * 8]) = *(const int4*)(&Bt[bo]);
      *(int4*)(&sBl[fl * 8]) = *(const int4*)(&Bt[bPl + bo]);
    }
    __syncthreads();
    short8 ah[4], al[4], bh[4], bl[4];
    #pragma unroll
    for (int q = 0; q < 4; ++q) {
      int ra = (wm + q * 16 + lr) * 32 + lk;
      int rb = (wn + q * 16 + lr) * 32 + lk;
      ah[q] = *(const short8*)(&sAh[ra]);
      al[q] = *(const short8*)(&sAl[ra]);
      bh[q] = *(const short8*)(&sBh[rb]);
      bl[q] = *(const short8*)(&sBl[rb]);
    }
    #pragma unroll
    for (int mi = 0; mi < 4; ++mi)
      #pragma unroll
      for (int ni = 0; ni < 4; ++ni) {
        acc[mi][ni] = __builtin_amdgcn_mfma_f32_16x16x32_bf16(ah[mi], bh[ni], acc[mi][ni], 0, 0, 0);
        acc[mi][ni] = __builtin_amdgcn_mfma_f32_16x16x32_bf16(ah[mi], bl[ni], acc[mi][ni], 0, 0, 0);
        acc[mi][ni] = __builtin_amdgcn_mfma_f32_16x16x32_bf16(al[mi], bh[ni], acc[mi][ni], 0, 0, 0);
      }
    __syncthreads();
  }
  int rr = (l >> 4) * 4, cc = l & 15;
  #pragma unroll
  for (int mi = 0; mi < 4; ++mi)
    #pragma unroll
    for (int ni = 0; ni < 4; ++ni)
      #pragma unroll
      for (int j = 0; j < 4; ++j)
        C[(size_t)(m0 + wm + mi * 16 + rr + j) * N + (n0 + wn + ni * 16 + cc)] = acc[mi][ni][j];
}

// ---------------- build tokens (to_lorentz of conv feat + cls) ----------------
__global__ __launch_bounds__(256) void k_build_tok(const float* __restrict__ feat, const float* __restrict__ cls,
                                                   float* __restrict__ tok) {
  __shared__ float red[8];
  int r = blockIdx.x;                 // 0..6303
  int b = r / 197, i = r - b * 197;
  int t = threadIdx.x;
  const float* src = (i == 0) ? cls : (feat + (size_t)(b * 196 + i - 1) * 768);
  float v0 = src[t], v1 = src[256 + t], v2 = (t < 255) ? src[512 + t] : 0.f;
  float qs = bsum(v0 * v0 + v1 * v1 + v2 * v2, red);
  float* tp = tok + (size_t)r * 768;
  if (t == 0) tp[0] = sqrtf(fmaxf(qs + 1.f, 1e-6f));
  tp[1 + t] = v0; tp[257 + t] = v1; if (t < 255) tp[513 + t] = v2;
}

// ---------------- lorentz layernorm -> split bf16 spatial (pad col 767 = 0) ----------------
__global__ __launch_bounds__(256) void k_ln(const float* __restrict__ tok, const float* __restrict__ g,
                                            const float* __restrict__ bb, __hip_bfloat16* __restrict__ out) {
  __shared__ float red[8];
  int r = blockIdx.x, t = threadIdx.x;
  const float* xp = tok + (size_t)r * 768;
  float v0 = xp[1 + t], v1 = xp[257 + t], v2 = (t < 255) ? xp[513 + t] : 0.f;
  float s = bsum(v0 + v1 + v2, red);
  float q = bsum(v0 * v0 + v1 * v1 + v2 * v2, red);
  float mu = s * (1.f / 767.f);
  float rstd = rsqrtf(fmaxf(q * (1.f / 767.f) - mu * mu, 0.f) + 1e-6f);
  size_t o = (size_t)r * 768;
  wsplit((v0 - mu) * rstd * g[t]       + bb[t],       &out[o + t],       &out[PL_ACTA + o + t]);
  wsplit((v1 - mu) * rstd * g[256 + t] + bb[256 + t], &out[o + 256 + t], &out[PL_ACTA + o + 256 + t]);
  if (t < 255)
    wsplit((v2 - mu) * rstd * g[512 + t] + bb[512 + t], &out[o + 512 + t], &out[PL_ACTA + o + 512 + t]);
  if (t == 255) {
    out[o + 767] = __float2bfloat16(0.f);
    out[PL_ACTA + o + 767] = __float2bfloat16(0.f);
  }
}

// ---------------- QKV post: RoPE, times, layout for attention ----------------
__global__ __launch_bounds__(384) void k_qkvpost(const float* __restrict__ qkv, const float* __restrict__ cosb,
                                                 const float* __restrict__ sinb, float* __restrict__ qr,
                                                 float* __restrict__ qtb, float* __restrict__ kT,
                                                 float* __restrict__ vf) {
  int r = blockIdx.x;                 // 0..6303
  int b = r / 197, n = r - b * 197;
  int t = threadIdx.x;
  int h = t >> 5, j = t & 31;
  const float* row = qkv + (size_t)r * 2304;
  float q0 = row[h * 64 + 2 * j],        q1 = row[h * 64 + 2 * j + 1];
  float k0 = row[768 + h * 64 + 2 * j],  k1 = row[768 + h * 64 + 2 * j + 1];
  float v0 = row[1536 + h * 64 + 2 * j], v1 = row[1536 + h * 64 + 2 * j + 1];
  float c = cosb[n * 32 + j], sn = sinb[n * 32 + j];
  float qa = q0 * c - q1 * sn, qb = q0 * sn + q1 * c;
  float ka = k0 * c - k1 * sn, kb = k0 * sn + k1 * c;
  float sq = q0 * q0 + q1 * q1, sk = k0 * k0 + k1 * k1, sv = v0 * v0 + v1 * v1;
  #pragma unroll
  for (int m = 16; m; m >>= 1) {
    sq += __shfl_xor(sq, m, 64);
    sk += __shfl_xor(sk, m, 64);
    sv += __shfl_xor(sv, m, 64);
  }
  int bh = b * 12 + h;
  size_t qi = ((size_t)bh * 197 + n) * 64 + 2 * j;
  qr[qi] = qa; qr[qi + 1] = qb;
  size_t kbase = (size_t)bh * 65 * 208;
  kT[kbase + (size_t)(2 * j) * 208 + n]     = ka;
  kT[kbase + (size_t)(2 * j + 1) * 208 + n] = kb;
  size_t vi = ((size_t)bh * 197 + n) * 65;
  vf[vi + 1 + 2 * j] = v0; vf[vi + 2 + 2 * j] = v1;
  if (j == 0) {
    qtb[(size_t)bh * 197 + n]  = sqrtf(fmaxf(sq + 1.f, 1e-6f));
    kT[kbase + 64 * 208 + n]   = sqrtf(fmaxf(sk + 1.f, 1e-6f));
    vf[vi]                     = sqrtf(fmaxf(sv + 1.f, 1e-6f));
  }
}

// ---------------- attention: scores+softmax(unnorm)+PV+project, split-bf16 mid-spatial ----------------
__global__ __launch_bounds__(256) void k_attn(const float* __restrict__ qr, const float* __restrict__ qtb,
                                              const float* __restrict__ kT, const float* __restrict__ vf,
                                              __hip_bfloat16* __restrict__ outa) {
  __shared__ float kv[65 * 208];
  __shared__ float q8[8 * 64];
  __shared__ float qt8[8];
  __shared__ float pl[8 * 208];
  __shared__ float part[3 * 65];
  __shared__ float mids[65];
  __shared__ float redv[66];
  int t = threadIdx.x;
  int nb = blockIdx.x, bh = blockIdx.y;
  int b = bh / 12, hd = bh - b * 12;
  int n0 = nb * 8;
  const float* kbase = kT + (size_t)bh * 65 * 208;
  for (int i = t; i < 65 * 208; i += 256) kv[i] = kbase[i];
  for (int i = t; i < 512; i += 256) {
    int rr = i >> 6, d = i & 63; int n = n0 + rr;
    q8[i] = (n < 197) ? qr[((size_t)bh * 197 + n) * 64 + d] : 0.f;
  }
  if (t < 8) { int n = n0 + t; qt8[t] = (n < 197) ? qtb[(size_t)bh * 197 + n] : 0.f; }
  __syncthreads();
  if (t < 197) {
    float acc[8] = {0, 0, 0, 0, 0, 0, 0, 0};
    for (int d = 0; d < 64; ++d) {
      float kd = kv[d * 208 + t];
      #pragma unroll
      for (int rr = 0; rr < 8; ++rr) acc[rr] += q8[rr * 64 + d] * kd;
    }
    float ktv = kv[64 * 208 + t];
    const float invs = 0.03608439182435161f;  // 1/sqrt(768)
    #pragma unroll
    for (int rr = 0; rr < 8; ++rr)
      pl[rr * 208 + t] = (2.f + 2.f * (acc[rr] - qt8[rr] * ktv)) * invs;
  }
  __syncthreads();
  {
    int wv = t >> 6, l = t & 63;
    for (int rw = 0; rw < 2; ++rw) {
      int rr = wv * 2 + rw;
      float mx = -1e30f;
      for (int m = l; m < 197; m += 64) mx = fmaxf(mx, pl[rr * 208 + m]);
      #pragma unroll
      for (int mk = 32; mk; mk >>= 1) mx = fmaxf(mx, __shfl_xor(mx, mk, 64));
      for (int m = l; m < 197; m += 64) pl[rr * 208 + m] = __expf(pl[rr * 208 + m] - mx);
    }
  }
  __syncthreads();
  int g = t / 65, e = t - g * 65;     // valid for t < 195
  for (int rr = 0; rr < 8; ++rr) {
    int n = n0 + rr;
    if (t < 195) {
      float a = 0.f;
      for (int m = g; m < 197; m += 3) a += pl[rr * 208 + m] * vf[((size_t)bh * 197 + m) * 65 + e];
      part[g * 65 + e] = a;
    }
    __syncthreads();
    if (t < 65) {
      float mv = part[t] + part[65 + t] + part[130 + t];
      mids[t] = mv;
      redv[t] = (t == 0) ? -mv * mv : mv * mv;
    }
    __syncthreads();
    if (t < 64) {
      float v = redv[t] + ((t == 0) ? redv[64] : 0.f);
      #pragma unroll
      for (int mk = 32; mk; mk >>= 1) v += __shfl_xor(v, mk, 64);
      if (t == 0) redv[65] = rsqrtf(fmaxf(-v, 1e-6f));
    }
    __syncthreads();
    if (t < 64 && n < 197) {
      float v = mids[1 + t] * redv[65];
      size_t oi = ((size_t)(b * 197 + n)) * 768 + hd * 64 + t;
      wsplit(v, &outa[oi], &outa[PL_ACTA + oi]);
    }
    __syncthreads();
  }
}

// ---------------- lresnet: tok = project(tok + w * to_lorentz(s)) ----------------
__global__ __launch_bounds__(256) void k_resnet(float* __restrict__ tok, const float* __restrict__ s,
                                                const float* __restrict__ wyp, int l) {
  __shared__ float red[8];
  __shared__ float bc[1];
  int r = blockIdx.x, t = threadIdx.x;
  float w = wyp[l];
  const float* sp = s + (size_t)r * 768;
  float* tp = tok + (size_t)r * 768;
  float s0 = sp[t], s1 = sp[256 + t], s2 = (t < 255) ? sp[512 + t] : 0.f;
  float qs = bsum(s0 * s0 + s1 * s1 + s2 * s2, red);
  float at = sqrtf(fmaxf(qs + 1.f, 1e-6f));
  float z0 = tp[1 + t] + w * s0;
  float z1 = tp[257 + t] + w * s1;
  float z2 = (t < 255) ? (tp[513 + t] + w * s2) : 0.f;
  float zs = bsum(z0 * z0 + z1 * z1 + z2 * z2, red);
  if (t == 0) bc[0] = tp[0] + w * at;
  __syncthreads();
  float zt = bc[0];
  float rf = rsqrtf(fmaxf(zt * zt - zs, 1e-6f));
  tp[1 + t] = z0 * rf; tp[257 + t] = z1 * rf; if (t < 255) tp[513 + t] = z2 * rf;
  if (t == 0) tp[0] = zt * rf;
}

// ---------------- silu(u1) * u2 -> split bf16 ----------------
__global__ __launch_bounds__(256) void k_silu(const float* __restrict__ u, __hip_bfloat16* __restrict__ outb) {
  size_t idx = (size_t)blockIdx.x * 256 + threadIdx.x;    // 6304*2048
  int r = (int)(idx >> 11), n = (int)(idx & 2047);
  float a = u[(size_t)r * 4096 + n];
  float b = u[(size_t)r * 4096 + 2048 + n];
  float hval = a / (1.f + __expf(-a)) * b;
  size_t oi = (size_t)r * 2048 + n;
  wsplit(hval, &outb[oi], &outb[PL_ACTB + oi]);
}

// ---------------- final lorentz layernorm -> f32 out with time ----------------
__global__ __launch_bounds__(256) void k_final_ln(const float* __restrict__ tok, const float* __restrict__ g,
                                                  const float* __restrict__ bb, float* __restrict__ out) {
  __shared__ float red[8];
  int r = blockIdx.x, t = threadIdx.x;
  const float* xp = tok + (size_t)r * 768;
  float v0 = xp[1 + t], v1 = xp[257 + t], v2 = (t < 255) ? xp[513 + t] : 0.f;
  float s = bsum(v0 + v1 + v2, red);
  float q = bsum(v0 * v0 + v1 * v1 + v2 * v2, red);
  float mu = s * (1.f / 767.f);
  float rstd = rsqrtf(fmaxf(q * (1.f / 767.f) - mu * mu, 0.f) + 1e-6f);
  float y0 = (v0 - mu) * rstd * g[t] + bb[t];
  float y1 = (v1 - mu) * rstd * g[256 + t] + bb[256 + t];
  float y2 = (t < 255) ? ((v2 - mu) * rstd * g[512 + t] + bb[512 + t]) : 0.f;
  float qq = bsum(y0 * y0 + y1 * y1 + y2 * y2, red);
  float* op = out + (size_t)r * 768;
  op[1 + t] = y0; op[257 + t] = y1; if (t < 255) op[513 + t] = y2;
  if (t == 0) op[0] = sqrtf(fmaxf(qq + 1.f, 1e-6f));
}

extern "C" void kernel_launch(void* const* d_in, const int* in_sizes, int n_in,
                              void* d_out, int out_size, void* d_ws, size_t ws_size,
                              hipStream_t stream) {
  const float* x     = (const float*)d_in[0];
  const float* cls_s = (const float*)d_in[1];
  const float* Wp    = (const float*)d_in[2];
  const float* ln1g  = (const float*)d_in[3];
  const float* ln1b  = (const float*)d_in[4];
  const float* Wq    = (const float*)d_in[5];
  const float* Wk    = (const float*)d_in[6];
  const float* Wv    = (const float*)d_in[7];
  const float* Wo    = (const float*)d_in[8];
  const float* ln2g  = (const float*)d_in[9];
  const float* ln2b  = (const float*)d_in[10];
  const float* W1    = (const float*)d_in[11];
  const float* W2    = (const float*)d_in[12];
  const float* W3    = (const float*)d_in[13];
  const float* wy1   = (const float*)d_in[14];
  const float* wy2   = (const float*)d_in[15];
  const float* lnfg  = (const float*)d_in[16];
  const float* lnfb  = (const float*)d_in[17];

  if (ws_size < B_END) return;  // ~350 MB needed

  char* ws = (char*)d_ws;
  float*          cosb   = (float*)(ws + B_COS);
  float*          sinb   = (float*)(ws + B_SIN);
  __hip_bfloat16* wpt    = (__hip_bfloat16*)(ws + B_WPT);
  __hip_bfloat16* apatch = (__hip_bfloat16*)(ws + B_APATCH);
  __hip_bfloat16* wqkvt  = (__hip_bfloat16*)(ws + B_WQKVT);
  __hip_bfloat16* wot    = (__hip_bfloat16*)(ws + B_WOT);
  __hip_bfloat16* w12t   = (__hip_bfloat16*)(ws + B_W12T);
  __hip_bfloat16* w3t    = (__hip_bfloat16*)(ws + B_W3T);
  float*          tok    = (float*)(ws + B_TOK);
  __hip_bfloat16* acta   = (__hip_bfloat16*)(ws + B_ACTA);
  __hip_bfloat16* actb   = (__hip_bfloat16*)(ws + B_ACTB);
  float*          gout   = (float*)(ws + B_GOUT);
  float*          qrope  = (float*)(ws + B_QR);
  float*          qtb    = (float*)(ws + B_QT);
  float*          ktb    = (float*)(ws + B_KT);
  float*          vfb    = (float*)(ws + B_VF);

  k_rope_tab<<<25, 256, 0, stream>>>(cosb, sinb);
  k_tcast2<<<3072, 256, 0, stream>>>(Wp, wpt, 1024, 767, 1024, 768, PL_WP);
  k_im2col<<<CONVM, 256, 0, stream>>>(x, apatch);
  k_gemm3<<<dim3(49, 6), 256, 0, stream>>>((const ushort*)apatch, (const ushort*)wpt, gout, 768, 1024,
                                           PL_PATCH, PL_WP);
  k_build_tok<<<NTOK, 256, 0, stream>>>(gout, cls_s, tok);

  for (int l = 0; l < NLAYER; ++l) {
    k_tcast2<<<2304, 256, 0, stream>>>(Wq + (size_t)l * 767 * 768, wqkvt,                 767, 768, 768, 768, PL_QKV);
    k_tcast2<<<2304, 256, 0, stream>>>(Wk + (size_t)l * 767 * 768, wqkvt + 768 * 768,     767, 768, 768, 768, PL_QKV);
    k_tcast2<<<2304, 256, 0, stream>>>(Wv + (size_t)l * 767 * 768, wqkvt + 2 * 768 * 768, 767, 768, 768, 768, PL_QKV);
    k_tcast2<<<2304, 256, 0, stream>>>(Wo + (size_t)l * 768 * 767, wot,                   768, 767, 768, 768, PL_WO);
    k_tcast2<<<6144, 256, 0, stream>>>(W1 + (size_t)l * 767 * 2048, w12t,                 767, 2048, 768, 2048, PL_W12);
    k_tcast2<<<6144, 256, 0, stream>>>(W2 + (size_t)l * 767 * 2048, w12t + (size_t)2048 * 768, 767, 2048, 768, 2048, PL_W12);
    k_tcast2<<<6144, 256, 0, stream>>>(W3 + (size_t)l * 2048 * 767, w3t,                  2048, 767, 2048, 768, PL_W3);

    k_ln<<<NTOK, 256, 0, stream>>>(tok, ln1g + (size_t)l * 767, ln1b + (size_t)l * 767, acta);
    k_gemm3<<<dim3(50, 18), 256, 0, stream>>>((const ushort*)acta, (const ushort*)wqkvt, gout, 2304, 768,
                                              PL_ACTA, PL_QKV);
    k_qkvpost<<<NTOK, 384, 0, stream>>>(gout, cosb, sinb, qrope, qtb, ktb, vfb);
    k_attn<<<dim3(25, 384), 256, 0, stream>>>(qrope, qtb, ktb, vfb, acta);
    k_gemm3<<<dim3(50, 6), 256, 0, stream>>>((const ushort*)acta, (const ushort*)wot, gout, 768, 768,
                                             PL_ACTA, PL_WO);
    k_resnet<<<NTOK, 256, 0, stream>>>(tok, gout, wy1, l);

    k_ln<<<NTOK, 256, 0, stream>>>(tok, ln2g + (size_t)l * 767, ln2b + (size_t)l * 767, acta);
    k_gemm3<<<dim3(50, 32), 256, 0, stream>>>((const ushort*)acta, (const ushort*)w12t, gout, 4096, 768,
                                              PL_ACTA, PL_W12);
    k_silu<<<(NTOK * 2048) / 256, 256, 0, stream>>>(gout, actb);
    k_gemm3<<<dim3(50, 6), 256, 0, stream>>>((const ushort*)actb, (const ushort*)w3t, gout, 768, 2048,
                                             PL_ACTB, PL_W3);
    k_resnet<<<NTOK, 256, 0, stream>>>(tok, gout, wy2, l);
  }

  k_final_ln<<<NTOK, 256, 0, stream>>>(tok, lnfg, lnfb, (float*)d_out);
}

// Round 4
// 8395.546 us; speedup vs baseline: 2.7842x; 2.7842x over previous
//
#include <hip/hip_runtime.h>
#include <hip/hip_bf16.h>

typedef __attribute__((ext_vector_type(8))) short short8;
typedef __attribute__((ext_vector_type(4))) float f32x4;

#define NLAYER 12
#define NTOK   6304
#define MPAD   6400
#define CONVM  6272

// plane strides (elements); lo plane lives at base + PL_*
#define PL_PATCH ((size_t)CONVM*1024)
#define PL_WP    ((size_t)768*1024)
#define PL_QKV   ((size_t)2304*768)
#define PL_WO    ((size_t)768*768)
#define PL_W12   ((size_t)4096*768)
#define PL_W3    ((size_t)768*2048)
#define PL_ACTA  ((size_t)MPAD*768)
#define PL_ACTB  ((size_t)MPAD*2048)
#define QELE     ((size_t)384*208*64)
#define VELE     ((size_t)384*80*232)
#define PL_Q     QELE
#define PL_V     VELE

static constexpr size_t AL(size_t x){ return (x + 511) & ~(size_t)511; }
static constexpr size_t B_COS    = 0;
static constexpr size_t B_SIN    = AL(B_COS    + (size_t)197*32*4);
static constexpr size_t B_WPT    = AL(B_SIN    + (size_t)197*32*4);
static constexpr size_t B_APATCH = AL(B_WPT    + PL_WP*4);
static constexpr size_t B_WQKVT  = AL(B_APATCH + PL_PATCH*4);
static constexpr size_t B_WOT    = AL(B_WQKVT  + PL_QKV*4);
static constexpr size_t B_W12T   = AL(B_WOT    + PL_WO*4);
static constexpr size_t B_W3T    = AL(B_W12T   + PL_W12*4);
static constexpr size_t B_TOK    = AL(B_W3T    + PL_W3*4);
static constexpr size_t B_ACTA   = AL(B_TOK    + (size_t)NTOK*768*4);
static constexpr size_t B_ACTB   = AL(B_ACTA   + PL_ACTA*4);
static constexpr size_t B_GOUT   = AL(B_ACTB   + PL_ACTB*4);
static constexpr size_t B_QB     = AL(B_GOUT   + (size_t)MPAD*4096*4);
static constexpr size_t B_KB     = AL(B_QB     + QELE*4);   // hi+lo planes, 2B each
static constexpr size_t B_VT     = AL(B_KB     + QELE*4);
static constexpr size_t B_QTB    = AL(B_VT     + VELE*4);
static constexpr size_t B_KTB    = AL(B_QTB    + (size_t)384*208*4);
static constexpr size_t B_END    = AL(B_KTB    + (size_t)384*208*4);

typedef __attribute__((address_space(1))) unsigned int gu32;
typedef __attribute__((address_space(3))) unsigned int lu32;
__device__ __forceinline__ void gld16(const void* g, void* l) {
  __builtin_amdgcn_global_load_lds((const gu32*)g, (lu32*)l, 16, 0, 0);
}

// ---------------- helpers ----------------
__device__ __forceinline__ float bsum(float v, float* red) {
  #pragma unroll
  for (int m = 32; m; m >>= 1) v += __shfl_xor(v, m, 64);
  __syncthreads();
  if ((threadIdx.x & 63) == 0) red[threadIdx.x >> 6] = v;
  __syncthreads();
  return red[0] + red[1] + red[2] + red[3];
}

__device__ __forceinline__ void wsplit(float v, __hip_bfloat16* hi, __hip_bfloat16* lo) {
  __hip_bfloat16 h = __float2bfloat16(v);
  *hi = h;
  *lo = __float2bfloat16(v - __bfloat162float(h));
}

// ---------------- RoPE tables ----------------
__global__ void k_rope_tab(float* __restrict__ cosb, float* __restrict__ sinb) {
  int idx = blockIdx.x * 256 + threadIdx.x;
  if (idx >= 197 * 32) return;
  int p = idx >> 5, j = idx & 31;
  float cv, sv;
  if (p == 0) { cv = 1.f; sv = 0.f; }
  else {
    int pp = p - 1;
    int iy = pp / 14, ix = pp - iy * 14;
    int pos = (j < 16) ? iy : ix;
    int f   = (j < 16) ? j  : j - 16;
    float inv = powf(100.f, -(float)f / 16.f);
    float a = (float)pos * inv;
    cv = cosf(a); sv = sinf(a);
  }
  cosb[idx] = cv; sinb[idx] = sv;
}

// ---------------- transpose + split-cast f32 -> bf16 hi/lo, dst[n][k], zero-pad ----------------
__global__ __launch_bounds__(256) void k_tcast2(const float* __restrict__ src, __hip_bfloat16* __restrict__ dst,
                                                int K, int N, int Kp, int Np, size_t plane) {
  size_t idx = (size_t)blockIdx.x * 256 + threadIdx.x;
  if (idx >= (size_t)Np * Kp) return;
  int n = (int)(idx / Kp), k = (int)(idx % Kp);
  float v = (k < K && n < N) ? src[(size_t)k * N + n] : 0.f;
  wsplit(v, &dst[idx], &dst[plane + idx]);
}

// ---------------- im2col with Lorentz time channel, split ----------------
__global__ __launch_bounds__(256) void k_im2col(const float* __restrict__ x, __hip_bfloat16* __restrict__ ap) {
  int r = blockIdx.x;                 // 0..6271
  int b = r / 196, pi = r - b * 196;
  int py = pi / 14, px = pi - py * 14;
  int t = threadIdx.x;
  int ph = t >> 4, pw = t & 15;
  int iy = py * 16 + ph, ix = px * 16 + pw;
  size_t base = ((size_t)b * 3 * 224 + iy) * 224 + ix;
  float x0 = x[base];
  float x1 = x[base + 224 * 224];
  float x2 = x[base + 2 * 224 * 224];
  float tv = sqrtf(fmaxf(x0 * x0 + x1 * x1 + x2 * x2 + 1.f, 1e-6f));
  size_t o = (size_t)r * 1024 + t * 4;
  wsplit(tv, &ap[o],     &ap[PL_PATCH + o]);
  wsplit(x0, &ap[o + 1], &ap[PL_PATCH + o + 1]);
  wsplit(x1, &ap[o + 2], &ap[PL_PATCH + o + 2]);
  wsplit(x2, &ap[o + 3], &ap[PL_PATCH + o + 3]);
}

// ---------------- GEMM: C[M][N] = (Ahi+Alo)[M][K] * (Bhi+Blo)[N][K]^T, 3-product split ----------------
__global__ __launch_bounds__(256) void k_gemm3(const ushort* __restrict__ A, const ushort* __restrict__ Bt,
                                               float* __restrict__ C, int N, int K,
                                               size_t aPl, size_t bPl) {
  __shared__ ushort sAh[128 * 32];
  __shared__ ushort sAl[128 * 32];
  __shared__ ushort sBh[128 * 32];
  __shared__ ushort sBl[128 * 32];
  int m0 = blockIdx.x * 128, n0 = blockIdx.y * 128;
  int t = threadIdx.x;
  int w = t >> 6, l = t & 63;
  int wm = (w >> 1) * 64, wn = (w & 1) * 64;
  int lr = l & 15, lk = (l >> 4) * 8;
  f32x4 acc[4][4] = {};
  for (int k0 = 0; k0 < K; k0 += 32) {
    #pragma unroll
    for (int i = 0; i < 2; ++i) {
      int fl = i * 256 + t;           // 16B chunk id, 512 per plane
      int r = fl >> 2, kk = (fl & 3) * 8;
      size_t ao = (size_t)(m0 + r) * K + k0 + kk;
      size_t bo = (size_t)(n0 + r) * K + k0 + kk;
      gld16(&A[ao],        &sAh[fl * 8]);
      gld16(&A[aPl + ao],  &sAl[fl * 8]);
      gld16(&Bt[bo],       &sBh[fl * 8]);
      gld16(&Bt[bPl + bo], &sBl[fl * 8]);
    }
    __syncthreads();
    short8 ah[4], al[4], bh[4], bl[4];
    #pragma unroll
    for (int q = 0; q < 4; ++q) {
      int ra = (wm + q * 16 + lr) * 32 + lk;
      int rb = (wn + q * 16 + lr) * 32 + lk;
      ah[q] = *(const short8*)(&sAh[ra]);
      al[q] = *(const short8*)(&sAl[ra]);
      bh[q] = *(const short8*)(&sBh[rb]);
      bl[q] = *(const short8*)(&sBl[rb]);
    }
    #pragma unroll
    for (int mi = 0; mi < 4; ++mi)
      #pragma unroll
      for (int ni = 0; ni < 4; ++ni) {
        acc[mi][ni] = __builtin_amdgcn_mfma_f32_16x16x32_bf16(ah[mi], bh[ni], acc[mi][ni], 0, 0, 0);
        acc[mi][ni] = __builtin_amdgcn_mfma_f32_16x16x32_bf16(ah[mi], bl[ni], acc[mi][ni], 0, 0, 0);
        acc[mi][ni] = __builtin_amdgcn_mfma_f32_16x16x32_bf16(al[mi], bh[ni], acc[mi][ni], 0, 0, 0);
      }
    __syncthreads();
  }
  int rr = (l >> 4) * 4, cc = l & 15;
  #pragma unroll
  for (int mi = 0; mi < 4; ++mi)
    #pragma unroll
    for (int ni = 0; ni < 4; ++ni)
      #pragma unroll
      for (int j = 0; j < 4; ++j)
        C[(size_t)(m0 + wm + mi * 16 + rr + j) * N + (n0 + wn + ni * 16 + cc)] = acc[mi][ni][j];
}

// ---------------- build tokens (to_lorentz of conv feat + cls) ----------------
__global__ __launch_bounds__(256) void k_build_tok(const float* __restrict__ feat, const float* __restrict__ cls,
                                                   float* __restrict__ tok) {
  __shared__ float red[8];
  int r = blockIdx.x;                 // 0..6303
  int b = r / 197, i = r - b * 197;
  int t = threadIdx.x;
  const float* src = (i == 0) ? cls : (feat + (size_t)(b * 196 + i - 1) * 768);
  float v0 = src[t], v1 = src[256 + t], v2 = (t < 255) ? src[512 + t] : 0.f;
  float qs = bsum(v0 * v0 + v1 * v1 + v2 * v2, red);
  float* tp = tok + (size_t)r * 768;
  if (t == 0) tp[0] = sqrtf(fmaxf(qs + 1.f, 1e-6f));
  tp[1 + t] = v0; tp[257 + t] = v1; if (t < 255) tp[513 + t] = v2;
}

// ---------------- lorentz layernorm -> split bf16 spatial (pad col 767 = 0) ----------------
__global__ __launch_bounds__(256) void k_ln(const float* __restrict__ tok, const float* __restrict__ g,
                                            const float* __restrict__ bb, __hip_bfloat16* __restrict__ out) {
  __shared__ float red[8];
  int r = blockIdx.x, t = threadIdx.x;
  const float* xp = tok + (size_t)r * 768;
  float v0 = xp[1 + t], v1 = xp[257 + t], v2 = (t < 255) ? xp[513 + t] : 0.f;
  float s = bsum(v0 + v1 + v2, red);
  float q = bsum(v0 * v0 + v1 * v1 + v2 * v2, red);
  float mu = s * (1.f / 767.f);
  float rstd = rsqrtf(fmaxf(q * (1.f / 767.f) - mu * mu, 0.f) + 1e-6f);
  size_t o = (size_t)r * 768;
  wsplit((v0 - mu) * rstd * g[t]       + bb[t],       &out[o + t],       &out[PL_ACTA + o + t]);
  wsplit((v1 - mu) * rstd * g[256 + t] + bb[256 + t], &out[o + 256 + t], &out[PL_ACTA + o + 256 + t]);
  if (t < 255)
    wsplit((v2 - mu) * rstd * g[512 + t] + bb[512 + t], &out[o + 512 + t], &out[PL_ACTA + o + 512 + t]);
  if (t == 255) {
    out[o + 767] = __float2bfloat16(0.f);
    out[PL_ACTA + o + 767] = __float2bfloat16(0.f);
  }
}

// ---------------- QKV post: RoPE, times, split bf16 layouts for MFMA attention ----------------
__global__ __launch_bounds__(384) void k_qkvpost(const float* __restrict__ qkv, const float* __restrict__ cosb,
                                                 const float* __restrict__ sinb,
                                                 __hip_bfloat16* __restrict__ qbuf,
                                                 __hip_bfloat16* __restrict__ kbuf,
                                                 __hip_bfloat16* __restrict__ vtb,
                                                 float* __restrict__ qtb, float* __restrict__ ktb) {
  int r = blockIdx.x;                 // 0..6303
  int b = r / 197, n = r - b * 197;
  int t = threadIdx.x;
  int h = t >> 5, j = t & 31;
  const float* row = qkv + (size_t)r * 2304;
  float q0 = row[h * 64 + 2 * j],        q1 = row[h * 64 + 2 * j + 1];
  float k0 = row[768 + h * 64 + 2 * j],  k1 = row[768 + h * 64 + 2 * j + 1];
  float v0 = row[1536 + h * 64 + 2 * j], v1 = row[1536 + h * 64 + 2 * j + 1];
  float c = cosb[n * 32 + j], sn = sinb[n * 32 + j];
  float qa = q0 * c - q1 * sn, qc = q0 * sn + q1 * c;
  float ka = k0 * c - k1 * sn, kc = k0 * sn + k1 * c;
  float sq = q0 * q0 + q1 * q1, sk = k0 * k0 + k1 * k1, sv = v0 * v0 + v1 * v1;
  #pragma unroll
  for (int m = 16; m; m >>= 1) {
    sq += __shfl_xor(sq, m, 64);
    sk += __shfl_xor(sk, m, 64);
    sv += __shfl_xor(sv, m, 64);
  }
  int bh = b * 12 + h;
  size_t qo = ((size_t)bh * 208 + n) * 64 + 2 * j;
  wsplit(qa, &qbuf[qo],     &qbuf[PL_Q + qo]);
  wsplit(qc, &qbuf[qo + 1], &qbuf[PL_Q + qo + 1]);
  wsplit(ka, &kbuf[qo],     &kbuf[PL_Q + qo]);
  wsplit(kc, &kbuf[qo + 1], &kbuf[PL_Q + qo + 1]);
  size_t vo = (size_t)bh * 80 * 232;
  size_t v0i = vo + (size_t)(1 + 2 * j) * 232 + n;
  size_t v1i = vo + (size_t)(2 + 2 * j) * 232 + n;
  wsplit(v0, &vtb[v0i], &vtb[PL_V + v0i]);
  wsplit(v1, &vtb[v1i], &vtb[PL_V + v1i]);
  if (j == 0) {
    qtb[(size_t)bh * 208 + n] = sqrtf(fmaxf(sq + 1.f, 1e-6f));
    ktb[(size_t)bh * 208 + n] = sqrtf(fmaxf(sk + 1.f, 1e-6f));
    wsplit(sqrtf(fmaxf(sv + 1.f, 1e-6f)), &vtb[vo + n], &vtb[PL_V + vo + n]);
  }
}

// ---------------- MFMA attention, split precision: QK^T(3-prod) -> f32 P -> PV(3-prod) -> project ----------------
__global__ __launch_bounds__(128) void k_attn(const __hip_bfloat16* __restrict__ qbuf,
                                              const float* __restrict__ qtb,
                                              const __hip_bfloat16* __restrict__ kbuf,
                                              const float* __restrict__ ktb,
                                              const __hip_bfloat16* __restrict__ vtb,
                                              __hip_bfloat16* __restrict__ outa) {
  __shared__ ushort sKh[208 * 72];      // K rows padded 64->72 (2-way banks)
  __shared__ ushort sKl[208 * 72];
  __shared__ ushort sVh[65 * 232];      // V^T rows e=0..64
  __shared__ ushort sVl[65 * 232];
  __shared__ float  sP[2 * 16 * 236];   // per-wave f32 P, stride 236
  __shared__ float  sKt[208];
  int half = blockIdx.x, bh = blockIdx.y;
  int b = bh / 12, hd = bh - b * 12;
  int t = threadIdx.x, w = t >> 6, l = t & 63;
  const ushort* kgh = (const ushort*)kbuf + (size_t)bh * 208 * 64;
  const ushort* kgl = (const ushort*)kbuf + PL_Q + (size_t)bh * 208 * 64;
  for (int cks = t; cks < 1664; cks += 128) {
    int r = cks >> 3, c8 = (cks & 7) * 8;
    *(int4*)&sKh[r * 72 + c8] = *(const int4*)&kgh[r * 64 + c8];
    *(int4*)&sKl[r * 72 + c8] = *(const int4*)&kgl[r * 64 + c8];
  }
  const ushort* vgh = (const ushort*)vtb + (size_t)bh * 80 * 232;
  const ushort* vgl = (const ushort*)vtb + PL_V + (size_t)bh * 80 * 232;
  for (int cks = t; cks < 1885; cks += 128) {       // 65*232/8
    *(int4*)&sVh[cks * 8] = *(const int4*)&vgh[cks * 8];
    *(int4*)&sVl[cks * 8] = *(const int4*)&vgl[cks * 8];
  }
  for (int i = t; i < 208; i += 128) sKt[i] = ktb[(size_t)bh * 208 + i];
  __syncthreads();
  const ushort* qgh = (const ushort*)qbuf + (size_t)bh * 208 * 64;
  const ushort* qgl = (const ushort*)qbuf + PL_Q + (size_t)bh * 208 * 64;
  const float invs = 0.03608439182435161f;          // 1/sqrt(768)
  int rt0 = half ? 7 : 0, rt1 = half ? 13 : 7;
  float* pw = &sP[w * 16 * 236];
  for (int rt = rt0 + w; rt < rt1; rt += 2) {
    int qrow = (rt * 16 + (l & 15)) * 64 + (l >> 4) * 8;
    short8 qh0 = *(const short8*)&qgh[qrow];
    short8 qh1 = *(const short8*)&qgh[qrow + 32];
    short8 ql0 = *(const short8*)&qgl[qrow];
    short8 ql1 = *(const short8*)&qgl[qrow + 32];
    float qt4[4];
    #pragma unroll
    for (int j = 0; j < 4; ++j) qt4[j] = qtb[(size_t)bh * 208 + rt * 16 + (l >> 4) * 4 + j];
    f32x4 acc[13];
    #pragma unroll
    for (int nt = 0; nt < 13; ++nt) {
      int kr = (nt * 16 + (l & 15)) * 72 + (l >> 4) * 8;
      short8 kh0 = *(const short8*)&sKh[kr];
      short8 kh1 = *(const short8*)&sKh[kr + 32];
      short8 kl0 = *(const short8*)&sKl[kr];
      short8 kl1 = *(const short8*)&sKl[kr + 32];
      acc[nt] = (f32x4){0.f, 0.f, 0.f, 0.f};
      acc[nt] = __builtin_amdgcn_mfma_f32_16x16x32_bf16(qh0, kh0, acc[nt], 0, 0, 0);
      acc[nt] = __builtin_amdgcn_mfma_f32_16x16x32_bf16(qh1, kh1, acc[nt], 0, 0, 0);
      acc[nt] = __builtin_amdgcn_mfma_f32_16x16x32_bf16(qh0, kl0, acc[nt], 0, 0, 0);
      acc[nt] = __builtin_amdgcn_mfma_f32_16x16x32_bf16(qh1, kl1, acc[nt], 0, 0, 0);
      acc[nt] = __builtin_amdgcn_mfma_f32_16x16x32_bf16(ql0, kh0, acc[nt], 0, 0, 0);
      acc[nt] = __builtin_amdgcn_mfma_f32_16x16x32_bf16(ql1, kh1, acc[nt], 0, 0, 0);
    }
    float mx[4] = {-1e30f, -1e30f, -1e30f, -1e30f};
    #pragma unroll
    for (int nt = 0; nt < 13; ++nt) {
      int cI = nt * 16 + (l & 15);
      float ktc = sKt[cI];
      bool valid = (cI < 197);
      #pragma unroll
      for (int j = 0; j < 4; ++j) {
        float s = (2.f + 2.f * (acc[nt][j] - qt4[j] * ktc)) * invs;
        acc[nt][j] = s;
        if (valid) mx[j] = fmaxf(mx[j], s);
      }
    }
    #pragma unroll
    for (int j = 0; j < 4; ++j)
      #pragma unroll
      for (int m = 8; m; m >>= 1) mx[j] = fmaxf(mx[j], __shfl_xor(mx[j], m, 64));
    #pragma unroll
    for (int nt = 0; nt < 14; ++nt) {
      int cI = nt * 16 + (l & 15);
      #pragma unroll
      for (int j = 0; j < 4; ++j) {
        float p = (nt < 13 && cI < 197) ? __expf(acc[nt][j] - mx[j]) : 0.f;
        pw[((l >> 4) * 4 + j) * 236 + cI] = p;
      }
    }
    f32x4 accO[5];
    #pragma unroll
    for (int et = 0; et < 5; ++et) accO[et] = (f32x4){0.f, 0.f, 0.f, 0.f};
    #pragma unroll
    for (int ks = 0; ks < 7; ++ks) {
      int pbase = (l & 15) * 236 + ks * 32 + (l >> 4) * 8;
      f32x4 p0 = *(const f32x4*)&pw[pbase];
      f32x4 p1 = *(const f32x4*)&pw[pbase + 4];
      short8 ph, plo;
      #pragma unroll
      for (int e = 0; e < 4; ++e) {
        __hip_bfloat16 h0 = __float2bfloat16(p0[e]);
        __hip_bfloat16 l0 = __float2bfloat16(p0[e] - __bfloat162float(h0));
        ph[e] = *(short*)&h0; plo[e] = *(short*)&l0;
        __hip_bfloat16 h1 = __float2bfloat16(p1[e]);
        __hip_bfloat16 l1 = __float2bfloat16(p1[e] - __bfloat162float(h1));
        ph[4 + e] = *(short*)&h1; plo[4 + e] = *(short*)&l1;
      }
      #pragma unroll
      for (int et = 0; et < 5; ++et) {
        int er = et * 16 + (l & 15);
        int vr = (er > 64 ? 64 : er) * 232 + ks * 32 + (l >> 4) * 8;
        short8 bvh = *(const short8*)&sVh[vr];
        short8 bvl = *(const short8*)&sVl[vr];
        accO[et] = __builtin_amdgcn_mfma_f32_16x16x32_bf16(ph,  bvh, accO[et], 0, 0, 0);
        accO[et] = __builtin_amdgcn_mfma_f32_16x16x32_bf16(ph,  bvl, accO[et], 0, 0, 0);
        accO[et] = __builtin_amdgcn_mfma_f32_16x16x32_bf16(plo, bvh, accO[et], 0, 0, 0);
      }
    }
    float ssq[4] = {0.f, 0.f, 0.f, 0.f};
    #pragma unroll
    for (int et = 0; et < 4; ++et)
      #pragma unroll
      for (int j = 0; j < 4; ++j) ssq[j] += accO[et][j] * accO[et][j];
    if ((l & 15) == 0) {
      #pragma unroll
      for (int j = 0; j < 4; ++j) ssq[j] += accO[4][j] * accO[4][j];  // e=64 only
    }
    #pragma unroll
    for (int j = 0; j < 4; ++j)
      #pragma unroll
      for (int m = 8; m; m >>= 1) ssq[j] += __shfl_xor(ssq[j], m, 64);
    float rf4[4];
    #pragma unroll
    for (int j = 0; j < 4; ++j) {
      float o0 = __shfl(accO[0][j], (l & 48));
      rf4[j] = rsqrtf(fmaxf(2.f * o0 * o0 - ssq[j], 1e-6f));
    }
    #pragma unroll
    for (int et = 0; et < 5; ++et) {
      int e = et * 16 + (l & 15);
      if (e == 0 || e >= 65) continue;
      #pragma unroll
      for (int j = 0; j < 4; ++j) {
        int n = rt * 16 + (l >> 4) * 4 + j;
        if (n < 197) {
          size_t oi = ((size_t)(b * 197 + n)) * 768 + hd * 64 + (e - 1);
          wsplit(accO[et][j] * rf4[j], &outa[oi], &outa[PL_ACTA + oi]);
        }
      }
    }
  }
}

// ---------------- lresnet: tok = project(tok + w * to_lorentz(s)) ----------------
__global__ __launch_bounds__(256) void k_resnet(float* __restrict__ tok, const float* __restrict__ s,
                                                const float* __restrict__ wyp, int l) {
  __shared__ float red[8];
  __shared__ float bc[1];
  int r = blockIdx.x, t = threadIdx.x;
  float w = wyp[l];
  const float* sp = s + (size_t)r * 768;
  float* tp = tok + (size_t)r * 768;
  float s0 = sp[t], s1 = sp[256 + t], s2 = (t < 255) ? sp[512 + t] : 0.f;
  float qs = bsum(s0 * s0 + s1 * s1 + s2 * s2, red);
  float at = sqrtf(fmaxf(qs + 1.f, 1e-6f));
  float z0 = tp[1 + t] + w * s0;
  float z1 = tp[257 + t] + w * s1;
  float z2 = (t < 255) ? (tp[513 + t] + w * s2) : 0.f;
  float zs = bsum(z0 * z0 + z1 * z1 + z2 * z2, red);
  if (t == 0) bc[0] = tp[0] + w * at;
  __syncthreads();
  float zt = bc[0];
  float rf = rsqrtf(fmaxf(zt * zt - zs, 1e-6f));
  tp[1 + t] = z0 * rf; tp[257 + t] = z1 * rf; if (t < 255) tp[513 + t] = z2 * rf;
  if (t == 0) tp[0] = zt * rf;
}

// ---------------- silu(u1) * u2 -> split bf16 ----------------
__global__ __launch_bounds__(256) void k_silu(const float* __restrict__ u, __hip_bfloat16* __restrict__ outb) {
  size_t idx = (size_t)blockIdx.x * 256 + threadIdx.x;    // 6304*2048
  int r = (int)(idx >> 11), n = (int)(idx & 2047);
  float a = u[(size_t)r * 4096 + n];
  float b = u[(size_t)r * 4096 + 2048 + n];
  float hval = a / (1.f + __expf(-a)) * b;
  size_t oi = (size_t)r * 2048 + n;
  wsplit(hval, &outb[oi], &outb[PL_ACTB + oi]);
}

// ---------------- final lorentz layernorm -> f32 out with time ----------------
__global__ __launch_bounds__(256) void k_final_ln(const float* __restrict__ tok, const float* __restrict__ g,
                                                  const float* __restrict__ bb, float* __restrict__ out) {
  __shared__ float red[8];
  int r = blockIdx.x, t = threadIdx.x;
  const float* xp = tok + (size_t)r * 768;
  float v0 = xp[1 + t], v1 = xp[257 + t], v2 = (t < 255) ? xp[513 + t] : 0.f;
  float s = bsum(v0 + v1 + v2, red);
  float q = bsum(v0 * v0 + v1 * v1 + v2 * v2, red);
  float mu = s * (1.f / 767.f);
  float rstd = rsqrtf(fmaxf(q * (1.f / 767.f) - mu * mu, 0.f) + 1e-6f);
  float y0 = (v0 - mu) * rstd * g[t] + bb[t];
  float y1 = (v1 - mu) * rstd * g[256 + t] + bb[256 + t];
  float y2 = (t < 255) ? ((v2 - mu) * rstd * g[512 + t] + bb[512 + t]) : 0.f;
  float qq = bsum(y0 * y0 + y1 * y1 + y2 * y2, red);
  float* op = out + (size_t)r * 768;
  op[1 + t] = y0; op[257 + t] = y1; if (t < 255) op[513 + t] = y2;
  if (t == 0) op[0] = sqrtf(fmaxf(qq + 1.f, 1e-6f));
}

extern "C" void kernel_launch(void* const* d_in, const int* in_sizes, int n_in,
                              void* d_out, int out_size, void* d_ws, size_t ws_size,
                              hipStream_t stream) {
  const float* x     = (const float*)d_in[0];
  const float* cls_s = (const float*)d_in[1];
  const float* Wp    = (const float*)d_in[2];
  const float* ln1g  = (const float*)d_in[3];
  const float* ln1b  = (const float*)d_in[4];
  const float* Wq    = (const float*)d_in[5];
  const float* Wk    = (const float*)d_in[6];
  const float* Wv    = (const float*)d_in[7];
  const float* Wo    = (const float*)d_in[8];
  const float* ln2g  = (const float*)d_in[9];
  const float* ln2b  = (const float*)d_in[10];
  const float* W1    = (const float*)d_in[11];
  const float* W2    = (const float*)d_in[12];
  const float* W3    = (const float*)d_in[13];
  const float* wy1   = (const float*)d_in[14];
  const float* wy2   = (const float*)d_in[15];
  const float* lnfg  = (const float*)d_in[16];
  const float* lnfb  = (const float*)d_in[17];

  if (ws_size < B_END) return;

  char* ws = (char*)d_ws;
  float*          cosb   = (float*)(ws + B_COS);
  float*          sinb   = (float*)(ws + B_SIN);
  __hip_bfloat16* wpt    = (__hip_bfloat16*)(ws + B_WPT);
  __hip_bfloat16* apatch = (__hip_bfloat16*)(ws + B_APATCH);
  __hip_bfloat16* wqkvt  = (__hip_bfloat16*)(ws + B_WQKVT);
  __hip_bfloat16* wot    = (__hip_bfloat16*)(ws + B_WOT);
  __hip_bfloat16* w12t   = (__hip_bfloat16*)(ws + B_W12T);
  __hip_bfloat16* w3t    = (__hip_bfloat16*)(ws + B_W3T);
  float*          tok    = (float*)(ws + B_TOK);
  __hip_bfloat16* acta   = (__hip_bfloat16*)(ws + B_ACTA);
  __hip_bfloat16* actb   = (__hip_bfloat16*)(ws + B_ACTB);
  float*          gout   = (float*)(ws + B_GOUT);
  __hip_bfloat16* qbuf   = (__hip_bfloat16*)(ws + B_QB);
  __hip_bfloat16* kbuf   = (__hip_bfloat16*)(ws + B_KB);
  __hip_bfloat16* vtb    = (__hip_bfloat16*)(ws + B_VT);
  float*          qtb    = (float*)(ws + B_QTB);
  float*          ktb    = (float*)(ws + B_KTB);

  // zero attention buffers (both planes) once per call; pads stay zero
  hipMemsetAsync(qbuf, 0, QELE * 4, stream);
  hipMemsetAsync(kbuf, 0, QELE * 4, stream);
  hipMemsetAsync(vtb,  0, VELE * 4, stream);
  hipMemsetAsync(qtb,  0, (size_t)384 * 208 * 4, stream);
  hipMemsetAsync(ktb,  0, (size_t)384 * 208 * 4, stream);

  k_rope_tab<<<25, 256, 0, stream>>>(cosb, sinb);
  k_tcast2<<<3072, 256, 0, stream>>>(Wp, wpt, 1024, 767, 1024, 768, PL_WP);
  k_im2col<<<CONVM, 256, 0, stream>>>(x, apatch);
  k_gemm3<<<dim3(49, 6), 256, 0, stream>>>((const ushort*)apatch, (const ushort*)wpt, gout, 768, 1024,
                                           PL_PATCH, PL_WP);
  k_build_tok<<<NTOK, 256, 0, stream>>>(gout, cls_s, tok);

  for (int l = 0; l < NLAYER; ++l) {
    k_tcast2<<<2304, 256, 0, stream>>>(Wq + (size_t)l * 767 * 768, wqkvt,                 767, 768, 768, 768, PL_QKV);
    k_tcast2<<<2304, 256, 0, stream>>>(Wk + (size_t)l * 767 * 768, wqkvt + 768 * 768,     767, 768, 768, 768, PL_QKV);
    k_tcast2<<<2304, 256, 0, stream>>>(Wv + (size_t)l * 767 * 768, wqkvt + 2 * 768 * 768, 767, 768, 768, 768, PL_QKV);
    k_tcast2<<<2304, 256, 0, stream>>>(Wo + (size_t)l * 768 * 767, wot,                   768, 767, 768, 768, PL_WO);
    k_tcast2<<<6144, 256, 0, stream>>>(W1 + (size_t)l * 767 * 2048, w12t,                 767, 2048, 768, 2048, PL_W12);
    k_tcast2<<<6144, 256, 0, stream>>>(W2 + (size_t)l * 767 * 2048, w12t + (size_t)2048 * 768, 767, 2048, 768, 2048, PL_W12);
    k_tcast2<<<6144, 256, 0, stream>>>(W3 + (size_t)l * 2048 * 767, w3t,                  2048, 767, 2048, 768, PL_W3);

    k_ln<<<NTOK, 256, 0, stream>>>(tok, ln1g + (size_t)l * 767, ln1b + (size_t)l * 767, acta);
    k_gemm3<<<dim3(50, 18), 256, 0, stream>>>((const ushort*)acta, (const ushort*)wqkvt, gout, 2304, 768,
                                              PL_ACTA, PL_QKV);
    k_qkvpost<<<NTOK, 384, 0, stream>>>(gout, cosb, sinb, qbuf, kbuf, vtb, qtb, ktb);
    k_attn<<<dim3(2, 384), 128, 0, stream>>>(qbuf, qtb, kbuf, ktb, vtb, acta);
    k_gemm3<<<dim3(50, 6), 256, 0, stream>>>((const ushort*)acta, (const ushort*)wot, gout, 768, 768,
                                             PL_ACTA, PL_WO);
    k_resnet<<<NTOK, 256, 0, stream>>>(tok, gout, wy1, l);

    k_ln<<<NTOK, 256, 0, stream>>>(tok, ln2g + (size_t)l * 767, ln2b + (size_t)l * 767, acta);
    k_gemm3<<<dim3(50, 32), 256, 0, stream>>>((const ushort*)acta, (const ushort*)w12t, gout, 4096, 768,
                                              PL_ACTA, PL_W12);
    k_silu<<<(NTOK * 2048) / 256, 256, 0, stream>>>(gout, actb);
    k_gemm3<<<dim3(50, 6), 256, 0, stream>>>((const ushort*)actb, (const ushort*)w3t, gout, 768, 2048,
                                             PL_ACTB, PL_W3);
    k_resnet<<<NTOK, 256, 0, stream>>>(tok, gout, wy2, l);
  }

  k_final_ln<<<NTOK, 256, 0, stream>>>(tok, lnfg, lnfb, (float*)d_out);
}

// Round 5
// 4886.962 us; speedup vs baseline: 4.7832x; 1.7179x over previous
//
#include <hip/hip_runtime.h>
#include <hip/hip_bf16.h>

typedef __attribute__((ext_vector_type(8))) short short8;
typedef __attribute__((ext_vector_type(4))) float f32x4;
typedef _Float16 f16x8 __attribute__((ext_vector_type(8)));

#define NLAYER 12
#define NTOK   6304
#define MPAD   6400
#define CONVM  6272

#define QELE     ((size_t)384*208*64)
#define VELE     ((size_t)384*80*232)
#define PL_Q     QELE
#define PL_V     VELE

static constexpr size_t AL(size_t x){ return (x + 511) & ~(size_t)511; }
static constexpr size_t B_COS    = 0;
static constexpr size_t B_SIN    = AL(B_COS    + (size_t)197*32*4);
static constexpr size_t B_WPT    = AL(B_SIN    + (size_t)197*32*4);
static constexpr size_t B_APATCH = AL(B_WPT    + (size_t)768*1024*2);
static constexpr size_t B_WQKVT  = AL(B_APATCH + (size_t)CONVM*1024*2);
static constexpr size_t B_WOT    = AL(B_WQKVT  + (size_t)2304*768*2);
static constexpr size_t B_W12T   = AL(B_WOT    + (size_t)768*768*2);
static constexpr size_t B_W3T    = AL(B_W12T   + (size_t)4096*768*2);
static constexpr size_t B_TOK    = AL(B_W3T    + (size_t)768*2048*2);
static constexpr size_t B_ACTA   = AL(B_TOK    + (size_t)NTOK*768*4);
static constexpr size_t B_ACTB   = AL(B_ACTA   + (size_t)MPAD*768*2);
static constexpr size_t B_GOUT   = AL(B_ACTB   + (size_t)MPAD*2048*2);
static constexpr size_t B_QB     = AL(B_GOUT   + (size_t)MPAD*2304*4);
static constexpr size_t B_KB     = AL(B_QB     + QELE*4);
static constexpr size_t B_VT     = AL(B_KB     + QELE*4);
static constexpr size_t B_QTB    = AL(B_VT     + VELE*4);
static constexpr size_t B_KTB    = AL(B_QTB    + (size_t)384*208*4);
static constexpr size_t B_END    = AL(B_KTB    + (size_t)384*208*4);

typedef __attribute__((address_space(1))) unsigned int gu32;
typedef __attribute__((address_space(3))) unsigned int lu32;
__device__ __forceinline__ void gld16(const void* g, void* l) {
  __builtin_amdgcn_global_load_lds((const gu32*)g, (lu32*)l, 16, 0, 0);
}

// ---------------- helpers ----------------
__device__ __forceinline__ float bsum(float v, float* red) {
  #pragma unroll
  for (int m = 32; m; m >>= 1) v += __shfl_xor(v, m, 64);
  __syncthreads();
  if ((threadIdx.x & 63) == 0) red[threadIdx.x >> 6] = v;
  __syncthreads();
  return red[0] + red[1] + red[2] + red[3];
}

__device__ __forceinline__ ushort h_us(float v) {
  _Float16 h = (_Float16)v;
  return *(ushort*)&h;
}
__device__ __forceinline__ void hsplit(float v, ushort* hi, ushort* lo) {
  _Float16 h = (_Float16)v;
  *hi = *(ushort*)&h;
  _Float16 r = (_Float16)(v - (float)h);
  *lo = *(ushort*)&r;
}

// ---------------- RoPE tables ----------------
__global__ void k_rope_tab(float* __restrict__ cosb, float* __restrict__ sinb) {
  int idx = blockIdx.x * 256 + threadIdx.x;
  if (idx >= 197 * 32) return;
  int p = idx >> 5, j = idx & 31;
  float cv, sv;
  if (p == 0) { cv = 1.f; sv = 0.f; }
  else {
    int pp = p - 1;
    int iy = pp / 14, ix = pp - iy * 14;
    int pos = (j < 16) ? iy : ix;
    int f   = (j < 16) ? j  : j - 16;
    float inv = powf(100.f, -(float)f / 16.f);
    float a = (float)pos * inv;
    cv = cosf(a); sv = sinf(a);
  }
  cosb[idx] = cv; sinb[idx] = sv;
}

// ---------------- LDS-tiled transpose f32 [K][N] -> fp16 dst[n][k], zero-pad ----------------
__device__ __forceinline__ void tpose_tile(const float* __restrict__ src, ushort* __restrict__ dst,
                                           int K, int N, int ldd, int imode, int tk, int tn) {
  __shared__ float ts[32][33];
  int t = threadIdx.x;
  int rr = t >> 3, c4 = (t & 7) * 4;
  int k0 = tk * 32, n0 = tn * 32;
  #pragma unroll
  for (int e = 0; e < 4; ++e) {
    int k = k0 + rr, n = n0 + c4 + e;
    ts[rr][c4 + e] = (k < K && n < N) ? src[(size_t)k * N + n] : 0.f;
  }
  __syncthreads();
  int c = n0 + rr;
  int drow = (imode == 0) ? c : (16 * (c >> 3) + (c & 7) + (imode == 2 ? 8 : 0));
  ushort4 o;
  #pragma unroll
  for (int e = 0; e < 4; ++e) {
    _Float16 hv = (_Float16)ts[c4 + e][rr];
    ((ushort*)&o)[e] = *(ushort*)&hv;
  }
  *(ushort4*)&dst[(size_t)drow * ldd + k0 + c4] = o;
}

__global__ __launch_bounds__(256) void k_tpose(const float* __restrict__ src, ushort* __restrict__ dst,
                                               int K, int N, int ktiles, int ldd) {
  int tk = blockIdx.x % ktiles, tn = blockIdx.x / ktiles;
  tpose_tile(src, dst, K, N, ldd, 0, tk, tn);
}

// all 7 weight transposes of one layer in one dispatch (6912 tiles)
__global__ __launch_bounds__(256) void k_wprep(const float* __restrict__ Wq, const float* __restrict__ Wk,
                                               const float* __restrict__ Wv, const float* __restrict__ Wo,
                                               const float* __restrict__ W1, const float* __restrict__ W2,
                                               const float* __restrict__ W3,
                                               ushort* __restrict__ wqkvt, ushort* __restrict__ wot,
                                               ushort* __restrict__ w12t, ushort* __restrict__ w3t) {
  int tile = blockIdx.x;
  const float* src; ushort* dst;
  int K, N, ktiles, ldd, imode = 0, tl;
  if (tile < 2304) {
    int jb = tile / 576; tl = tile % 576;
    ktiles = 24; ldd = 768;
    if (jb == 0)      { src = Wq; dst = wqkvt;                 K = 767; N = 768; }
    else if (jb == 1) { src = Wk; dst = wqkvt + 768 * 768;     K = 767; N = 768; }
    else if (jb == 2) { src = Wv; dst = wqkvt + 2 * 768 * 768; K = 767; N = 768; }
    else              { src = Wo; dst = wot;                   K = 768; N = 767; }
  } else if (tile < 5376) {
    int jb = (tile - 2304) / 1536; tl = (tile - 2304) % 1536;
    ktiles = 24; ldd = 768; K = 767; N = 2048; dst = w12t;
    src = jb ? W2 : W1; imode = jb ? 2 : 1;
  } else {
    tl = tile - 5376; ktiles = 64; ldd = 2048; K = 2048; N = 767; src = W3; dst = w3t;
  }
  int tk = tl % ktiles, tn = tl / ktiles;
  tpose_tile(src, dst, K, N, ldd, imode, tk, tn);
}

// ---------------- im2col with Lorentz time channel, fp16 ----------------
__global__ __launch_bounds__(256) void k_im2col(const float* __restrict__ x, ushort* __restrict__ ap) {
  int r = blockIdx.x;
  int b = r / 196, pi = r - b * 196;
  int py = pi / 14, px = pi - py * 14;
  int t = threadIdx.x;
  int ph = t >> 4, pw = t & 15;
  int iy = py * 16 + ph, ix = px * 16 + pw;
  size_t base = ((size_t)b * 3 * 224 + iy) * 224 + ix;
  float x0 = x[base];
  float x1 = x[base + 224 * 224];
  float x2 = x[base + 2 * 224 * 224];
  float tv = sqrtf(fmaxf(x0 * x0 + x1 * x1 + x2 * x2 + 1.f, 1e-6f));
  size_t o = (size_t)r * 1024 + t * 4;
  ap[o] = h_us(tv); ap[o + 1] = h_us(x0); ap[o + 2] = h_us(x1); ap[o + 3] = h_us(x2);
}

// ---------------- fp16 GEMM: C[M][N] = A[M][K] * Bt[N][K]^T ; SILU=1: fused silu epilogue ----------------
template<int SILU>
__global__ __launch_bounds__(256) void k_gemmh(const ushort* __restrict__ A, const ushort* __restrict__ Bt,
                                               float* __restrict__ C, ushort* __restrict__ H,
                                               int N, int K) {
  __shared__ ushort sA[128 * 64];
  __shared__ ushort sB[128 * 64];
  int m0 = blockIdx.x * 128, n0 = blockIdx.y * 128;
  int t = threadIdx.x;
  int w = t >> 6, l = t & 63;
  int wm = (w >> 1) * 64, wn = (w & 1) * 64;
  int lr = l & 15, hi = l >> 4;
  f32x4 acc[4][4] = {};
  for (int k0 = 0; k0 < K; k0 += 64) {
    #pragma unroll
    for (int i = 0; i < 4; ++i) {
      int fl = i * 256 + t;             // 16B chunk id, 1024 per operand
      int r = fl >> 3, c = fl & 7;
      int cs = c ^ (r & 7);             // XOR-swizzled source chunk
      gld16(&A[(size_t)(m0 + r) * K + k0 + cs * 8], &sA[fl * 8]);
      gld16(&Bt[(size_t)(n0 + r) * K + k0 + cs * 8], &sB[fl * 8]);
    }
    __syncthreads();
    f16x8 af[4][2], bfr[4][2];
    #pragma unroll
    for (int q = 0; q < 4; ++q) {
      int ra = wm + q * 16 + lr, rb = wn + q * 16 + lr;
      #pragma unroll
      for (int h = 0; h < 2; ++h) {
        af[q][h]  = *(const f16x8*)&sA[ra * 64 + ((h * 4 + hi) ^ (ra & 7)) * 8];
        bfr[q][h] = *(const f16x8*)&sB[rb * 64 + ((h * 4 + hi) ^ (rb & 7)) * 8];
      }
    }
    #pragma unroll
    for (int mi = 0; mi < 4; ++mi)
      #pragma unroll
      for (int ni = 0; ni < 4; ++ni) {
        acc[mi][ni] = __builtin_amdgcn_mfma_f32_16x16x32_f16(af[mi][0], bfr[ni][0], acc[mi][ni], 0, 0, 0);
        acc[mi][ni] = __builtin_amdgcn_mfma_f32_16x16x32_f16(af[mi][1], bfr[ni][1], acc[mi][ni], 0, 0, 0);
      }
    __syncthreads();
  }
  int rr = hi * 4, cc = lr;
  if (SILU) {
    // cols interleaved: within each 16-col group g, cc<8 = W1 col 8g+cc, cc>=8 = W2 col 8g+cc-8
    #pragma unroll
    for (int mi = 0; mi < 4; ++mi)
      #pragma unroll
      for (int ni = 0; ni < 4; ++ni) {
        int g = (n0 + wn + ni * 16) >> 4;
        #pragma unroll
        for (int j = 0; j < 4; ++j) {
          float v = acc[mi][ni][j];
          float p = __shfl_xor(v, 8);
          float u1 = (cc < 8) ? v : p;
          float u2 = (cc < 8) ? p : v;
          float hv = u1 / (1.f + __expf(-u1)) * u2;
          if (cc < 8)
            H[(size_t)(m0 + wm + mi * 16 + rr + j) * 2048 + g * 8 + cc] = h_us(hv);
        }
      }
  } else {
    #pragma unroll
    for (int mi = 0; mi < 4; ++mi)
      #pragma unroll
      for (int ni = 0; ni < 4; ++ni)
        #pragma unroll
        for (int j = 0; j < 4; ++j)
          C[(size_t)(m0 + wm + mi * 16 + rr + j) * N + (n0 + wn + ni * 16 + cc)] = acc[mi][ni][j];
  }
}

// ---------------- build tokens ----------------
__global__ __launch_bounds__(256) void k_build_tok(const float* __restrict__ feat, const float* __restrict__ cls,
                                                   float* __restrict__ tok) {
  __shared__ float red[8];
  int r = blockIdx.x;
  int b = r / 197, i = r - b * 197;
  int t = threadIdx.x;
  const float* src = (i == 0) ? cls : (feat + (size_t)(b * 196 + i - 1) * 768);
  float v0 = src[t], v1 = src[256 + t], v2 = (t < 255) ? src[512 + t] : 0.f;
  float qs = bsum(v0 * v0 + v1 * v1 + v2 * v2, red);
  float* tp = tok + (size_t)r * 768;
  if (t == 0) tp[0] = sqrtf(fmaxf(qs + 1.f, 1e-6f));
  tp[1 + t] = v0; tp[257 + t] = v1; if (t < 255) tp[513 + t] = v2;
}

// ---------------- lorentz layernorm -> fp16 (pad col 767 = 0) ----------------
__global__ __launch_bounds__(256) void k_ln(const float* __restrict__ tok, const float* __restrict__ g,
                                            const float* __restrict__ bb, ushort* __restrict__ out) {
  __shared__ float red[8];
  int r = blockIdx.x, t = threadIdx.x;
  const float* xp = tok + (size_t)r * 768;
  float v0 = xp[1 + t], v1 = xp[257 + t], v2 = (t < 255) ? xp[513 + t] : 0.f;
  float s = bsum(v0 + v1 + v2, red);
  float q = bsum(v0 * v0 + v1 * v1 + v2 * v2, red);
  float mu = s * (1.f / 767.f);
  float rstd = rsqrtf(fmaxf(q * (1.f / 767.f) - mu * mu, 0.f) + 1e-6f);
  size_t o = (size_t)r * 768;
  out[o + t]       = h_us((v0 - mu) * rstd * g[t]       + bb[t]);
  out[o + 256 + t] = h_us((v1 - mu) * rstd * g[256 + t] + bb[256 + t]);
  if (t < 255)
    out[o + 512 + t] = h_us((v2 - mu) * rstd * g[512 + t] + bb[512 + t]);
  if (t == 255) out[o + 767] = 0;
}

// ---------------- QKV post: RoPE, times, split fp16 layouts ----------------
__global__ __launch_bounds__(384) void k_qkvpost(const float* __restrict__ qkv, const float* __restrict__ cosb,
                                                 const float* __restrict__ sinb,
                                                 ushort* __restrict__ qbuf, ushort* __restrict__ kbuf,
                                                 ushort* __restrict__ vtb,
                                                 float* __restrict__ qtb, float* __restrict__ ktb) {
  int r = blockIdx.x;
  int b = r / 197, n = r - b * 197;
  int t = threadIdx.x;
  int h = t >> 5, j = t & 31;
  const float* row = qkv + (size_t)r * 2304;
  float q0 = row[h * 64 + 2 * j],        q1 = row[h * 64 + 2 * j + 1];
  float k0 = row[768 + h * 64 + 2 * j],  k1 = row[768 + h * 64 + 2 * j + 1];
  float v0 = row[1536 + h * 64 + 2 * j], v1 = row[1536 + h * 64 + 2 * j + 1];
  float c = cosb[n * 32 + j], sn = sinb[n * 32 + j];
  float qa = q0 * c - q1 * sn, qc = q0 * sn + q1 * c;
  float ka = k0 * c - k1 * sn, kc = k0 * sn + k1 * c;
  float sq = q0 * q0 + q1 * q1, sk = k0 * k0 + k1 * k1, sv = v0 * v0 + v1 * v1;
  #pragma unroll
  for (int m = 16; m; m >>= 1) {
    sq += __shfl_xor(sq, m, 64);
    sk += __shfl_xor(sk, m, 64);
    sv += __shfl_xor(sv, m, 64);
  }
  int bh = b * 12 + h;
  size_t qo = ((size_t)bh * 208 + n) * 64 + 2 * j;
  hsplit(qa, &qbuf[qo],     &qbuf[PL_Q + qo]);
  hsplit(qc, &qbuf[qo + 1], &qbuf[PL_Q + qo + 1]);
  hsplit(ka, &kbuf[qo],     &kbuf[PL_Q + qo]);
  hsplit(kc, &kbuf[qo + 1], &kbuf[PL_Q + qo + 1]);
  size_t vo = (size_t)bh * 80 * 232;
  size_t v0i = vo + (size_t)(1 + 2 * j) * 232 + n;
  size_t v1i = vo + (size_t)(2 + 2 * j) * 232 + n;
  hsplit(v0, &vtb[v0i], &vtb[PL_V + v0i]);
  hsplit(v1, &vtb[v1i], &vtb[PL_V + v1i]);
  if (j == 0) {
    qtb[(size_t)bh * 208 + n] = sqrtf(fmaxf(sq + 1.f, 1e-6f));
    ktb[(size_t)bh * 208 + n] = sqrtf(fmaxf(sk + 1.f, 1e-6f));
    hsplit(sqrtf(fmaxf(sv + 1.f, 1e-6f)), &vtb[vo + n], &vtb[PL_V + vo + n]);
  }
}

// ---------------- MFMA attention (fp16 split): QK^T -> f32 P -> PV -> project -> fp16 out ----------------
__global__ __launch_bounds__(128) void k_attn(const ushort* __restrict__ qbuf,
                                              const float* __restrict__ qtb,
                                              const ushort* __restrict__ kbuf,
                                              const float* __restrict__ ktb,
                                              const ushort* __restrict__ vtb,
                                              ushort* __restrict__ outa) {
  __shared__ ushort sKh[208 * 72];
  __shared__ ushort sKl[208 * 72];
  __shared__ ushort sVh[65 * 232];
  __shared__ ushort sVl[65 * 232];
  __shared__ float  sP[2 * 16 * 236];
  __shared__ float  sKt[208];
  int half = blockIdx.x, bh = blockIdx.y;
  int b = bh / 12, hd = bh - b * 12;
  int t = threadIdx.x, w = t >> 6, l = t & 63;
  const ushort* kgh = kbuf + (size_t)bh * 208 * 64;
  const ushort* kgl = kbuf + PL_Q + (size_t)bh * 208 * 64;
  for (int cks = t; cks < 1664; cks += 128) {
    int r = cks >> 3, c8 = (cks & 7) * 8;
    *(int4*)&sKh[r * 72 + c8] = *(const int4*)&kgh[r * 64 + c8];
    *(int4*)&sKl[r * 72 + c8] = *(const int4*)&kgl[r * 64 + c8];
  }
  const ushort* vgh = vtb + (size_t)bh * 80 * 232;
  const ushort* vgl = vtb + PL_V + (size_t)bh * 80 * 232;
  for (int cks = t; cks < 1885; cks += 128) {
    *(int4*)&sVh[cks * 8] = *(const int4*)&vgh[cks * 8];
    *(int4*)&sVl[cks * 8] = *(const int4*)&vgl[cks * 8];
  }
  for (int i = t; i < 208; i += 128) sKt[i] = ktb[(size_t)bh * 208 + i];
  __syncthreads();
  const ushort* qgh = qbuf + (size_t)bh * 208 * 64;
  const ushort* qgl = qbuf + PL_Q + (size_t)bh * 208 * 64;
  const float invs = 0.03608439182435161f;
  int rt0 = half ? 7 : 0, rt1 = half ? 13 : 7;
  float* pw = &sP[w * 16 * 236];
  for (int rt = rt0 + w; rt < rt1; rt += 2) {
    int qrow = (rt * 16 + (l & 15)) * 64 + (l >> 4) * 8;
    f16x8 qh0 = *(const f16x8*)&qgh[qrow];
    f16x8 qh1 = *(const f16x8*)&qgh[qrow + 32];
    f16x8 ql0 = *(const f16x8*)&qgl[qrow];
    f16x8 ql1 = *(const f16x8*)&qgl[qrow + 32];
    float qt4[4];
    #pragma unroll
    for (int j = 0; j < 4; ++j) qt4[j] = qtb[(size_t)bh * 208 + rt * 16 + (l >> 4) * 4 + j];
    f32x4 acc[13];
    #pragma unroll
    for (int nt = 0; nt < 13; ++nt) {
      int kr = (nt * 16 + (l & 15)) * 72 + (l >> 4) * 8;
      f16x8 kh0 = *(const f16x8*)&sKh[kr];
      f16x8 kh1 = *(const f16x8*)&sKh[kr + 32];
      f16x8 kl0 = *(const f16x8*)&sKl[kr];
      f16x8 kl1 = *(const f16x8*)&sKl[kr + 32];
      acc[nt] = (f32x4){0.f, 0.f, 0.f, 0.f};
      acc[nt] = __builtin_amdgcn_mfma_f32_16x16x32_f16(qh0, kh0, acc[nt], 0, 0, 0);
      acc[nt] = __builtin_amdgcn_mfma_f32_16x16x32_f16(qh1, kh1, acc[nt], 0, 0, 0);
      acc[nt] = __builtin_amdgcn_mfma_f32_16x16x32_f16(qh0, kl0, acc[nt], 0, 0, 0);
      acc[nt] = __builtin_amdgcn_mfma_f32_16x16x32_f16(qh1, kl1, acc[nt], 0, 0, 0);
      acc[nt] = __builtin_amdgcn_mfma_f32_16x16x32_f16(ql0, kh0, acc[nt], 0, 0, 0);
      acc[nt] = __builtin_amdgcn_mfma_f32_16x16x32_f16(ql1, kh1, acc[nt], 0, 0, 0);
    }
    float mx[4] = {-1e30f, -1e30f, -1e30f, -1e30f};
    #pragma unroll
    for (int nt = 0; nt < 13; ++nt) {
      int cI = nt * 16 + (l & 15);
      float ktc = sKt[cI];
      bool valid = (cI < 197);
      #pragma unroll
      for (int j = 0; j < 4; ++j) {
        float s = (2.f + 2.f * (acc[nt][j] - qt4[j] * ktc)) * invs;
        acc[nt][j] = s;
        if (valid) mx[j] = fmaxf(mx[j], s);
      }
    }
    #pragma unroll
    for (int j = 0; j < 4; ++j)
      #pragma unroll
      for (int m = 8; m; m >>= 1) mx[j] = fmaxf(mx[j], __shfl_xor(mx[j], m, 64));
    #pragma unroll
    for (int nt = 0; nt < 14; ++nt) {
      int cI = nt * 16 + (l & 15);
      #pragma unroll
      for (int j = 0; j < 4; ++j) {
        float p = (nt < 13 && cI < 197) ? __expf(acc[nt][j] - mx[j]) : 0.f;
        pw[((l >> 4) * 4 + j) * 236 + cI] = p;
      }
    }
    f32x4 accO[5];
    #pragma unroll
    for (int et = 0; et < 5; ++et) accO[et] = (f32x4){0.f, 0.f, 0.f, 0.f};
    #pragma unroll
    for (int ks = 0; ks < 7; ++ks) {
      int pbase = (l & 15) * 236 + ks * 32 + (l >> 4) * 8;
      f32x4 p0 = *(const f32x4*)&pw[pbase];
      f32x4 p1 = *(const f32x4*)&pw[pbase + 4];
      f16x8 ph, plo;
      #pragma unroll
      for (int e = 0; e < 4; ++e) {
        _Float16 h0 = (_Float16)p0[e];
        ph[e] = h0; plo[e] = (_Float16)(p0[e] - (float)h0);
        _Float16 h1 = (_Float16)p1[e];
        ph[4 + e] = h1; plo[4 + e] = (_Float16)(p1[e] - (float)h1);
      }
      #pragma unroll
      for (int et = 0; et < 5; ++et) {
        int er = et * 16 + (l & 15);
        int vr = (er > 64 ? 64 : er) * 232 + ks * 32 + (l >> 4) * 8;
        f16x8 bvh = *(const f16x8*)&sVh[vr];
        f16x8 bvl = *(const f16x8*)&sVl[vr];
        accO[et] = __builtin_amdgcn_mfma_f32_16x16x32_f16(ph,  bvh, accO[et], 0, 0, 0);
        accO[et] = __builtin_amdgcn_mfma_f32_16x16x32_f16(ph,  bvl, accO[et], 0, 0, 0);
        accO[et] = __builtin_amdgcn_mfma_f32_16x16x32_f16(plo, bvh, accO[et], 0, 0, 0);
      }
    }
    float ssq[4] = {0.f, 0.f, 0.f, 0.f};
    #pragma unroll
    for (int et = 0; et < 4; ++et)
      #pragma unroll
      for (int j = 0; j < 4; ++j) ssq[j] += accO[et][j] * accO[et][j];
    if ((l & 15) == 0) {
      #pragma unroll
      for (int j = 0; j < 4; ++j) ssq[j] += accO[4][j] * accO[4][j];
    }
    #pragma unroll
    for (int j = 0; j < 4; ++j)
      #pragma unroll
      for (int m = 8; m; m >>= 1) ssq[j] += __shfl_xor(ssq[j], m, 64);
    float rf4[4];
    #pragma unroll
    for (int j = 0; j < 4; ++j) {
      float o0 = __shfl(accO[0][j], (l & 48));
      rf4[j] = rsqrtf(fmaxf(2.f * o0 * o0 - ssq[j], 1e-6f));
    }
    #pragma unroll
    for (int et = 0; et < 5; ++et) {
      int e = et * 16 + (l & 15);
      if (e == 0 || e >= 65) continue;
      #pragma unroll
      for (int j = 0; j < 4; ++j) {
        int n = rt * 16 + (l >> 4) * 4 + j;
        if (n < 197)
          outa[((size_t)(b * 197 + n)) * 768 + hd * 64 + (e - 1)] = h_us(accO[et][j] * rf4[j]);
      }
    }
  }
}

// ---------------- lresnet ----------------
__global__ __launch_bounds__(256) void k_resnet(float* __restrict__ tok, const float* __restrict__ s,
                                                const float* __restrict__ wyp, int l) {
  __shared__ float red[8];
  __shared__ float bc[1];
  int r = blockIdx.x, t = threadIdx.x;
  float w = wyp[l];
  const float* sp = s + (size_t)r * 768;
  float* tp = tok + (size_t)r * 768;
  float s0 = sp[t], s1 = sp[256 + t], s2 = (t < 255) ? sp[512 + t] : 0.f;
  float qs = bsum(s0 * s0 + s1 * s1 + s2 * s2, red);
  float at = sqrtf(fmaxf(qs + 1.f, 1e-6f));
  float z0 = tp[1 + t] + w * s0;
  float z1 = tp[257 + t] + w * s1;
  float z2 = (t < 255) ? (tp[513 + t] + w * s2) : 0.f;
  float zs = bsum(z0 * z0 + z1 * z1 + z2 * z2, red);
  if (t == 0) bc[0] = tp[0] + w * at;
  __syncthreads();
  float zt = bc[0];
  float rf = rsqrtf(fmaxf(zt * zt - zs, 1e-6f));
  tp[1 + t] = z0 * rf; tp[257 + t] = z1 * rf; if (t < 255) tp[513 + t] = z2 * rf;
  if (t == 0) tp[0] = zt * rf;
}

// ---------------- final lorentz layernorm ----------------
__global__ __launch_bounds__(256) void k_final_ln(const float* __restrict__ tok, const float* __restrict__ g,
                                                  const float* __restrict__ bb, float* __restrict__ out) {
  __shared__ float red[8];
  int r = blockIdx.x, t = threadIdx.x;
  const float* xp = tok + (size_t)r * 768;
  float v0 = xp[1 + t], v1 = xp[257 + t], v2 = (t < 255) ? xp[513 + t] : 0.f;
  float s = bsum(v0 + v1 + v2, red);
  float q = bsum(v0 * v0 + v1 * v1 + v2 * v2, red);
  float mu = s * (1.f / 767.f);
  float rstd = rsqrtf(fmaxf(q * (1.f / 767.f) - mu * mu, 0.f) + 1e-6f);
  float y0 = (v0 - mu) * rstd * g[t] + bb[t];
  float y1 = (v1 - mu) * rstd * g[256 + t] + bb[256 + t];
  float y2 = (t < 255) ? ((v2 - mu) * rstd * g[512 + t] + bb[512 + t]) : 0.f;
  float qq = bsum(y0 * y0 + y1 * y1 + y2 * y2, red);
  float* op = out + (size_t)r * 768;
  op[1 + t] = y0; op[257 + t] = y1; if (t < 255) op[513 + t] = y2;
  if (t == 0) op[0] = sqrtf(fmaxf(qq + 1.f, 1e-6f));
}

extern "C" void kernel_launch(void* const* d_in, const int* in_sizes, int n_in,
                              void* d_out, int out_size, void* d_ws, size_t ws_size,
                              hipStream_t stream) {
  const float* x     = (const float*)d_in[0];
  const float* cls_s = (const float*)d_in[1];
  const float* Wp    = (const float*)d_in[2];
  const float* ln1g  = (const float*)d_in[3];
  const float* ln1b  = (const float*)d_in[4];
  const float* Wq    = (const float*)d_in[5];
  const float* Wk    = (const float*)d_in[6];
  const float* Wv    = (const float*)d_in[7];
  const float* Wo    = (const float*)d_in[8];
  const float* ln2g  = (const float*)d_in[9];
  const float* ln2b  = (const float*)d_in[10];
  const float* W1    = (const float*)d_in[11];
  const float* W2    = (const float*)d_in[12];
  const float* W3    = (const float*)d_in[13];
  const float* wy1   = (const float*)d_in[14];
  const float* wy2   = (const float*)d_in[15];
  const float* lnfg  = (const float*)d_in[16];
  const float* lnfb  = (const float*)d_in[17];

  if (ws_size < B_END) return;

  char* ws = (char*)d_ws;
  float*  cosb   = (float*)(ws + B_COS);
  float*  sinb   = (float*)(ws + B_SIN);
  ushort* wpt    = (ushort*)(ws + B_WPT);
  ushort* apatch = (ushort*)(ws + B_APATCH);
  ushort* wqkvt  = (ushort*)(ws + B_WQKVT);
  ushort* wot    = (ushort*)(ws + B_WOT);
  ushort* w12t   = (ushort*)(ws + B_W12T);
  ushort* w3t    = (ushort*)(ws + B_W3T);
  float*  tok    = (float*)(ws + B_TOK);
  ushort* acta   = (ushort*)(ws + B_ACTA);
  ushort* actb   = (ushort*)(ws + B_ACTB);
  float*  gout   = (float*)(ws + B_GOUT);
  ushort* qbuf   = (ushort*)(ws + B_QB);
  ushort* kbuf   = (ushort*)(ws + B_KB);
  ushort* vtb    = (ushort*)(ws + B_VT);
  float*  qtb    = (float*)(ws + B_QTB);
  float*  ktb    = (float*)(ws + B_KTB);

  hipMemsetAsync(qbuf, 0, QELE * 4, stream);
  hipMemsetAsync(kbuf, 0, QELE * 4, stream);
  hipMemsetAsync(vtb,  0, VELE * 4, stream);
  hipMemsetAsync(qtb,  0, (size_t)384 * 208 * 4, stream);
  hipMemsetAsync(ktb,  0, (size_t)384 * 208 * 4, stream);

  k_rope_tab<<<25, 256, 0, stream>>>(cosb, sinb);
  k_tpose<<<32 * 24, 256, 0, stream>>>(Wp, wpt, 1024, 767, 32, 1024);
  k_im2col<<<CONVM, 256, 0, stream>>>(x, apatch);
  k_gemmh<0><<<dim3(49, 6), 256, 0, stream>>>(apatch, wpt, gout, nullptr, 768, 1024);
  k_build_tok<<<NTOK, 256, 0, stream>>>(gout, cls_s, tok);

  for (int l = 0; l < NLAYER; ++l) {
    k_wprep<<<6912, 256, 0, stream>>>(Wq + (size_t)l * 767 * 768, Wk + (size_t)l * 767 * 768,
                                      Wv + (size_t)l * 767 * 768, Wo + (size_t)l * 768 * 767,
                                      W1 + (size_t)l * 767 * 2048, W2 + (size_t)l * 767 * 2048,
                                      W3 + (size_t)l * 2048 * 767, wqkvt, wot, w12t, w3t);

    k_ln<<<NTOK, 256, 0, stream>>>(tok, ln1g + (size_t)l * 767, ln1b + (size_t)l * 767, acta);
    k_gemmh<0><<<dim3(50, 18), 256, 0, stream>>>(acta, wqkvt, gout, nullptr, 2304, 768);
    k_qkvpost<<<NTOK, 384, 0, stream>>>(gout, cosb, sinb, qbuf, kbuf, vtb, qtb, ktb);
    k_attn<<<dim3(2, 384), 128, 0, stream>>>(qbuf, qtb, kbuf, ktb, vtb, acta);
    k_gemmh<0><<<dim3(50, 6), 256, 0, stream>>>(acta, wot, gout, nullptr, 768, 768);
    k_resnet<<<NTOK, 256, 0, stream>>>(tok, gout, wy1, l);

    k_ln<<<NTOK, 256, 0, stream>>>(tok, ln2g + (size_t)l * 767, ln2b + (size_t)l * 767, acta);
    k_gemmh<1><<<dim3(50, 32), 256, 0, stream>>>(acta, w12t, nullptr, actb, 4096, 768);
    k_gemmh<0><<<dim3(50, 6), 256, 0, stream>>>(actb, w3t, gout, nullptr, 768, 2048);
    k_resnet<<<NTOK, 256, 0, stream>>>(tok, gout, wy2, l);
  }

  k_final_ln<<<NTOK, 256, 0, stream>>>(tok, lnfg, lnfb, (float*)d_out);
}

// Round 6
// 3628.764 us; speedup vs baseline: 6.4416x; 1.3467x over previous
//
#include <hip/hip_runtime.h>
#include <hip/hip_bf16.h>

typedef __attribute__((ext_vector_type(8))) short short8;
typedef __attribute__((ext_vector_type(4))) float f32x4;
typedef _Float16 f16x8 __attribute__((ext_vector_type(8)));

#define NLAYER 12
#define NTOK   6304
#define MPAD   6400
#define CONVM  6272

#define QELE     ((size_t)384*208*64)
#define VELE     ((size_t)384*80*232)

static constexpr size_t AL(size_t x){ return (x + 511) & ~(size_t)511; }
static constexpr size_t B_COS    = 0;
static constexpr size_t B_SIN    = AL(B_COS    + (size_t)197*32*4);
static constexpr size_t B_WPT    = AL(B_SIN    + (size_t)197*32*4);
static constexpr size_t B_APATCH = AL(B_WPT    + (size_t)768*1024*2);
static constexpr size_t B_WQKVT  = AL(B_APATCH + (size_t)CONVM*1024*2);
static constexpr size_t B_WOT    = AL(B_WQKVT  + (size_t)2304*768*2);
static constexpr size_t B_W12T   = AL(B_WOT    + (size_t)768*768*2);
static constexpr size_t B_W3T    = AL(B_W12T   + (size_t)4096*768*2);
static constexpr size_t B_TOK    = AL(B_W3T    + (size_t)768*2048*2);
static constexpr size_t B_ACTA   = AL(B_TOK    + (size_t)NTOK*768*4);
static constexpr size_t B_ACTB   = AL(B_ACTA   + (size_t)MPAD*768*2);
static constexpr size_t B_GOUT   = AL(B_ACTB   + (size_t)MPAD*2048*2);
static constexpr size_t B_QB     = AL(B_GOUT   + (size_t)MPAD*2304*4);
static constexpr size_t B_KB     = AL(B_QB     + QELE*2);
static constexpr size_t B_VT     = AL(B_KB     + QELE*2);
static constexpr size_t B_QTB    = AL(B_VT     + VELE*2);
static constexpr size_t B_KTB    = AL(B_QTB    + (size_t)384*208*4);
static constexpr size_t B_END    = AL(B_KTB    + (size_t)384*208*4);

typedef __attribute__((address_space(1))) unsigned int gu32;
typedef __attribute__((address_space(3))) unsigned int lu32;
__device__ __forceinline__ void gld16(const void* g, void* l) {
  __builtin_amdgcn_global_load_lds((const gu32*)g, (lu32*)l, 16, 0, 0);
}

// ---------------- helpers ----------------
__device__ __forceinline__ float bsum(float v, float* red) {
  #pragma unroll
  for (int m = 32; m; m >>= 1) v += __shfl_xor(v, m, 64);
  __syncthreads();
  if ((threadIdx.x & 63) == 0) red[threadIdx.x >> 6] = v;
  __syncthreads();
  return red[0] + red[1] + red[2] + red[3];
}

__device__ __forceinline__ ushort h_us(float v) {
  _Float16 h = (_Float16)v;
  return *(ushort*)&h;
}

// ---------------- RoPE tables ----------------
__global__ void k_rope_tab(float* __restrict__ cosb, float* __restrict__ sinb) {
  int idx = blockIdx.x * 256 + threadIdx.x;
  if (idx >= 197 * 32) return;
  int p = idx >> 5, j = idx & 31;
  float cv, sv;
  if (p == 0) { cv = 1.f; sv = 0.f; }
  else {
    int pp = p - 1;
    int iy = pp / 14, ix = pp - iy * 14;
    int pos = (j < 16) ? iy : ix;
    int f   = (j < 16) ? j  : j - 16;
    float inv = powf(100.f, -(float)f / 16.f);
    float a = (float)pos * inv;
    cv = cosf(a); sv = sinf(a);
  }
  cosb[idx] = cv; sinb[idx] = sv;
}

// ---------------- LDS-tiled transpose f32 [K][N] -> fp16 dst[n][k], zero-pad ----------------
__device__ __forceinline__ void tpose_tile(const float* __restrict__ src, ushort* __restrict__ dst,
                                           int K, int N, int ldd, int imode, int tk, int tn) {
  __shared__ float ts[32][33];
  int t = threadIdx.x;
  int rr = t >> 3, c4 = (t & 7) * 4;
  int k0 = tk * 32, n0 = tn * 32;
  #pragma unroll
  for (int e = 0; e < 4; ++e) {
    int k = k0 + rr, n = n0 + c4 + e;
    ts[rr][c4 + e] = (k < K && n < N) ? src[(size_t)k * N + n] : 0.f;
  }
  __syncthreads();
  int c = n0 + rr;
  int drow = (imode == 0) ? c : (16 * (c >> 3) + (c & 7) + (imode == 2 ? 8 : 0));
  ushort4 o;
  #pragma unroll
  for (int e = 0; e < 4; ++e) {
    _Float16 hv = (_Float16)ts[c4 + e][rr];
    ((ushort*)&o)[e] = *(ushort*)&hv;
  }
  *(ushort4*)&dst[(size_t)drow * ldd + k0 + c4] = o;
}

__global__ __launch_bounds__(256) void k_tpose(const float* __restrict__ src, ushort* __restrict__ dst,
                                               int K, int N, int ktiles, int ldd) {
  int tk = blockIdx.x % ktiles, tn = blockIdx.x / ktiles;
  tpose_tile(src, dst, K, N, ldd, 0, tk, tn);
}

__global__ __launch_bounds__(256) void k_wprep(const float* __restrict__ Wq, const float* __restrict__ Wk,
                                               const float* __restrict__ Wv, const float* __restrict__ Wo,
                                               const float* __restrict__ W1, const float* __restrict__ W2,
                                               const float* __restrict__ W3,
                                               ushort* __restrict__ wqkvt, ushort* __restrict__ wot,
                                               ushort* __restrict__ w12t, ushort* __restrict__ w3t) {
  int tile = blockIdx.x;
  const float* src; ushort* dst;
  int K, N, ktiles, ldd, imode = 0, tl;
  if (tile < 2304) {
    int jb = tile / 576; tl = tile % 576;
    ktiles = 24; ldd = 768;
    if (jb == 0)      { src = Wq; dst = wqkvt;                 K = 767; N = 768; }
    else if (jb == 1) { src = Wk; dst = wqkvt + 768 * 768;     K = 767; N = 768; }
    else if (jb == 2) { src = Wv; dst = wqkvt + 2 * 768 * 768; K = 767; N = 768; }
    else              { src = Wo; dst = wot;                   K = 768; N = 767; }
  } else if (tile < 5376) {
    int jb = (tile - 2304) / 1536; tl = (tile - 2304) % 1536;
    ktiles = 24; ldd = 768; K = 767; N = 2048; dst = w12t;
    src = jb ? W2 : W1; imode = jb ? 2 : 1;
  } else {
    tl = tile - 5376; ktiles = 64; ldd = 2048; K = 2048; N = 767; src = W3; dst = w3t;
  }
  int tk = tl % ktiles, tn = tl / ktiles;
  tpose_tile(src, dst, K, N, ldd, imode, tk, tn);
}

// ---------------- im2col with Lorentz time channel, fp16 ----------------
__global__ __launch_bounds__(256) void k_im2col(const float* __restrict__ x, ushort* __restrict__ ap) {
  int r = blockIdx.x;
  int b = r / 196, pi = r - b * 196;
  int py = pi / 14, px = pi - py * 14;
  int t = threadIdx.x;
  int ph = t >> 4, pw = t & 15;
  int iy = py * 16 + ph, ix = px * 16 + pw;
  size_t base = ((size_t)b * 3 * 224 + iy) * 224 + ix;
  float x0 = x[base];
  float x1 = x[base + 224 * 224];
  float x2 = x[base + 2 * 224 * 224];
  float tv = sqrtf(fmaxf(x0 * x0 + x1 * x1 + x2 * x2 + 1.f, 1e-6f));
  size_t o = (size_t)r * 1024 + t * 4;
  ap[o] = h_us(tv); ap[o + 1] = h_us(x0); ap[o + 2] = h_us(x1); ap[o + 3] = h_us(x2);
}

// ---------------- fp16 GEMM: C[M][N] = A[M][K] * Bt[N][K]^T ; SILU=1: fused silu epilogue ----------------
template<int SILU>
__global__ __launch_bounds__(256) void k_gemmh(const ushort* __restrict__ A, const ushort* __restrict__ Bt,
                                               float* __restrict__ C, ushort* __restrict__ H,
                                               int N, int K) {
  __shared__ ushort sA[128 * 64];
  __shared__ ushort sB[128 * 64];
  int m0 = blockIdx.x * 128, n0 = blockIdx.y * 128;
  int t = threadIdx.x;
  int w = t >> 6, l = t & 63;
  int wm = (w >> 1) * 64, wn = (w & 1) * 64;
  int lr = l & 15, hi = l >> 4;
  f32x4 acc[4][4] = {};
  for (int k0 = 0; k0 < K; k0 += 64) {
    #pragma unroll
    for (int i = 0; i < 4; ++i) {
      int fl = i * 256 + t;
      int r = fl >> 3, c = fl & 7;
      int cs = c ^ (r & 7);
      gld16(&A[(size_t)(m0 + r) * K + k0 + cs * 8], &sA[fl * 8]);
      gld16(&Bt[(size_t)(n0 + r) * K + k0 + cs * 8], &sB[fl * 8]);
    }
    __syncthreads();
    f16x8 af[4][2], bfr[4][2];
    #pragma unroll
    for (int q = 0; q < 4; ++q) {
      int ra = wm + q * 16 + lr, rb = wn + q * 16 + lr;
      #pragma unroll
      for (int h = 0; h < 2; ++h) {
        af[q][h]  = *(const f16x8*)&sA[ra * 64 + ((h * 4 + hi) ^ (ra & 7)) * 8];
        bfr[q][h] = *(const f16x8*)&sB[rb * 64 + ((h * 4 + hi) ^ (rb & 7)) * 8];
      }
    }
    #pragma unroll
    for (int mi = 0; mi < 4; ++mi)
      #pragma unroll
      for (int ni = 0; ni < 4; ++ni) {
        acc[mi][ni] = __builtin_amdgcn_mfma_f32_16x16x32_f16(af[mi][0], bfr[ni][0], acc[mi][ni], 0, 0, 0);
        acc[mi][ni] = __builtin_amdgcn_mfma_f32_16x16x32_f16(af[mi][1], bfr[ni][1], acc[mi][ni], 0, 0, 0);
      }
    __syncthreads();
  }
  int rr = hi * 4, cc = lr;
  if (SILU) {
    #pragma unroll
    for (int mi = 0; mi < 4; ++mi)
      #pragma unroll
      for (int ni = 0; ni < 4; ++ni) {
        int g = (n0 + wn + ni * 16) >> 4;
        #pragma unroll
        for (int j = 0; j < 4; ++j) {
          float v = acc[mi][ni][j];
          float p = __shfl_xor(v, 8);
          float u1 = (cc < 8) ? v : p;
          float u2 = (cc < 8) ? p : v;
          float hv = u1 / (1.f + __expf(-u1)) * u2;
          if (cc < 8)
            H[(size_t)(m0 + wm + mi * 16 + rr + j) * 2048 + g * 8 + cc] = h_us(hv);
        }
      }
  } else {
    #pragma unroll
    for (int mi = 0; mi < 4; ++mi)
      #pragma unroll
      for (int ni = 0; ni < 4; ++ni)
        #pragma unroll
        for (int j = 0; j < 4; ++j)
          C[(size_t)(m0 + wm + mi * 16 + rr + j) * N + (n0 + wn + ni * 16 + cc)] = acc[mi][ni][j];
  }
}

// ---------------- build tokens ----------------
__global__ __launch_bounds__(256) void k_build_tok(const float* __restrict__ feat, const float* __restrict__ cls,
                                                   float* __restrict__ tok) {
  __shared__ float red[8];
  int r = blockIdx.x;
  int b = r / 197, i = r - b * 197;
  int t = threadIdx.x;
  const float* src = (i == 0) ? cls : (feat + (size_t)(b * 196 + i - 1) * 768);
  float v0 = src[t], v1 = src[256 + t], v2 = (t < 255) ? src[512 + t] : 0.f;
  float qs = bsum(v0 * v0 + v1 * v1 + v2 * v2, red);
  float* tp = tok + (size_t)r * 768;
  if (t == 0) tp[0] = sqrtf(fmaxf(qs + 1.f, 1e-6f));
  tp[1 + t] = v0; tp[257 + t] = v1; if (t < 255) tp[513 + t] = v2;
}

// ---------------- lorentz layernorm -> fp16 (pad col 767 = 0) ----------------
__global__ __launch_bounds__(256) void k_ln(const float* __restrict__ tok, const float* __restrict__ g,
                                            const float* __restrict__ bb, ushort* __restrict__ out) {
  __shared__ float red[8];
  int r = blockIdx.x, t = threadIdx.x;
  const float* xp = tok + (size_t)r * 768;
  float v0 = xp[1 + t], v1 = xp[257 + t], v2 = (t < 255) ? xp[513 + t] : 0.f;
  float s = bsum(v0 + v1 + v2, red);
  float q = bsum(v0 * v0 + v1 * v1 + v2 * v2, red);
  float mu = s * (1.f / 767.f);
  float rstd = rsqrtf(fmaxf(q * (1.f / 767.f) - mu * mu, 0.f) + 1e-6f);
  size_t o = (size_t)r * 768;
  out[o + t]       = h_us((v0 - mu) * rstd * g[t]       + bb[t]);
  out[o + 256 + t] = h_us((v1 - mu) * rstd * g[256 + t] + bb[256 + t]);
  if (t < 255)
    out[o + 512 + t] = h_us((v2 - mu) * rstd * g[512 + t] + bb[512 + t]);
  if (t == 255) out[o + 767] = 0;
}

// ---------------- QKV post: RoPE, times, fp16 layouts ----------------
__global__ __launch_bounds__(384) void k_qkvpost(const float* __restrict__ qkv, const float* __restrict__ cosb,
                                                 const float* __restrict__ sinb,
                                                 ushort* __restrict__ qbuf, ushort* __restrict__ kbuf,
                                                 ushort* __restrict__ vtb,
                                                 float* __restrict__ qtb, float* __restrict__ ktb) {
  int r = blockIdx.x;
  int b = r / 197, n = r - b * 197;
  int t = threadIdx.x;
  int h = t >> 5, j = t & 31;
  const float* row = qkv + (size_t)r * 2304;
  float q0 = row[h * 64 + 2 * j],        q1 = row[h * 64 + 2 * j + 1];
  float k0 = row[768 + h * 64 + 2 * j],  k1 = row[768 + h * 64 + 2 * j + 1];
  float v0 = row[1536 + h * 64 + 2 * j], v1 = row[1536 + h * 64 + 2 * j + 1];
  float c = cosb[n * 32 + j], sn = sinb[n * 32 + j];
  float qa = q0 * c - q1 * sn, qc = q0 * sn + q1 * c;
  float ka = k0 * c - k1 * sn, kc = k0 * sn + k1 * c;
  float sq = q0 * q0 + q1 * q1, sk = k0 * k0 + k1 * k1, sv = v0 * v0 + v1 * v1;
  #pragma unroll
  for (int m = 16; m; m >>= 1) {
    sq += __shfl_xor(sq, m, 64);
    sk += __shfl_xor(sk, m, 64);
    sv += __shfl_xor(sv, m, 64);
  }
  int bh = b * 12 + h;
  size_t qo = ((size_t)bh * 208 + n) * 64 + 2 * j;
  qbuf[qo] = h_us(qa); qbuf[qo + 1] = h_us(qc);
  kbuf[qo] = h_us(ka); kbuf[qo + 1] = h_us(kc);
  size_t vo = (size_t)bh * 80 * 232;
  vtb[vo + (size_t)(1 + 2 * j) * 232 + n] = h_us(v0);
  vtb[vo + (size_t)(2 + 2 * j) * 232 + n] = h_us(v1);
  if (j == 0) {
    qtb[(size_t)bh * 208 + n] = sqrtf(fmaxf(sq + 1.f, 1e-6f));
    ktb[(size_t)bh * 208 + n] = sqrtf(fmaxf(sk + 1.f, 1e-6f));
    vtb[vo + n] = h_us(sqrtf(fmaxf(sv + 1.f, 1e-6f)));
  }
}

// ---------------- MFMA attention, fp16 single: QK^T -> fp16 P (LDS) -> PV (V from L2) -> project ----------------
__global__ __launch_bounds__(128) void k_attn(const ushort* __restrict__ qbuf,
                                              const float* __restrict__ qtb,
                                              const ushort* __restrict__ kbuf,
                                              const float* __restrict__ ktb,
                                              const ushort* __restrict__ vtb,
                                              ushort* __restrict__ outa) {
  __shared__ ushort sK[208 * 72];       // rows padded 64->72 (2-way banks)
  __shared__ ushort sP[2][16 * 248];    // per-wave fp16 P, stride 248 (2-way banks, 16B aligned)
  __shared__ float  sKt[208];
  int half = blockIdx.x, bh = blockIdx.y;
  int b = bh / 12, hd = bh - b * 12;
  int t = threadIdx.x, w = t >> 6, l = t & 63;
  const ushort* kg = kbuf + (size_t)bh * 208 * 64;
  for (int cks = t; cks < 1664; cks += 128) {
    int r = cks >> 3, c8 = (cks & 7) * 8;
    *(int4*)&sK[r * 72 + c8] = *(const int4*)&kg[r * 64 + c8];
  }
  for (int i = t; i < 208; i += 128) sKt[i] = ktb[(size_t)bh * 208 + i];
  __syncthreads();
  const ushort* qg = qbuf + (size_t)bh * 208 * 64;
  const ushort* vg = vtb + (size_t)bh * 80 * 232;
  const float invs = 0.03608439182435161f;          // 1/sqrt(768)
  int rt0 = half ? 7 : 0, rt1 = half ? 13 : 7;
  int lr = l & 15, hi4 = l >> 4;
  ushort* pw = &sP[w][0];
  for (int rt = rt0 + w; rt < rt1; rt += 2) {
    int qrow = (rt * 16 + lr) * 64 + hi4 * 8;
    f16x8 q0 = *(const f16x8*)&qg[qrow];
    f16x8 q1 = *(const f16x8*)&qg[qrow + 32];
    float qt4[4];
    #pragma unroll
    for (int j = 0; j < 4; ++j) qt4[j] = qtb[(size_t)bh * 208 + rt * 16 + hi4 * 4 + j];
    f32x4 acc[13];
    #pragma unroll
    for (int nt = 0; nt < 13; ++nt) {
      int kr = (nt * 16 + lr) * 72 + hi4 * 8;
      f16x8 k0 = *(const f16x8*)&sK[kr];
      f16x8 k1 = *(const f16x8*)&sK[kr + 32];
      acc[nt] = (f32x4){0.f, 0.f, 0.f, 0.f};
      acc[nt] = __builtin_amdgcn_mfma_f32_16x16x32_f16(q0, k0, acc[nt], 0, 0, 0);
      acc[nt] = __builtin_amdgcn_mfma_f32_16x16x32_f16(q1, k1, acc[nt], 0, 0, 0);
    }
    float mx[4] = {-1e30f, -1e30f, -1e30f, -1e30f};
    #pragma unroll
    for (int nt = 0; nt < 13; ++nt) {
      int cI = nt * 16 + lr;
      float ktc = sKt[cI];
      bool valid = (cI < 197);
      #pragma unroll
      for (int j = 0; j < 4; ++j) {
        float s = (2.f + 2.f * (acc[nt][j] - qt4[j] * ktc)) * invs;
        acc[nt][j] = s;
        if (valid) mx[j] = fmaxf(mx[j], s);
      }
    }
    #pragma unroll
    for (int j = 0; j < 4; ++j)
      #pragma unroll
      for (int m = 8; m; m >>= 1) mx[j] = fmaxf(mx[j], __shfl_xor(mx[j], m, 64));
    #pragma unroll
    for (int nt = 0; nt < 14; ++nt) {
      int cI = nt * 16 + lr;
      #pragma unroll
      for (int j = 0; j < 4; ++j) {
        float p = (nt < 13 && cI < 197) ? __expf(acc[nt][j] - mx[j]) : 0.f;
        pw[(hi4 * 4 + j) * 248 + cI] = h_us(p);
      }
    }
    f32x4 accO[5];
    #pragma unroll
    for (int et = 0; et < 5; ++et) accO[et] = (f32x4){0.f, 0.f, 0.f, 0.f};
    #pragma unroll
    for (int ks = 0; ks < 7; ++ks) {
      f16x8 pa = *(const f16x8*)&pw[lr * 248 + ks * 32 + hi4 * 8];
      #pragma unroll
      for (int et = 0; et < 5; ++et) {
        int er = et * 16 + lr;
        f16x8 bv = *(const f16x8*)&vg[(er > 64 ? 64 : er) * 232 + ks * 32 + hi4 * 8];
        accO[et] = __builtin_amdgcn_mfma_f32_16x16x32_f16(pa, bv, accO[et], 0, 0, 0);
      }
    }
    float ssq[4] = {0.f, 0.f, 0.f, 0.f};
    #pragma unroll
    for (int et = 0; et < 4; ++et)
      #pragma unroll
      for (int j = 0; j < 4; ++j) ssq[j] += accO[et][j] * accO[et][j];
    if (lr == 0) {
      #pragma unroll
      for (int j = 0; j < 4; ++j) ssq[j] += accO[4][j] * accO[4][j];
    }
    #pragma unroll
    for (int j = 0; j < 4; ++j)
      #pragma unroll
      for (int m = 8; m; m >>= 1) ssq[j] += __shfl_xor(ssq[j], m, 64);
    float rf4[4];
    #pragma unroll
    for (int j = 0; j < 4; ++j) {
      float o0 = __shfl(accO[0][j], (l & 48));
      rf4[j] = rsqrtf(fmaxf(2.f * o0 * o0 - ssq[j], 1e-6f));
    }
    #pragma unroll
    for (int et = 0; et < 5; ++et) {
      int e = et * 16 + lr;
      if (e == 0 || e >= 65) continue;
      #pragma unroll
      for (int j = 0; j < 4; ++j) {
        int n = rt * 16 + hi4 * 4 + j;
        if (n < 197)
          outa[((size_t)(b * 197 + n)) * 768 + hd * 64 + (e - 1)] = h_us(accO[et][j] * rf4[j]);
      }
    }
  }
}

// ---------------- fused lresnet + lorentz layernorm ----------------
template<int FIN>
__global__ __launch_bounds__(256) void k_resnet_ln(float* __restrict__ tok, const float* __restrict__ s,
                                                   const float* __restrict__ wyp, int l,
                                                   const float* __restrict__ g, const float* __restrict__ bb,
                                                   ushort* __restrict__ out16, float* __restrict__ out32) {
  __shared__ float red[8];
  __shared__ float bc[1];
  int r = blockIdx.x, t = threadIdx.x;
  float w = wyp[l];
  const float* sp = s + (size_t)r * 768;
  float* tp = tok + (size_t)r * 768;
  float s0 = sp[t], s1 = sp[256 + t], s2 = (t < 255) ? sp[512 + t] : 0.f;
  float qs = bsum(s0 * s0 + s1 * s1 + s2 * s2, red);
  float at = sqrtf(fmaxf(qs + 1.f, 1e-6f));
  float z0 = tp[1 + t] + w * s0;
  float z1 = tp[257 + t] + w * s1;
  float z2 = (t < 255) ? (tp[513 + t] + w * s2) : 0.f;
  float zs = bsum(z0 * z0 + z1 * z1 + z2 * z2, red);
  if (t == 0) bc[0] = tp[0] + w * at;
  __syncthreads();
  float zt = bc[0];
  float rf = rsqrtf(fmaxf(zt * zt - zs, 1e-6f));
  float n0 = z0 * rf, n1 = z1 * rf, n2 = z2 * rf;
  tp[1 + t] = n0; tp[257 + t] = n1; if (t < 255) tp[513 + t] = n2;
  if (t == 0) tp[0] = zt * rf;
  float sm = bsum(n0 + n1 + n2, red);
  float sq = bsum(n0 * n0 + n1 * n1 + n2 * n2, red);
  float mu = sm * (1.f / 767.f);
  float rstd = rsqrtf(fmaxf(sq * (1.f / 767.f) - mu * mu, 0.f) + 1e-6f);
  float y0 = (n0 - mu) * rstd * g[t] + bb[t];
  float y1 = (n1 - mu) * rstd * g[256 + t] + bb[256 + t];
  float y2 = (t < 255) ? ((n2 - mu) * rstd * g[512 + t] + bb[512 + t]) : 0.f;
  if (FIN) {
    float qq = bsum(y0 * y0 + y1 * y1 + y2 * y2, red);
    float* op = out32 + (size_t)r * 768;
    op[1 + t] = y0; op[257 + t] = y1; if (t < 255) op[513 + t] = y2;
    if (t == 0) op[0] = sqrtf(fmaxf(qq + 1.f, 1e-6f));
  } else {
    size_t o = (size_t)r * 768;
    out16[o + t] = h_us(y0);
    out16[o + 256 + t] = h_us(y1);
    if (t < 255) out16[o + 512 + t] = h_us(y2);
    if (t == 255) out16[o + 767] = 0;
  }
}

extern "C" void kernel_launch(void* const* d_in, const int* in_sizes, int n_in,
                              void* d_out, int out_size, void* d_ws, size_t ws_size,
                              hipStream_t stream) {
  const float* x     = (const float*)d_in[0];
  const float* cls_s = (const float*)d_in[1];
  const float* Wp    = (const float*)d_in[2];
  const float* ln1g  = (const float*)d_in[3];
  const float* ln1b  = (const float*)d_in[4];
  const float* Wq    = (const float*)d_in[5];
  const float* Wk    = (const float*)d_in[6];
  const float* Wv    = (const float*)d_in[7];
  const float* Wo    = (const float*)d_in[8];
  const float* ln2g  = (const float*)d_in[9];
  const float* ln2b  = (const float*)d_in[10];
  const float* W1    = (const float*)d_in[11];
  const float* W2    = (const float*)d_in[12];
  const float* W3    = (const float*)d_in[13];
  const float* wy1   = (const float*)d_in[14];
  const float* wy2   = (const float*)d_in[15];
  const float* lnfg  = (const float*)d_in[16];
  const float* lnfb  = (const float*)d_in[17];

  if (ws_size < B_END) return;

  char* ws = (char*)d_ws;
  float*  cosb   = (float*)(ws + B_COS);
  float*  sinb   = (float*)(ws + B_SIN);
  ushort* wpt    = (ushort*)(ws + B_WPT);
  ushort* apatch = (ushort*)(ws + B_APATCH);
  ushort* wqkvt  = (ushort*)(ws + B_WQKVT);
  ushort* wot    = (ushort*)(ws + B_WOT);
  ushort* w12t   = (ushort*)(ws + B_W12T);
  ushort* w3t    = (ushort*)(ws + B_W3T);
  float*  tok    = (float*)(ws + B_TOK);
  ushort* acta   = (ushort*)(ws + B_ACTA);
  ushort* actb   = (ushort*)(ws + B_ACTB);
  float*  gout   = (float*)(ws + B_GOUT);
  ushort* qbuf   = (ushort*)(ws + B_QB);
  ushort* kbuf   = (ushort*)(ws + B_KB);
  ushort* vtb    = (ushort*)(ws + B_VT);
  float*  qtb    = (float*)(ws + B_QTB);
  float*  ktb    = (float*)(ws + B_KTB);

  // only V pads must be zero (P=0 x NaN would poison PV MFMA); K/Q pads are masked.
  hipMemsetAsync(vtb, 0, VELE * 2, stream);

  k_rope_tab<<<25, 256, 0, stream>>>(cosb, sinb);
  k_tpose<<<32 * 24, 256, 0, stream>>>(Wp, wpt, 1024, 767, 32, 1024);
  k_im2col<<<CONVM, 256, 0, stream>>>(x, apatch);
  k_gemmh<0><<<dim3(49, 6), 256, 0, stream>>>(apatch, wpt, gout, nullptr, 768, 1024);
  k_build_tok<<<NTOK, 256, 0, stream>>>(gout, cls_s, tok);
  k_ln<<<NTOK, 256, 0, stream>>>(tok, ln1g, ln1b, acta);

  for (int l = 0; l < NLAYER; ++l) {
    k_wprep<<<6912, 256, 0, stream>>>(Wq + (size_t)l * 767 * 768, Wk + (size_t)l * 767 * 768,
                                      Wv + (size_t)l * 767 * 768, Wo + (size_t)l * 768 * 767,
                                      W1 + (size_t)l * 767 * 2048, W2 + (size_t)l * 767 * 2048,
                                      W3 + (size_t)l * 2048 * 767, wqkvt, wot, w12t, w3t);

    k_gemmh<0><<<dim3(50, 18), 256, 0, stream>>>(acta, wqkvt, gout, nullptr, 2304, 768);
    k_qkvpost<<<NTOK, 384, 0, stream>>>(gout, cosb, sinb, qbuf, kbuf, vtb, qtb, ktb);
    k_attn<<<dim3(2, 384), 128, 0, stream>>>(qbuf, qtb, kbuf, ktb, vtb, acta);
    k_gemmh<0><<<dim3(50, 6), 256, 0, stream>>>(acta, wot, gout, nullptr, 768, 768);
    k_resnet_ln<0><<<NTOK, 256, 0, stream>>>(tok, gout, wy1, l,
                                             ln2g + (size_t)l * 767, ln2b + (size_t)l * 767, acta, nullptr);

    k_gemmh<1><<<dim3(50, 32), 256, 0, stream>>>(acta, w12t, nullptr, actb, 4096, 768);
    k_gemmh<0><<<dim3(50, 6), 256, 0, stream>>>(actb, w3t, gout, nullptr, 768, 2048);
    if (l < NLAYER - 1)
      k_resnet_ln<0><<<NTOK, 256, 0, stream>>>(tok, gout, wy2, l,
                                               ln1g + (size_t)(l + 1) * 767, ln1b + (size_t)(l + 1) * 767,
                                               acta, nullptr);
    else
      k_resnet_ln<1><<<NTOK, 256, 0, stream>>>(tok, gout, wy2, l, lnfg, lnfb, nullptr, (float*)d_out);
  }
}

// Round 7
// 3338.113 us; speedup vs baseline: 7.0025x; 1.0871x over previous
//
#include <hip/hip_runtime.h>
#include <hip/hip_bf16.h>

typedef __attribute__((ext_vector_type(8))) short short8;
typedef __attribute__((ext_vector_type(4))) float f32x4;
typedef _Float16 f16x8 __attribute__((ext_vector_type(8)));

#define NLAYER 12
#define NTOK   6304
#define MPAD   6400
#define CONVM  6272

#define QELE     ((size_t)384*208*64)
#define VELE     ((size_t)384*80*232)

static constexpr size_t AL(size_t x){ return (x + 511) & ~(size_t)511; }
static constexpr size_t B_COS    = 0;
static constexpr size_t B_SIN    = AL(B_COS    + (size_t)197*32*4);
static constexpr size_t B_WPT    = AL(B_SIN    + (size_t)197*32*4);
static constexpr size_t B_APATCH = AL(B_WPT    + (size_t)768*1024*2);
static constexpr size_t B_WQKVT  = AL(B_APATCH + (size_t)CONVM*1024*2);
static constexpr size_t B_WOT    = AL(B_WQKVT  + (size_t)2304*768*2);
static constexpr size_t B_W12T   = AL(B_WOT    + (size_t)768*768*2);
static constexpr size_t B_W3T    = AL(B_W12T   + (size_t)4096*768*2);
static constexpr size_t B_TOK    = AL(B_W3T    + (size_t)768*2048*2);
static constexpr size_t B_ACTA   = AL(B_TOK    + (size_t)NTOK*768*4);
static constexpr size_t B_ACTB   = AL(B_ACTA   + (size_t)MPAD*768*2);
static constexpr size_t B_GOUT   = AL(B_ACTB   + (size_t)MPAD*2048*2);
static constexpr size_t B_QB     = AL(B_GOUT   + (size_t)MPAD*2304*4);
static constexpr size_t B_KB     = AL(B_QB     + QELE*2);
static constexpr size_t B_VT     = AL(B_KB     + QELE*2);
static constexpr size_t B_QTB    = AL(B_VT     + VELE*2);
static constexpr size_t B_KTB    = AL(B_QTB    + (size_t)384*208*4);
static constexpr size_t B_END    = AL(B_KTB    + (size_t)384*208*4);

typedef __attribute__((address_space(1))) unsigned int gu32;
typedef __attribute__((address_space(3))) unsigned int lu32;
__device__ __forceinline__ void gld16(const void* g, void* l) {
  __builtin_amdgcn_global_load_lds((const gu32*)g, (lu32*)l, 16, 0, 0);
}

// ---------------- helpers ----------------
__device__ __forceinline__ float bsum(float v, float* red) {
  #pragma unroll
  for (int m = 32; m; m >>= 1) v += __shfl_xor(v, m, 64);
  __syncthreads();
  if ((threadIdx.x & 63) == 0) red[threadIdx.x >> 6] = v;
  __syncthreads();
  return red[0] + red[1] + red[2] + red[3];
}

__device__ __forceinline__ ushort h_us(float v) {
  _Float16 h = (_Float16)v;
  return *(ushort*)&h;
}
__device__ __forceinline__ float us_f(ushort u) {
  return (float)*(const _Float16*)&u;
}

// ---------------- RoPE tables ----------------
__global__ void k_rope_tab(float* __restrict__ cosb, float* __restrict__ sinb) {
  int idx = blockIdx.x * 256 + threadIdx.x;
  if (idx >= 197 * 32) return;
  int p = idx >> 5, j = idx & 31;
  float cv, sv;
  if (p == 0) { cv = 1.f; sv = 0.f; }
  else {
    int pp = p - 1;
    int iy = pp / 14, ix = pp - iy * 14;
    int pos = (j < 16) ? iy : ix;
    int f   = (j < 16) ? j  : j - 16;
    float inv = powf(100.f, -(float)f / 16.f);
    float a = (float)pos * inv;
    cv = cosf(a); sv = sinf(a);
  }
  cosb[idx] = cv; sinb[idx] = sv;
}

// ---------------- LDS-tiled transpose f32 [K][N] -> fp16 dst[n][k], zero-pad ----------------
__device__ __forceinline__ void tpose_tile(const float* __restrict__ src, ushort* __restrict__ dst,
                                           int K, int N, int ldd, int imode, int tk, int tn) {
  __shared__ float ts[32][33];
  int t = threadIdx.x;
  int rr = t >> 3, c4 = (t & 7) * 4;
  int k0 = tk * 32, n0 = tn * 32;
  #pragma unroll
  for (int e = 0; e < 4; ++e) {
    int k = k0 + rr, n = n0 + c4 + e;
    ts[rr][c4 + e] = (k < K && n < N) ? src[(size_t)k * N + n] : 0.f;
  }
  __syncthreads();
  int c = n0 + rr;
  int drow = (imode == 0) ? c : (16 * (c >> 3) + (c & 7) + (imode == 2 ? 8 : 0));
  ushort4 o;
  #pragma unroll
  for (int e = 0; e < 4; ++e) {
    _Float16 hv = (_Float16)ts[c4 + e][rr];
    ((ushort*)&o)[e] = *(ushort*)&hv;
  }
  *(ushort4*)&dst[(size_t)drow * ldd + k0 + c4] = o;
}

__global__ __launch_bounds__(256) void k_tpose(const float* __restrict__ src, ushort* __restrict__ dst,
                                               int K, int N, int ktiles, int ldd) {
  int tk = blockIdx.x % ktiles, tn = blockIdx.x / ktiles;
  tpose_tile(src, dst, K, N, ldd, 0, tk, tn);
}

__global__ __launch_bounds__(256) void k_wprep(const float* __restrict__ Wq, const float* __restrict__ Wk,
                                               const float* __restrict__ Wv, const float* __restrict__ Wo,
                                               const float* __restrict__ W1, const float* __restrict__ W2,
                                               const float* __restrict__ W3,
                                               ushort* __restrict__ wqkvt, ushort* __restrict__ wot,
                                               ushort* __restrict__ w12t, ushort* __restrict__ w3t) {
  int tile = blockIdx.x;
  const float* src; ushort* dst;
  int K, N, ktiles, ldd, imode = 0, tl;
  if (tile < 2304) {
    int jb = tile / 576; tl = tile % 576;
    ktiles = 24; ldd = 768;
    if (jb == 0)      { src = Wq; dst = wqkvt;                 K = 767; N = 768; }
    else if (jb == 1) { src = Wk; dst = wqkvt + 768 * 768;     K = 767; N = 768; }
    else if (jb == 2) { src = Wv; dst = wqkvt + 2 * 768 * 768; K = 767; N = 768; }
    else              { src = Wo; dst = wot;                   K = 768; N = 767; }
  } else if (tile < 5376) {
    int jb = (tile - 2304) / 1536; tl = (tile - 2304) % 1536;
    ktiles = 24; ldd = 768; K = 767; N = 2048; dst = w12t;
    src = jb ? W2 : W1; imode = jb ? 2 : 1;
  } else {
    tl = tile - 5376; ktiles = 64; ldd = 2048; K = 2048; N = 767; src = W3; dst = w3t;
  }
  int tk = tl % ktiles, tn = tl / ktiles;
  tpose_tile(src, dst, K, N, ldd, imode, tk, tn);
}

// ---------------- im2col with Lorentz time channel, fp16 ----------------
__global__ __launch_bounds__(256) void k_im2col(const float* __restrict__ x, ushort* __restrict__ ap) {
  int r = blockIdx.x;
  int b = r / 196, pi = r - b * 196;
  int py = pi / 14, px = pi - py * 14;
  int t = threadIdx.x;
  int ph = t >> 4, pw = t & 15;
  int iy = py * 16 + ph, ix = px * 16 + pw;
  size_t base = ((size_t)b * 3 * 224 + iy) * 224 + ix;
  float x0 = x[base];
  float x1 = x[base + 224 * 224];
  float x2 = x[base + 2 * 224 * 224];
  float tv = sqrtf(fmaxf(x0 * x0 + x1 * x1 + x2 * x2 + 1.f, 1e-6f));
  size_t o = (size_t)r * 1024 + t * 4;
  ap[o] = h_us(tv); ap[o + 1] = h_us(x0); ap[o + 2] = h_us(x1); ap[o + 3] = h_us(x2);
}

// ---------------- fp16 GEMM. MODE 0: f32 C; 1: fused silu -> fp16 H; 2: fused QKV epilogue; 3: fp16 H ----------------
template<int MODE>
__global__ __launch_bounds__(256) void k_gemmh(const ushort* __restrict__ A, const ushort* __restrict__ Bt,
                                               float* __restrict__ C, ushort* __restrict__ H,
                                               int N, int K,
                                               ushort* __restrict__ qbuf, ushort* __restrict__ kbuf,
                                               ushort* __restrict__ vtb,
                                               float* __restrict__ qtb, float* __restrict__ ktb,
                                               const float* __restrict__ cosb, const float* __restrict__ sinb) {
  __shared__ ushort sA[128 * 64];
  __shared__ ushort sB[128 * 64];
  int m0 = blockIdx.x * 128, n0 = blockIdx.y * 128;
  int t = threadIdx.x;
  int w = t >> 6, l = t & 63;
  int wm = (w >> 1) * 64, wn = (w & 1) * 64;
  int lr = l & 15, hi = l >> 4;
  f32x4 acc[4][4] = {};
  for (int k0 = 0; k0 < K; k0 += 64) {
    #pragma unroll
    for (int i = 0; i < 4; ++i) {
      int fl = i * 256 + t;
      int r = fl >> 3, c = fl & 7;
      int cs = c ^ (r & 7);
      gld16(&A[(size_t)(m0 + r) * K + k0 + cs * 8], &sA[fl * 8]);
      gld16(&Bt[(size_t)(n0 + r) * K + k0 + cs * 8], &sB[fl * 8]);
    }
    __syncthreads();
    f16x8 af[4][2], bfr[4][2];
    #pragma unroll
    for (int q = 0; q < 4; ++q) {
      int ra = wm + q * 16 + lr, rb = wn + q * 16 + lr;
      #pragma unroll
      for (int h = 0; h < 2; ++h) {
        af[q][h]  = *(const f16x8*)&sA[ra * 64 + ((h * 4 + hi) ^ (ra & 7)) * 8];
        bfr[q][h] = *(const f16x8*)&sB[rb * 64 + ((h * 4 + hi) ^ (rb & 7)) * 8];
      }
    }
    #pragma unroll
    for (int mi = 0; mi < 4; ++mi)
      #pragma unroll
      for (int ni = 0; ni < 4; ++ni) {
        acc[mi][ni] = __builtin_amdgcn_mfma_f32_16x16x32_f16(af[mi][0], bfr[ni][0], acc[mi][ni], 0, 0, 0);
        acc[mi][ni] = __builtin_amdgcn_mfma_f32_16x16x32_f16(af[mi][1], bfr[ni][1], acc[mi][ni], 0, 0, 0);
      }
    __syncthreads();
  }
  int rr = hi * 4, cc = lr;
  if (MODE == 1) {
    #pragma unroll
    for (int mi = 0; mi < 4; ++mi)
      #pragma unroll
      for (int ni = 0; ni < 4; ++ni) {
        int g = (n0 + wn + ni * 16) >> 4;
        #pragma unroll
        for (int j = 0; j < 4; ++j) {
          float v = acc[mi][ni][j];
          float p = __shfl_xor(v, 8);
          float u1 = (cc < 8) ? v : p;
          float u2 = (cc < 8) ? p : v;
          float hv = u1 / (1.f + __expf(-u1)) * u2;
          if (cc < 8)
            H[(size_t)(m0 + wm + mi * 16 + rr + j) * 2048 + g * 8 + cc] = h_us(hv);
        }
      }
  } else if (MODE == 2) {
    // wave spans exactly one head (64 cols). rope + norms + layout writes.
    int secBase = n0 + wn;
    int sec = secBase / 768;
    int hh = (secBase - sec * 768) >> 6;
    #pragma unroll
    for (int mi = 0; mi < 4; ++mi) {
      float nrm[4];
      #pragma unroll
      for (int j = 0; j < 4; ++j) {
        float ss = 0.f;
        #pragma unroll
        for (int ni = 0; ni < 4; ++ni) ss += acc[mi][ni][j] * acc[mi][ni][j];
        #pragma unroll
        for (int m = 8; m; m >>= 1) ss += __shfl_xor(ss, m, 64);
        nrm[j] = sqrtf(fmaxf(ss + 1.f, 1e-6f));
      }
      #pragma unroll
      for (int j = 0; j < 4; ++j) {
        int m = m0 + wm + mi * 16 + rr + j;         // token row (uniform per 16-lane group)
        if (m < NTOK) {
          int b = m / 197, nn = m - b * 197;
          int bh = b * 12 + hh;
          if (sec == 2) {
            size_t vo = (size_t)bh * 80 * 232;
            if (lr == 0) vtb[vo + nn] = h_us(nrm[j]);
            #pragma unroll
            for (int ni = 0; ni < 4; ++ni) {
              int e = ni * 16 + lr;
              vtb[vo + (size_t)(1 + e) * 232 + nn] = h_us(acc[mi][ni][j]);
            }
          } else {
            float* tb = (sec == 0) ? qtb : ktb;
            ushort* ob = (sec == 0) ? qbuf : kbuf;
            if (lr == 0) tb[(size_t)bh * 208 + nn] = nrm[j];
            size_t rowb = ((size_t)bh * 208 + nn) * 64;
            #pragma unroll
            for (int ni = 0; ni < 4; ++ni) {
              int d = ni * 16 + lr;
              float v = acc[mi][ni][j];
              float p = __shfl_xor(v, 1);
              int j2 = d >> 1;
              float cz = cosb[nn * 32 + j2], sz = sinb[nn * 32 + j2];
              float rv = ((lr & 1) == 0) ? (v * cz - p * sz) : (p * sz + v * cz);
              ob[rowb + d] = h_us(rv);
            }
          }
        }
      }
    }
  } else if (MODE == 3) {
    #pragma unroll
    for (int mi = 0; mi < 4; ++mi)
      #pragma unroll
      for (int ni = 0; ni < 4; ++ni)
        #pragma unroll
        for (int j = 0; j < 4; ++j)
          H[(size_t)(m0 + wm + mi * 16 + rr + j) * N + (n0 + wn + ni * 16 + cc)] = h_us(acc[mi][ni][j]);
  } else {
    #pragma unroll
    for (int mi = 0; mi < 4; ++mi)
      #pragma unroll
      for (int ni = 0; ni < 4; ++ni)
        #pragma unroll
        for (int j = 0; j < 4; ++j)
          C[(size_t)(m0 + wm + mi * 16 + rr + j) * N + (n0 + wn + ni * 16 + cc)] = acc[mi][ni][j];
  }
}

// ---------------- build tokens ----------------
__global__ __launch_bounds__(256) void k_build_tok(const float* __restrict__ feat, const float* __restrict__ cls,
                                                   float* __restrict__ tok) {
  __shared__ float red[8];
  int r = blockIdx.x;
  int b = r / 197, i = r - b * 197;
  int t = threadIdx.x;
  const float* src = (i == 0) ? cls : (feat + (size_t)(b * 196 + i - 1) * 768);
  float v0 = src[t], v1 = src[256 + t], v2 = (t < 255) ? src[512 + t] : 0.f;
  float qs = bsum(v0 * v0 + v1 * v1 + v2 * v2, red);
  float* tp = tok + (size_t)r * 768;
  if (t == 0) tp[0] = sqrtf(fmaxf(qs + 1.f, 1e-6f));
  tp[1 + t] = v0; tp[257 + t] = v1; if (t < 255) tp[513 + t] = v2;
}

// ---------------- lorentz layernorm -> fp16 (pad col 767 = 0) ----------------
__global__ __launch_bounds__(256) void k_ln(const float* __restrict__ tok, const float* __restrict__ g,
                                            const float* __restrict__ bb, ushort* __restrict__ out) {
  __shared__ float red[8];
  int r = blockIdx.x, t = threadIdx.x;
  const float* xp = tok + (size_t)r * 768;
  float v0 = xp[1 + t], v1 = xp[257 + t], v2 = (t < 255) ? xp[513 + t] : 0.f;
  float s = bsum(v0 + v1 + v2, red);
  float q = bsum(v0 * v0 + v1 * v1 + v2 * v2, red);
  float mu = s * (1.f / 767.f);
  float rstd = rsqrtf(fmaxf(q * (1.f / 767.f) - mu * mu, 0.f) + 1e-6f);
  size_t o = (size_t)r * 768;
  out[o + t]       = h_us((v0 - mu) * rstd * g[t]       + bb[t]);
  out[o + 256 + t] = h_us((v1 - mu) * rstd * g[256 + t] + bb[256 + t]);
  if (t < 255)
    out[o + 512 + t] = h_us((v2 - mu) * rstd * g[512 + t] + bb[512 + t]);
  if (t == 255) out[o + 767] = 0;
}

// ---------------- MFMA attention, fp16 single: QK^T -> fp16 P (LDS) -> PV (V from L2) -> project ----------------
__global__ __launch_bounds__(128) void k_attn(const ushort* __restrict__ qbuf,
                                              const float* __restrict__ qtb,
                                              const ushort* __restrict__ kbuf,
                                              const float* __restrict__ ktb,
                                              const ushort* __restrict__ vtb,
                                              ushort* __restrict__ outa) {
  __shared__ ushort sK[208 * 72];
  __shared__ ushort sP[2][16 * 248];
  __shared__ float  sKt[208];
  int half = blockIdx.x, bh = blockIdx.y;
  int b = bh / 12, hd = bh - b * 12;
  int t = threadIdx.x, w = t >> 6, l = t & 63;
  const ushort* kg = kbuf + (size_t)bh * 208 * 64;
  for (int cks = t; cks < 1664; cks += 128) {
    int r = cks >> 3, c8 = (cks & 7) * 8;
    *(int4*)&sK[r * 72 + c8] = *(const int4*)&kg[r * 64 + c8];
  }
  for (int i = t; i < 208; i += 128) sKt[i] = ktb[(size_t)bh * 208 + i];
  __syncthreads();
  const ushort* qg = qbuf + (size_t)bh * 208 * 64;
  const ushort* vg = vtb + (size_t)bh * 80 * 232;
  const float invs = 0.03608439182435161f;
  int rt0 = half ? 7 : 0, rt1 = half ? 13 : 7;
  int lr = l & 15, hi4 = l >> 4;
  ushort* pw = &sP[w][0];
  for (int rt = rt0 + w; rt < rt1; rt += 2) {
    int qrow = (rt * 16 + lr) * 64 + hi4 * 8;
    f16x8 q0 = *(const f16x8*)&qg[qrow];
    f16x8 q1 = *(const f16x8*)&qg[qrow + 32];
    float qt4[4];
    #pragma unroll
    for (int j = 0; j < 4; ++j) qt4[j] = qtb[(size_t)bh * 208 + rt * 16 + hi4 * 4 + j];
    f32x4 acc[13];
    #pragma unroll
    for (int nt = 0; nt < 13; ++nt) {
      int kr = (nt * 16 + lr) * 72 + hi4 * 8;
      f16x8 k0 = *(const f16x8*)&sK[kr];
      f16x8 k1 = *(const f16x8*)&sK[kr + 32];
      acc[nt] = (f32x4){0.f, 0.f, 0.f, 0.f};
      acc[nt] = __builtin_amdgcn_mfma_f32_16x16x32_f16(q0, k0, acc[nt], 0, 0, 0);
      acc[nt] = __builtin_amdgcn_mfma_f32_16x16x32_f16(q1, k1, acc[nt], 0, 0, 0);
    }
    float mx[4] = {-1e30f, -1e30f, -1e30f, -1e30f};
    #pragma unroll
    for (int nt = 0; nt < 13; ++nt) {
      int cI = nt * 16 + lr;
      float ktc = sKt[cI];
      bool valid = (cI < 197);
      #pragma unroll
      for (int j = 0; j < 4; ++j) {
        float s = (2.f + 2.f * (acc[nt][j] - qt4[j] * ktc)) * invs;
        acc[nt][j] = s;
        if (valid) mx[j] = fmaxf(mx[j], s);
      }
    }
    #pragma unroll
    for (int j = 0; j < 4; ++j)
      #pragma unroll
      for (int m = 8; m; m >>= 1) mx[j] = fmaxf(mx[j], __shfl_xor(mx[j], m, 64));
    #pragma unroll
    for (int nt = 0; nt < 14; ++nt) {
      int cI = nt * 16 + lr;
      #pragma unroll
      for (int j = 0; j < 4; ++j) {
        float p = (nt < 13 && cI < 197) ? __expf(acc[nt][j] - mx[j]) : 0.f;
        pw[(hi4 * 4 + j) * 248 + cI] = h_us(p);
      }
    }
    f32x4 accO[5];
    #pragma unroll
    for (int et = 0; et < 5; ++et) accO[et] = (f32x4){0.f, 0.f, 0.f, 0.f};
    #pragma unroll
    for (int ks = 0; ks < 7; ++ks) {
      f16x8 pa = *(const f16x8*)&pw[lr * 248 + ks * 32 + hi4 * 8];
      #pragma unroll
      for (int et = 0; et < 5; ++et) {
        int er = et * 16 + lr;
        f16x8 bv = *(const f16x8*)&vg[(er > 64 ? 64 : er) * 232 + ks * 32 + hi4 * 8];
        accO[et] = __builtin_amdgcn_mfma_f32_16x16x32_f16(pa, bv, accO[et], 0, 0, 0);
      }
    }
    float ssq[4] = {0.f, 0.f, 0.f, 0.f};
    #pragma unroll
    for (int et = 0; et < 4; ++et)
      #pragma unroll
      for (int j = 0; j < 4; ++j) ssq[j] += accO[et][j] * accO[et][j];
    if (lr == 0) {
      #pragma unroll
      for (int j = 0; j < 4; ++j) ssq[j] += accO[4][j] * accO[4][j];
    }
    #pragma unroll
    for (int j = 0; j < 4; ++j)
      #pragma unroll
      for (int m = 8; m; m >>= 1) ssq[j] += __shfl_xor(ssq[j], m, 64);
    float rf4[4];
    #pragma unroll
    for (int j = 0; j < 4; ++j) {
      float o0 = __shfl(accO[0][j], (l & 48));
      rf4[j] = rsqrtf(fmaxf(2.f * o0 * o0 - ssq[j], 1e-6f));
    }
    #pragma unroll
    for (int et = 0; et < 5; ++et) {
      int e = et * 16 + lr;
      if (e == 0 || e >= 65) continue;
      #pragma unroll
      for (int j = 0; j < 4; ++j) {
        int n = rt * 16 + hi4 * 4 + j;
        if (n < 197)
          outa[((size_t)(b * 197 + n)) * 768 + hd * 64 + (e - 1)] = h_us(accO[et][j] * rf4[j]);
      }
    }
  }
}

// ---------------- fused lresnet + lorentz layernorm (s input fp16) ----------------
template<int FIN>
__global__ __launch_bounds__(256) void k_resnet_ln(float* __restrict__ tok, const ushort* __restrict__ s,
                                                   const float* __restrict__ wyp, int l,
                                                   const float* __restrict__ g, const float* __restrict__ bb,
                                                   ushort* __restrict__ out16, float* __restrict__ out32) {
  __shared__ float red[8];
  __shared__ float bc[1];
  int r = blockIdx.x, t = threadIdx.x;
  float w = wyp[l];
  const ushort* sp = s + (size_t)r * 768;
  float* tp = tok + (size_t)r * 768;
  float s0 = us_f(sp[t]), s1 = us_f(sp[256 + t]), s2 = (t < 255) ? us_f(sp[512 + t]) : 0.f;
  float qs = bsum(s0 * s0 + s1 * s1 + s2 * s2, red);
  float at = sqrtf(fmaxf(qs + 1.f, 1e-6f));
  float z0 = tp[1 + t] + w * s0;
  float z1 = tp[257 + t] + w * s1;
  float z2 = (t < 255) ? (tp[513 + t] + w * s2) : 0.f;
  float zs = bsum(z0 * z0 + z1 * z1 + z2 * z2, red);
  if (t == 0) bc[0] = tp[0] + w * at;
  __syncthreads();
  float zt = bc[0];
  float rf = rsqrtf(fmaxf(zt * zt - zs, 1e-6f));
  float n0 = z0 * rf, n1 = z1 * rf, n2 = z2 * rf;
  tp[1 + t] = n0; tp[257 + t] = n1; if (t < 255) tp[513 + t] = n2;
  if (t == 0) tp[0] = zt * rf;
  float sm = bsum(n0 + n1 + n2, red);
  float sq = bsum(n0 * n0 + n1 * n1 + n2 * n2, red);
  float mu = sm * (1.f / 767.f);
  float rstd = rsqrtf(fmaxf(sq * (1.f / 767.f) - mu * mu, 0.f) + 1e-6f);
  float y0 = (n0 - mu) * rstd * g[t] + bb[t];
  float y1 = (n1 - mu) * rstd * g[256 + t] + bb[256 + t];
  float y2 = (t < 255) ? ((n2 - mu) * rstd * g[512 + t] + bb[512 + t]) : 0.f;
  if (FIN) {
    float qq = bsum(y0 * y0 + y1 * y1 + y2 * y2, red);
    float* op = out32 + (size_t)r * 768;
    op[1 + t] = y0; op[257 + t] = y1; if (t < 255) op[513 + t] = y2;
    if (t == 0) op[0] = sqrtf(fmaxf(qq + 1.f, 1e-6f));
  } else {
    size_t o = (size_t)r * 768;
    out16[o + t] = h_us(y0);
    out16[o + 256 + t] = h_us(y1);
    if (t < 255) out16[o + 512 + t] = h_us(y2);
    if (t == 255) out16[o + 767] = 0;
  }
}

extern "C" void kernel_launch(void* const* d_in, const int* in_sizes, int n_in,
                              void* d_out, int out_size, void* d_ws, size_t ws_size,
                              hipStream_t stream) {
  const float* x     = (const float*)d_in[0];
  const float* cls_s = (const float*)d_in[1];
  const float* Wp    = (const float*)d_in[2];
  const float* ln1g  = (const float*)d_in[3];
  const float* ln1b  = (const float*)d_in[4];
  const float* Wq    = (const float*)d_in[5];
  const float* Wk    = (const float*)d_in[6];
  const float* Wv    = (const float*)d_in[7];
  const float* Wo    = (const float*)d_in[8];
  const float* ln2g  = (const float*)d_in[9];
  const float* ln2b  = (const float*)d_in[10];
  const float* W1    = (const float*)d_in[11];
  const float* W2    = (const float*)d_in[12];
  const float* W3    = (const float*)d_in[13];
  const float* wy1   = (const float*)d_in[14];
  const float* wy2   = (const float*)d_in[15];
  const float* lnfg  = (const float*)d_in[16];
  const float* lnfb  = (const float*)d_in[17];

  if (ws_size < B_END) return;

  char* ws = (char*)d_ws;
  float*  cosb   = (float*)(ws + B_COS);
  float*  sinb   = (float*)(ws + B_SIN);
  ushort* wpt    = (ushort*)(ws + B_WPT);
  ushort* apatch = (ushort*)(ws + B_APATCH);
  ushort* wqkvt  = (ushort*)(ws + B_WQKVT);
  ushort* wot    = (ushort*)(ws + B_WOT);
  ushort* w12t   = (ushort*)(ws + B_W12T);
  ushort* w3t    = (ushort*)(ws + B_W3T);
  float*  tok    = (float*)(ws + B_TOK);
  ushort* acta   = (ushort*)(ws + B_ACTA);
  ushort* actb   = (ushort*)(ws + B_ACTB);
  float*  gout   = (float*)(ws + B_GOUT);
  ushort* gouth  = (ushort*)(ws + B_GOUT);
  ushort* qbuf   = (ushort*)(ws + B_QB);
  ushort* kbuf   = (ushort*)(ws + B_KB);
  ushort* vtb    = (ushort*)(ws + B_VT);
  float*  qtb    = (float*)(ws + B_QTB);
  float*  ktb    = (float*)(ws + B_KTB);

  // only V pads must be zero (P=0 x garbage would still contribute via PV MFMA).
  hipMemsetAsync(vtb, 0, VELE * 2, stream);

  k_rope_tab<<<25, 256, 0, stream>>>(cosb, sinb);
  k_tpose<<<32 * 24, 256, 0, stream>>>(Wp, wpt, 1024, 767, 32, 1024);
  k_im2col<<<CONVM, 256, 0, stream>>>(x, apatch);
  k_gemmh<0><<<dim3(49, 6), 256, 0, stream>>>(apatch, wpt, gout, nullptr, 768, 1024,
                                              nullptr, nullptr, nullptr, nullptr, nullptr, nullptr, nullptr);
  k_build_tok<<<NTOK, 256, 0, stream>>>(gout, cls_s, tok);
  k_ln<<<NTOK, 256, 0, stream>>>(tok, ln1g, ln1b, acta);

  for (int l = 0; l < NLAYER; ++l) {
    k_wprep<<<6912, 256, 0, stream>>>(Wq + (size_t)l * 767 * 768, Wk + (size_t)l * 767 * 768,
                                      Wv + (size_t)l * 767 * 768, Wo + (size_t)l * 768 * 767,
                                      W1 + (size_t)l * 767 * 2048, W2 + (size_t)l * 767 * 2048,
                                      W3 + (size_t)l * 2048 * 767, wqkvt, wot, w12t, w3t);

    k_gemmh<2><<<dim3(50, 18), 256, 0, stream>>>(acta, wqkvt, nullptr, nullptr, 2304, 768,
                                                 qbuf, kbuf, vtb, qtb, ktb, cosb, sinb);
    k_attn<<<dim3(2, 384), 128, 0, stream>>>(qbuf, qtb, kbuf, ktb, vtb, acta);
    k_gemmh<3><<<dim3(50, 6), 256, 0, stream>>>(acta, wot, nullptr, gouth, 768, 768,
                                                nullptr, nullptr, nullptr, nullptr, nullptr, nullptr, nullptr);
    k_resnet_ln<0><<<NTOK, 256, 0, stream>>>(tok, gouth, wy1, l,
                                             ln2g + (size_t)l * 767, ln2b + (size_t)l * 767, acta, nullptr);

    k_gemmh<1><<<dim3(50, 32), 256, 0, stream>>>(acta, w12t, nullptr, actb, 4096, 768,
                                                 nullptr, nullptr, nullptr, nullptr, nullptr, nullptr, nullptr);
    k_gemmh<3><<<dim3(50, 6), 256, 0, stream>>>(actb, w3t, nullptr, gouth, 768, 2048,
                                                nullptr, nullptr, nullptr, nullptr, nullptr, nullptr, nullptr);
    if (l < NLAYER - 1)
      k_resnet_ln<0><<<NTOK, 256, 0, stream>>>(tok, gouth, wy2, l,
                                               ln1g + (size_t)(l + 1) * 767, ln1b + (size_t)(l + 1) * 767,
                                               acta, nullptr);
    else
      k_resnet_ln<1><<<NTOK, 256, 0, stream>>>(tok, gouth, wy2, l, lnfg, lnfb, nullptr, (float*)d_out);
  }
}

// Round 8
// 3283.831 us; speedup vs baseline: 7.1183x; 1.0165x over previous
//
#include <hip/hip_runtime.h>
#include <hip/hip_bf16.h>

typedef __attribute__((ext_vector_type(8))) short short8;
typedef __attribute__((ext_vector_type(4))) float f32x4;
typedef _Float16 f16x8 __attribute__((ext_vector_type(8)));

#define NLAYER 12
#define NTOK   6304
#define MPAD   6400
#define CONVM  6272

#define QELE     ((size_t)384*208*64)
#define VELE     ((size_t)384*80*232)

static constexpr size_t AL(size_t x){ return (x + 511) & ~(size_t)511; }
static constexpr size_t B_COS    = 0;
static constexpr size_t B_SIN    = AL(B_COS    + (size_t)197*32*4);
static constexpr size_t B_WPT    = AL(B_SIN    + (size_t)197*32*4);
static constexpr size_t B_APATCH = AL(B_WPT    + (size_t)768*1024*2);
static constexpr size_t B_WQKVT  = AL(B_APATCH + (size_t)CONVM*1024*2);
static constexpr size_t B_WOT    = AL(B_WQKVT  + (size_t)2304*768*2);
static constexpr size_t B_W12T   = AL(B_WOT    + (size_t)768*768*2);
static constexpr size_t B_W3T    = AL(B_W12T   + (size_t)4096*768*2);
static constexpr size_t B_TOK    = AL(B_W3T    + (size_t)768*2048*2);
static constexpr size_t B_ACTA   = AL(B_TOK    + (size_t)NTOK*768*4);
static constexpr size_t B_ACTB   = AL(B_ACTA   + (size_t)MPAD*768*2);
static constexpr size_t B_GOUT   = AL(B_ACTB   + (size_t)MPAD*2048*2);
static constexpr size_t B_QB     = AL(B_GOUT   + (size_t)MPAD*2304*4);
static constexpr size_t B_KB     = AL(B_QB     + QELE*2);
static constexpr size_t B_VT     = AL(B_KB     + QELE*2);
static constexpr size_t B_QTB    = AL(B_VT     + VELE*2);
static constexpr size_t B_KTB    = AL(B_QTB    + (size_t)384*208*4);
static constexpr size_t B_END    = AL(B_KTB    + (size_t)384*208*4);

typedef __attribute__((address_space(1))) unsigned int gu32;
typedef __attribute__((address_space(3))) unsigned int lu32;
__device__ __forceinline__ void gld16(const void* g, void* l) {
  __builtin_amdgcn_global_load_lds((const gu32*)g, (lu32*)l, 16, 0, 0);
}

// ---------------- helpers ----------------
__device__ __forceinline__ float bsum(float v, float* red) {
  #pragma unroll
  for (int m = 32; m; m >>= 1) v += __shfl_xor(v, m, 64);
  __syncthreads();
  if ((threadIdx.x & 63) == 0) red[threadIdx.x >> 6] = v;
  __syncthreads();
  return red[0] + red[1] + red[2] + red[3];
}

__device__ __forceinline__ ushort h_us(float v) {
  _Float16 h = (_Float16)v;
  return *(ushort*)&h;
}
__device__ __forceinline__ float us_f(ushort u) {
  return (float)*(const _Float16*)&u;
}

// ---------------- RoPE tables ----------------
__global__ void k_rope_tab(float* __restrict__ cosb, float* __restrict__ sinb) {
  int idx = blockIdx.x * 256 + threadIdx.x;
  if (idx >= 197 * 32) return;
  int p = idx >> 5, j = idx & 31;
  float cv, sv;
  if (p == 0) { cv = 1.f; sv = 0.f; }
  else {
    int pp = p - 1;
    int iy = pp / 14, ix = pp - iy * 14;
    int pos = (j < 16) ? iy : ix;
    int f   = (j < 16) ? j  : j - 16;
    float inv = powf(100.f, -(float)f / 16.f);
    float a = (float)pos * inv;
    cv = cosf(a); sv = sinf(a);
  }
  cosb[idx] = cv; sinb[idx] = sv;
}

// ---------------- LDS-tiled transpose f32 [K][N] -> fp16 dst[n][k], zero-pad ----------------
__device__ __forceinline__ void tpose_tile(const float* __restrict__ src, ushort* __restrict__ dst,
                                           int K, int N, int ldd, int imode, int tk, int tn) {
  __shared__ float ts[32][33];
  int t = threadIdx.x;
  int rr = t >> 3, c4 = (t & 7) * 4;
  int k0 = tk * 32, n0 = tn * 32;
  #pragma unroll
  for (int e = 0; e < 4; ++e) {
    int k = k0 + rr, n = n0 + c4 + e;
    ts[rr][c4 + e] = (k < K && n < N) ? src[(size_t)k * N + n] : 0.f;
  }
  __syncthreads();
  int c = n0 + rr;
  int drow = (imode == 0) ? c : (16 * (c >> 3) + (c & 7) + (imode == 2 ? 8 : 0));
  ushort4 o;
  #pragma unroll
  for (int e = 0; e < 4; ++e) {
    _Float16 hv = (_Float16)ts[c4 + e][rr];
    ((ushort*)&o)[e] = *(ushort*)&hv;
  }
  *(ushort4*)&dst[(size_t)drow * ldd + k0 + c4] = o;
}

__global__ __launch_bounds__(256) void k_tpose(const float* __restrict__ src, ushort* __restrict__ dst,
                                               int K, int N, int ktiles, int ldd) {
  int tk = blockIdx.x % ktiles, tn = blockIdx.x / ktiles;
  tpose_tile(src, dst, K, N, ldd, 0, tk, tn);
}

__global__ __launch_bounds__(256) void k_wprep(const float* __restrict__ Wq, const float* __restrict__ Wk,
                                               const float* __restrict__ Wv, const float* __restrict__ Wo,
                                               const float* __restrict__ W1, const float* __restrict__ W2,
                                               const float* __restrict__ W3,
                                               ushort* __restrict__ wqkvt, ushort* __restrict__ wot,
                                               ushort* __restrict__ w12t, ushort* __restrict__ w3t) {
  int tile = blockIdx.x;
  const float* src; ushort* dst;
  int K, N, ktiles, ldd, imode = 0, tl;
  if (tile < 2304) {
    int jb = tile / 576; tl = tile % 576;
    ktiles = 24; ldd = 768;
    if (jb == 0)      { src = Wq; dst = wqkvt;                 K = 767; N = 768; }
    else if (jb == 1) { src = Wk; dst = wqkvt + 768 * 768;     K = 767; N = 768; }
    else if (jb == 2) { src = Wv; dst = wqkvt + 2 * 768 * 768; K = 767; N = 768; }
    else              { src = Wo; dst = wot;                   K = 768; N = 767; }
  } else if (tile < 5376) {
    int jb = (tile - 2304) / 1536; tl = (tile - 2304) % 1536;
    ktiles = 24; ldd = 768; K = 767; N = 2048; dst = w12t;
    src = jb ? W2 : W1; imode = jb ? 2 : 1;
  } else {
    tl = tile - 5376; ktiles = 64; ldd = 2048; K = 2048; N = 767; src = W3; dst = w3t;
  }
  int tk = tl % ktiles, tn = tl / ktiles;
  tpose_tile(src, dst, K, N, ldd, imode, tk, tn);
}

// ---------------- im2col with Lorentz time channel, fp16 ----------------
__global__ __launch_bounds__(256) void k_im2col(const float* __restrict__ x, ushort* __restrict__ ap) {
  int r = blockIdx.x;
  int b = r / 196, pi = r - b * 196;
  int py = pi / 14, px = pi - py * 14;
  int t = threadIdx.x;
  int ph = t >> 4, pw = t & 15;
  int iy = py * 16 + ph, ix = px * 16 + pw;
  size_t base = ((size_t)b * 3 * 224 + iy) * 224 + ix;
  float x0 = x[base];
  float x1 = x[base + 224 * 224];
  float x2 = x[base + 2 * 224 * 224];
  float tv = sqrtf(fmaxf(x0 * x0 + x1 * x1 + x2 * x2 + 1.f, 1e-6f));
  size_t o = (size_t)r * 1024 + t * 4;
  ap[o] = h_us(tv); ap[o + 1] = h_us(x0); ap[o + 2] = h_us(x1); ap[o + 3] = h_us(x2);
}

// ---------------- 128-tile fp16 GEMM (2-barrier). MODE 0: f32 C; 3: fp16 H ----------------
template<int MODE>
__global__ __launch_bounds__(256) void k_gemmh(const ushort* __restrict__ A, const ushort* __restrict__ Bt,
                                               float* __restrict__ C, ushort* __restrict__ H,
                                               int N, int K) {
  __shared__ ushort sA[128 * 64];
  __shared__ ushort sB[128 * 64];
  int m0 = blockIdx.x * 128, n0 = blockIdx.y * 128;
  int t = threadIdx.x;
  int w = t >> 6, l = t & 63;
  int wm = (w >> 1) * 64, wn = (w & 1) * 64;
  int lr = l & 15, hi = l >> 4;
  f32x4 acc[4][4] = {};
  for (int k0 = 0; k0 < K; k0 += 64) {
    #pragma unroll
    for (int i = 0; i < 4; ++i) {
      int fl = i * 256 + t;
      int r = fl >> 3, c = fl & 7;
      int cs = c ^ (r & 7);
      gld16(&A[(size_t)(m0 + r) * K + k0 + cs * 8], &sA[fl * 8]);
      gld16(&Bt[(size_t)(n0 + r) * K + k0 + cs * 8], &sB[fl * 8]);
    }
    __syncthreads();
    f16x8 af[4][2], bfr[4][2];
    #pragma unroll
    for (int q = 0; q < 4; ++q) {
      int ra = wm + q * 16 + lr, rb = wn + q * 16 + lr;
      #pragma unroll
      for (int h = 0; h < 2; ++h) {
        af[q][h]  = *(const f16x8*)&sA[ra * 64 + ((h * 4 + hi) ^ (ra & 7)) * 8];
        bfr[q][h] = *(const f16x8*)&sB[rb * 64 + ((h * 4 + hi) ^ (rb & 7)) * 8];
      }
    }
    #pragma unroll
    for (int mi = 0; mi < 4; ++mi)
      #pragma unroll
      for (int ni = 0; ni < 4; ++ni) {
        acc[mi][ni] = __builtin_amdgcn_mfma_f32_16x16x32_f16(af[mi][0], bfr[ni][0], acc[mi][ni], 0, 0, 0);
        acc[mi][ni] = __builtin_amdgcn_mfma_f32_16x16x32_f16(af[mi][1], bfr[ni][1], acc[mi][ni], 0, 0, 0);
      }
    __syncthreads();
  }
  int rr = hi * 4, cc = lr;
  if (MODE == 3) {
    #pragma unroll
    for (int mi = 0; mi < 4; ++mi)
      #pragma unroll
      for (int ni = 0; ni < 4; ++ni)
        #pragma unroll
        for (int j = 0; j < 4; ++j)
          H[(size_t)(m0 + wm + mi * 16 + rr + j) * N + (n0 + wn + ni * 16 + cc)] = h_us(acc[mi][ni][j]);
  } else {
    #pragma unroll
    for (int mi = 0; mi < 4; ++mi)
      #pragma unroll
      for (int ni = 0; ni < 4; ++ni)
        #pragma unroll
        for (int j = 0; j < 4; ++j)
          C[(size_t)(m0 + wm + mi * 16 + rr + j) * N + (n0 + wn + ni * 16 + cc)] = acc[mi][ni][j];
  }
}

// ---------------- 256-tile 8-phase counted-vmcnt fp16 GEMM. MODE 1: silu->H; MODE 2: QKV epilogue ----------------
template<int MODE>
__global__ __launch_bounds__(512, 2) void k_g256(const ushort* __restrict__ A, const ushort* __restrict__ Bt,
                                                 ushort* __restrict__ H, int N, int K,
                                                 ushort* __restrict__ qbuf, ushort* __restrict__ kbuf,
                                                 ushort* __restrict__ vtb,
                                                 float* __restrict__ qtb, float* __restrict__ ktb,
                                                 const float* __restrict__ cosb, const float* __restrict__ sinb) {
  // LDS: [buf][khalf] regions of 16KB each: 256 rows x 4 chunks(16B), chunk XOR-swizzled by (row&3)
  __shared__ ushort sA[2][2][256 * 32];
  __shared__ ushort sB[2][2][256 * 32];
  const int t = threadIdx.x;
  const int w = t >> 6, l = t & 63;
  const int wr = w >> 2, wc = w & 3;
  const int lr = l & 15, hi4 = l >> 4;
  const int m0 = blockIdx.x * 256, n0 = blockIdx.y * 256;

  auto stageA = [&](int kt, int kh, int buf) {
    #pragma unroll
    for (int ii = 0; ii < 2; ++ii) {
      int q = ii * 512 + t;
      int r = q >> 2, ci = q & 3;
      gld16(&A[(size_t)(m0 + r) * K + kt * 64 + kh * 32 + ((ci ^ (r & 3)) * 8)], &sA[buf][kh][q * 8]);
    }
  };
  auto stageB = [&](int kt, int kh, int buf) {
    #pragma unroll
    for (int ii = 0; ii < 2; ++ii) {
      int q = ii * 512 + t;
      int r = q >> 2, ci = q & 3;
      gld16(&Bt[(size_t)(n0 + r) * K + kt * 64 + kh * 32 + ((ci ^ (r & 3)) * 8)], &sB[buf][kh][q * 8]);
    }
  };

  f32x4 acc[8][4] = {};
  auto ldA = [&](int buf, int ks, int G, f16x8* fr) {
    #pragma unroll
    for (int mi = 0; mi < 4; ++mi) {
      int r = wr * 128 + (G * 4 + mi) * 16 + lr;
      fr[mi] = *(const f16x8*)&sA[buf][ks][(r * 4 + (hi4 ^ (r & 3))) * 8];
    }
  };
  auto ldB = [&](int buf, int ks, f16x8* fr) {
    #pragma unroll
    for (int ni = 0; ni < 4; ++ni) {
      int r = wc * 64 + ni * 16 + lr;
      fr[ni] = *(const f16x8*)&sB[buf][ks][(r * 4 + (hi4 ^ (r & 3))) * 8];
    }
  };
  auto mmaG = [&](int G, f16x8* a, f16x8* b) {
    __builtin_amdgcn_s_setprio(1);
    #pragma unroll
    for (int mi = 0; mi < 4; ++mi)
      #pragma unroll
      for (int ni = 0; ni < 4; ++ni)
        acc[G * 4 + mi][ni] = __builtin_amdgcn_mfma_f32_16x16x32_f16(a[mi], b[ni], acc[G * 4 + mi][ni], 0, 0, 0);
    __builtin_amdgcn_s_setprio(0);
  };

  const int NT = K >> 6;        // 64-wide K tiles (even)
  const int NI = NT >> 1;
  // prologue: tile 0 -> buf0 (units: Ak0, Bk0, Ak1, Bk1)
  stageA(0, 0, 0); stageB(0, 0, 0); stageA(0, 1, 0); stageB(0, 1, 0);

  for (int i = 0; i < NI; ++i) {
    const int T1 = 2 * i + 1, T2 = 2 * i + 2;
    const bool last = (i == NI - 1);
    f16x8 a0[4], a1[4], b0[4], b1[4];
    // ---- ph1: consume buf0 ks0 G0 ; stage A(T1)k0 -> buf1 ----
    asm volatile("s_waitcnt vmcnt(4)" ::: "memory");
    __builtin_amdgcn_sched_barrier(0);
    __builtin_amdgcn_s_barrier();
    ldA(0, 0, 0, a0); ldB(0, 0, b0);
    stageA(T1, 0, 1);
    mmaG(0, a0, b0);
    // ---- ph2 ----
    ldA(0, 0, 1, a1);
    stageB(T1, 0, 1);
    mmaG(1, a1, b0);
    // ---- ph3 ----
    asm volatile("s_waitcnt vmcnt(4)" ::: "memory");
    __builtin_amdgcn_sched_barrier(0);
    __builtin_amdgcn_s_barrier();
    ldA(0, 1, 0, a0); ldB(0, 1, b1);
    stageA(T1, 1, 1);
    mmaG(0, a0, b1);
    // ---- ph4 ----
    ldA(0, 1, 1, a1);
    stageB(T1, 1, 1);
    mmaG(1, a1, b1);
    // ---- ph5: consume buf1 (T1) ; stage A(T2)k0 -> buf0 ----
    asm volatile("s_waitcnt vmcnt(4)" ::: "memory");
    __builtin_amdgcn_sched_barrier(0);
    __builtin_amdgcn_s_barrier();
    ldA(1, 0, 0, a0); ldB(1, 0, b0);
    if (!last) stageA(T2, 0, 0);
    mmaG(0, a0, b0);
    // ---- ph6 ----
    ldA(1, 0, 1, a1);
    if (!last) stageB(T2, 0, 0);
    mmaG(1, a1, b0);
    // ---- ph7 ----
    if (last) { asm volatile("s_waitcnt vmcnt(0)" ::: "memory"); }
    else      { asm volatile("s_waitcnt vmcnt(4)" ::: "memory"); }
    __builtin_amdgcn_sched_barrier(0);
    __builtin_amdgcn_s_barrier();
    ldA(1, 1, 0, a0); ldB(1, 1, b1);
    if (!last) stageA(T2, 1, 0);
    mmaG(0, a0, b1);
    // ---- ph8 ----
    ldA(1, 1, 1, a1);
    if (!last) stageB(T2, 1, 0);
    mmaG(1, a1, b1);
  }

  // -------- epilogues --------
  if (MODE == 1) {
    int cc = lr;
    #pragma unroll
    for (int mi = 0; mi < 8; ++mi)
      #pragma unroll
      for (int ni = 0; ni < 4; ++ni) {
        int g = (n0 + wc * 64 + ni * 16) >> 4;
        #pragma unroll
        for (int j = 0; j < 4; ++j) {
          float v = acc[mi][ni][j];
          float p = __shfl_xor(v, 8);
          float u1 = (cc < 8) ? v : p;
          float u2 = (cc < 8) ? p : v;
          float hv = u1 / (1.f + __expf(-u1)) * u2;
          if (cc < 8)
            H[(size_t)(m0 + wr * 128 + mi * 16 + hi4 * 4 + j) * 2048 + g * 8 + cc] = h_us(hv);
        }
      }
  } else if (MODE == 2) {
    int secBase = n0 + wc * 64;
    int sec = secBase / 768;
    int hh = (secBase - sec * 768) >> 6;
    #pragma unroll
    for (int mi = 0; mi < 8; ++mi) {
      float nrm[4];
      #pragma unroll
      for (int j = 0; j < 4; ++j) {
        float ss = 0.f;
        #pragma unroll
        for (int ni = 0; ni < 4; ++ni) ss += acc[mi][ni][j] * acc[mi][ni][j];
        #pragma unroll
        for (int m = 8; m; m >>= 1) ss += __shfl_xor(ss, m, 64);
        nrm[j] = sqrtf(fmaxf(ss + 1.f, 1e-6f));
      }
      #pragma unroll
      for (int j = 0; j < 4; ++j) {
        int m = m0 + wr * 128 + mi * 16 + hi4 * 4 + j;
        if (m < NTOK) {
          int b = m / 197, nn = m - b * 197;
          int bh = b * 12 + hh;
          if (sec == 2) {
            size_t vo = (size_t)bh * 80 * 232;
            if (lr == 0) vtb[vo + nn] = h_us(nrm[j]);
            #pragma unroll
            for (int ni = 0; ni < 4; ++ni) {
              int e = ni * 16 + lr;
              vtb[vo + (size_t)(1 + e) * 232 + nn] = h_us(acc[mi][ni][j]);
            }
          } else {
            float* tb = (sec == 0) ? qtb : ktb;
            ushort* ob = (sec == 0) ? qbuf : kbuf;
            if (lr == 0) tb[(size_t)bh * 208 + nn] = nrm[j];
            size_t rowb = ((size_t)bh * 208 + nn) * 64;
            #pragma unroll
            for (int ni = 0; ni < 4; ++ni) {
              int d = ni * 16 + lr;
              float v = acc[mi][ni][j];
              float p = __shfl_xor(v, 1);
              int j2 = d >> 1;
              float cz = cosb[nn * 32 + j2], sz = sinb[nn * 32 + j2];
              float rv = ((lr & 1) == 0) ? (v * cz - p * sz) : (p * sz + v * cz);
              ob[rowb + d] = h_us(rv);
            }
          }
        }
      }
    }
  }
}

// ---------------- build tokens ----------------
__global__ __launch_bounds__(256) void k_build_tok(const float* __restrict__ feat, const float* __restrict__ cls,
                                                   float* __restrict__ tok) {
  __shared__ float red[8];
  int r = blockIdx.x;
  int b = r / 197, i = r - b * 197;
  int t = threadIdx.x;
  const float* src = (i == 0) ? cls : (feat + (size_t)(b * 196 + i - 1) * 768);
  float v0 = src[t], v1 = src[256 + t], v2 = (t < 255) ? src[512 + t] : 0.f;
  float qs = bsum(v0 * v0 + v1 * v1 + v2 * v2, red);
  float* tp = tok + (size_t)r * 768;
  if (t == 0) tp[0] = sqrtf(fmaxf(qs + 1.f, 1e-6f));
  tp[1 + t] = v0; tp[257 + t] = v1; if (t < 255) tp[513 + t] = v2;
}

// ---------------- lorentz layernorm -> fp16 (pad col 767 = 0) ----------------
__global__ __launch_bounds__(256) void k_ln(const float* __restrict__ tok, const float* __restrict__ g,
                                            const float* __restrict__ bb, ushort* __restrict__ out) {
  __shared__ float red[8];
  int r = blockIdx.x, t = threadIdx.x;
  const float* xp = tok + (size_t)r * 768;
  float v0 = xp[1 + t], v1 = xp[257 + t], v2 = (t < 255) ? xp[513 + t] : 0.f;
  float s = bsum(v0 + v1 + v2, red);
  float q = bsum(v0 * v0 + v1 * v1 + v2 * v2, red);
  float mu = s * (1.f / 767.f);
  float rstd = rsqrtf(fmaxf(q * (1.f / 767.f) - mu * mu, 0.f) + 1e-6f);
  size_t o = (size_t)r * 768;
  out[o + t]       = h_us((v0 - mu) * rstd * g[t]       + bb[t]);
  out[o + 256 + t] = h_us((v1 - mu) * rstd * g[256 + t] + bb[256 + t]);
  if (t < 255)
    out[o + 512 + t] = h_us((v2 - mu) * rstd * g[512 + t] + bb[512 + t]);
  if (t == 255) out[o + 767] = 0;
}

// ---------------- MFMA attention, fp16 single ----------------
__global__ __launch_bounds__(128) void k_attn(const ushort* __restrict__ qbuf,
                                              const float* __restrict__ qtb,
                                              const ushort* __restrict__ kbuf,
                                              const float* __restrict__ ktb,
                                              const ushort* __restrict__ vtb,
                                              ushort* __restrict__ outa) {
  __shared__ ushort sK[208 * 72];
  __shared__ ushort sP[2][16 * 248];
  __shared__ float  sKt[208];
  int half = blockIdx.x, bh = blockIdx.y;
  int b = bh / 12, hd = bh - b * 12;
  int t = threadIdx.x, w = t >> 6, l = t & 63;
  const ushort* kg = kbuf + (size_t)bh * 208 * 64;
  for (int cks = t; cks < 1664; cks += 128) {
    int r = cks >> 3, c8 = (cks & 7) * 8;
    *(int4*)&sK[r * 72 + c8] = *(const int4*)&kg[r * 64 + c8];
  }
  for (int i = t; i < 208; i += 128) sKt[i] = ktb[(size_t)bh * 208 + i];
  __syncthreads();
  const ushort* qg = qbuf + (size_t)bh * 208 * 64;
  const ushort* vg = vtb + (size_t)bh * 80 * 232;
  const float invs = 0.03608439182435161f;
  int rt0 = half ? 7 : 0, rt1 = half ? 13 : 7;
  int lr = l & 15, hi4 = l >> 4;
  ushort* pw = &sP[w][0];
  for (int rt = rt0 + w; rt < rt1; rt += 2) {
    int qrow = (rt * 16 + lr) * 64 + hi4 * 8;
    f16x8 q0 = *(const f16x8*)&qg[qrow];
    f16x8 q1 = *(const f16x8*)&qg[qrow + 32];
    float qt4[4];
    #pragma unroll
    for (int j = 0; j < 4; ++j) qt4[j] = qtb[(size_t)bh * 208 + rt * 16 + hi4 * 4 + j];
    f32x4 acc[13];
    #pragma unroll
    for (int nt = 0; nt < 13; ++nt) {
      int kr = (nt * 16 + lr) * 72 + hi4 * 8;
      f16x8 k0 = *(const f16x8*)&sK[kr];
      f16x8 k1 = *(const f16x8*)&sK[kr + 32];
      acc[nt] = (f32x4){0.f, 0.f, 0.f, 0.f};
      acc[nt] = __builtin_amdgcn_mfma_f32_16x16x32_f16(q0, k0, acc[nt], 0, 0, 0);
      acc[nt] = __builtin_amdgcn_mfma_f32_16x16x32_f16(q1, k1, acc[nt], 0, 0, 0);
    }
    float mx[4] = {-1e30f, -1e30f, -1e30f, -1e30f};
    #pragma unroll
    for (int nt = 0; nt < 13; ++nt) {
      int cI = nt * 16 + lr;
      float ktc = sKt[cI];
      bool valid = (cI < 197);
      #pragma unroll
      for (int j = 0; j < 4; ++j) {
        float s = (2.f + 2.f * (acc[nt][j] - qt4[j] * ktc)) * invs;
        acc[nt][j] = s;
        if (valid) mx[j] = fmaxf(mx[j], s);
      }
    }
    #pragma unroll
    for (int j = 0; j < 4; ++j)
      #pragma unroll
      for (int m = 8; m; m >>= 1) mx[j] = fmaxf(mx[j], __shfl_xor(mx[j], m, 64));
    #pragma unroll
    for (int nt = 0; nt < 14; ++nt) {
      int cI = nt * 16 + lr;
      #pragma unroll
      for (int j = 0; j < 4; ++j) {
        float p = (nt < 13 && cI < 197) ? __expf(acc[nt][j] - mx[j]) : 0.f;
        pw[(hi4 * 4 + j) * 248 + cI] = h_us(p);
      }
    }
    f32x4 accO[5];
    #pragma unroll
    for (int et = 0; et < 5; ++et) accO[et] = (f32x4){0.f, 0.f, 0.f, 0.f};
    #pragma unroll
    for (int ks = 0; ks < 7; ++ks) {
      f16x8 pa = *(const f16x8*)&pw[lr * 248 + ks * 32 + hi4 * 8];
      #pragma unroll
      for (int et = 0; et < 5; ++et) {
        int er = et * 16 + lr;
        f16x8 bv = *(const f16x8*)&vg[(er > 64 ? 64 : er) * 232 + ks * 32 + hi4 * 8];
        accO[et] = __builtin_amdgcn_mfma_f32_16x16x32_f16(pa, bv, accO[et], 0, 0, 0);
      }
    }
    float ssq[4] = {0.f, 0.f, 0.f, 0.f};
    #pragma unroll
    for (int et = 0; et < 4; ++et)
      #pragma unroll
      for (int j = 0; j < 4; ++j) ssq[j] += accO[et][j] * accO[et][j];
    if (lr == 0) {
      #pragma unroll
      for (int j = 0; j < 4; ++j) ssq[j] += accO[4][j] * accO[4][j];
    }
    #pragma unroll
    for (int j = 0; j < 4; ++j)
      #pragma unroll
      for (int m = 8; m; m >>= 1) ssq[j] += __shfl_xor(ssq[j], m, 64);
    float rf4[4];
    #pragma unroll
    for (int j = 0; j < 4; ++j) {
      float o0 = __shfl(accO[0][j], (l & 48));
      rf4[j] = rsqrtf(fmaxf(2.f * o0 * o0 - ssq[j], 1e-6f));
    }
    #pragma unroll
    for (int et = 0; et < 5; ++et) {
      int e = et * 16 + lr;
      if (e == 0 || e >= 65) continue;
      #pragma unroll
      for (int j = 0; j < 4; ++j) {
        int n = rt * 16 + hi4 * 4 + j;
        if (n < 197)
          outa[((size_t)(b * 197 + n)) * 768 + hd * 64 + (e - 1)] = h_us(accO[et][j] * rf4[j]);
      }
    }
  }
}

// ---------------- fused lresnet + lorentz layernorm (s input fp16) ----------------
template<int FIN>
__global__ __launch_bounds__(256) void k_resnet_ln(float* __restrict__ tok, const ushort* __restrict__ s,
                                                   const float* __restrict__ wyp, int l,
                                                   const float* __restrict__ g, const float* __restrict__ bb,
                                                   ushort* __restrict__ out16, float* __restrict__ out32) {
  __shared__ float red[8];
  __shared__ float bc[1];
  int r = blockIdx.x, t = threadIdx.x;
  float w = wyp[l];
  const ushort* sp = s + (size_t)r * 768;
  float* tp = tok + (size_t)r * 768;
  float s0 = us_f(sp[t]), s1 = us_f(sp[256 + t]), s2 = (t < 255) ? us_f(sp[512 + t]) : 0.f;
  float qs = bsum(s0 * s0 + s1 * s1 + s2 * s2, red);
  float at = sqrtf(fmaxf(qs + 1.f, 1e-6f));
  float z0 = tp[1 + t] + w * s0;
  float z1 = tp[257 + t] + w * s1;
  float z2 = (t < 255) ? (tp[513 + t] + w * s2) : 0.f;
  float zs = bsum(z0 * z0 + z1 * z1 + z2 * z2, red);
  if (t == 0) bc[0] = tp[0] + w * at;
  __syncthreads();
  float zt = bc[0];
  float rf = rsqrtf(fmaxf(zt * zt - zs, 1e-6f));
  float n0 = z0 * rf, n1 = z1 * rf, n2 = z2 * rf;
  tp[1 + t] = n0; tp[257 + t] = n1; if (t < 255) tp[513 + t] = n2;
  if (t == 0) tp[0] = zt * rf;
  float sm = bsum(n0 + n1 + n2, red);
  float sq = bsum(n0 * n0 + n1 * n1 + n2 * n2, red);
  float mu = sm * (1.f / 767.f);
  float rstd = rsqrtf(fmaxf(sq * (1.f / 767.f) - mu * mu, 0.f) + 1e-6f);
  float y0 = (n0 - mu) * rstd * g[t] + bb[t];
  float y1 = (n1 - mu) * rstd * g[256 + t] + bb[256 + t];
  float y2 = (t < 255) ? ((n2 - mu) * rstd * g[512 + t] + bb[512 + t]) : 0.f;
  if (FIN) {
    float qq = bsum(y0 * y0 + y1 * y1 + y2 * y2, red);
    float* op = out32 + (size_t)r * 768;
    op[1 + t] = y0; op[257 + t] = y1; if (t < 255) op[513 + t] = y2;
    if (t == 0) op[0] = sqrtf(fmaxf(qq + 1.f, 1e-6f));
  } else {
    size_t o = (size_t)r * 768;
    out16[o + t] = h_us(y0);
    out16[o + 256 + t] = h_us(y1);
    if (t < 255) out16[o + 512 + t] = h_us(y2);
    if (t == 255) out16[o + 767] = 0;
  }
}

extern "C" void kernel_launch(void* const* d_in, const int* in_sizes, int n_in,
                              void* d_out, int out_size, void* d_ws, size_t ws_size,
                              hipStream_t stream) {
  const float* x     = (const float*)d_in[0];
  const float* cls_s = (const float*)d_in[1];
  const float* Wp    = (const float*)d_in[2];
  const float* ln1g  = (const float*)d_in[3];
  const float* ln1b  = (const float*)d_in[4];
  const float* Wq    = (const float*)d_in[5];
  const float* Wk    = (const float*)d_in[6];
  const float* Wv    = (const float*)d_in[7];
  const float* Wo    = (const float*)d_in[8];
  const float* ln2g  = (const float*)d_in[9];
  const float* ln2b  = (const float*)d_in[10];
  const float* W1    = (const float*)d_in[11];
  const float* W2    = (const float*)d_in[12];
  const float* W3    = (const float*)d_in[13];
  const float* wy1   = (const float*)d_in[14];
  const float* wy2   = (const float*)d_in[15];
  const float* lnfg  = (const float*)d_in[16];
  const float* lnfb  = (const float*)d_in[17];

  if (ws_size < B_END) return;

  char* ws = (char*)d_ws;
  float*  cosb   = (float*)(ws + B_COS);
  float*  sinb   = (float*)(ws + B_SIN);
  ushort* wpt    = (ushort*)(ws + B_WPT);
  ushort* apatch = (ushort*)(ws + B_APATCH);
  ushort* wqkvt  = (ushort*)(ws + B_WQKVT);
  ushort* wot    = (ushort*)(ws + B_WOT);
  ushort* w12t   = (ushort*)(ws + B_W12T);
  ushort* w3t    = (ushort*)(ws + B_W3T);
  float*  tok    = (float*)(ws + B_TOK);
  ushort* acta   = (ushort*)(ws + B_ACTA);
  ushort* actb   = (ushort*)(ws + B_ACTB);
  float*  gout   = (float*)(ws + B_GOUT);
  ushort* gouth  = (ushort*)(ws + B_GOUT);
  ushort* qbuf   = (ushort*)(ws + B_QB);
  ushort* kbuf   = (ushort*)(ws + B_KB);
  ushort* vtb    = (ushort*)(ws + B_VT);
  float*  qtb    = (float*)(ws + B_QTB);
  float*  ktb    = (float*)(ws + B_KTB);

  // only V pads must be zero (P=0 x garbage would still contribute via PV MFMA).
  hipMemsetAsync(vtb, 0, VELE * 2, stream);

  k_rope_tab<<<25, 256, 0, stream>>>(cosb, sinb);
  k_tpose<<<32 * 24, 256, 0, stream>>>(Wp, wpt, 1024, 767, 32, 1024);
  k_im2col<<<CONVM, 256, 0, stream>>>(x, apatch);
  k_gemmh<0><<<dim3(49, 6), 256, 0, stream>>>(apatch, wpt, gout, nullptr, 768, 1024);
  k_build_tok<<<NTOK, 256, 0, stream>>>(gout, cls_s, tok);
  k_ln<<<NTOK, 256, 0, stream>>>(tok, ln1g, ln1b, acta);

  for (int l = 0; l < NLAYER; ++l) {
    k_wprep<<<6912, 256, 0, stream>>>(Wq + (size_t)l * 767 * 768, Wk + (size_t)l * 767 * 768,
                                      Wv + (size_t)l * 767 * 768, Wo + (size_t)l * 768 * 767,
                                      W1 + (size_t)l * 767 * 2048, W2 + (size_t)l * 767 * 2048,
                                      W3 + (size_t)l * 2048 * 767, wqkvt, wot, w12t, w3t);

    k_g256<2><<<dim3(25, 9), 512, 0, stream>>>(acta, wqkvt, nullptr, 2304, 768,
                                               qbuf, kbuf, vtb, qtb, ktb, cosb, sinb);
    k_attn<<<dim3(2, 384), 128, 0, stream>>>(qbuf, qtb, kbuf, ktb, vtb, acta);
    k_gemmh<3><<<dim3(50, 6), 256, 0, stream>>>(acta, wot, nullptr, gouth, 768, 768);
    k_resnet_ln<0><<<NTOK, 256, 0, stream>>>(tok, gouth, wy1, l,
                                             ln2g + (size_t)l * 767, ln2b + (size_t)l * 767, acta, nullptr);

    k_g256<1><<<dim3(25, 16), 512, 0, stream>>>(acta, w12t, actb, 4096, 768,
                                                nullptr, nullptr, nullptr, nullptr, nullptr, nullptr, nullptr);
    k_gemmh<3><<<dim3(50, 6), 256, 0, stream>>>(actb, w3t, nullptr, gouth, 768, 2048);
    if (l < NLAYER - 1)
      k_resnet_ln<0><<<NTOK, 256, 0, stream>>>(tok, gouth, wy2, l,
                                               ln1g + (size_t)(l + 1) * 767, ln1b + (size_t)(l + 1) * 767,
                                               acta, nullptr);
    else
      k_resnet_ln<1><<<NTOK, 256, 0, stream>>>(tok, gouth, wy2, l, lnfg, lnfb, nullptr, (float*)d_out);
  }
}

// Round 9
// 3274.463 us; speedup vs baseline: 7.1386x; 1.0029x over previous
//
#include <hip/hip_runtime.h>
#include <hip/hip_bf16.h>

typedef __attribute__((ext_vector_type(8))) short short8;
typedef __attribute__((ext_vector_type(4))) float f32x4;
typedef _Float16 f16x8 __attribute__((ext_vector_type(8)));

#define NLAYER 12
#define NTOK   6304
#define MPAD   6400
#define CONVM  6272

#define QELE     ((size_t)384*208*64)
#define VELE     ((size_t)384*80*232)

static constexpr size_t AL(size_t x){ return (x + 511) & ~(size_t)511; }
static constexpr size_t B_COS    = 0;
static constexpr size_t B_SIN    = AL(B_COS    + (size_t)197*32*4);
static constexpr size_t B_WPT    = AL(B_SIN    + (size_t)197*32*4);
static constexpr size_t B_APATCH = AL(B_WPT    + (size_t)768*1024*2);
static constexpr size_t B_WQKVT  = AL(B_APATCH + (size_t)CONVM*1024*2);
static constexpr size_t B_WOT    = AL(B_WQKVT  + (size_t)2304*768*2);
static constexpr size_t B_W12T   = AL(B_WOT    + (size_t)768*768*2);
static constexpr size_t B_W3T    = AL(B_W12T   + (size_t)4096*768*2);
static constexpr size_t B_TOK    = AL(B_W3T    + (size_t)768*2048*2);
static constexpr size_t B_ACTA   = AL(B_TOK    + (size_t)NTOK*768*4);
static constexpr size_t B_ACTB   = AL(B_ACTA   + (size_t)MPAD*768*2);
static constexpr size_t B_GOUT   = AL(B_ACTB   + (size_t)MPAD*2048*2);
static constexpr size_t B_QB     = AL(B_GOUT   + (size_t)MPAD*2304*4);
static constexpr size_t B_KB     = AL(B_QB     + QELE*2);
static constexpr size_t B_VT     = AL(B_KB     + QELE*2);
static constexpr size_t B_QTB    = AL(B_VT     + VELE*2);
static constexpr size_t B_KTB    = AL(B_QTB    + (size_t)384*208*4);
static constexpr size_t B_END    = AL(B_KTB    + (size_t)384*208*4);

typedef __attribute__((address_space(1))) unsigned int gu32;
typedef __attribute__((address_space(3))) unsigned int lu32;
__device__ __forceinline__ void gld16(const void* g, void* l) {
  __builtin_amdgcn_global_load_lds((const gu32*)g, (lu32*)l, 16, 0, 0);
}

// ---------------- helpers ----------------
__device__ __forceinline__ float bsum(float v, float* red) {
  #pragma unroll
  for (int m = 32; m; m >>= 1) v += __shfl_xor(v, m, 64);
  __syncthreads();
  if ((threadIdx.x & 63) == 0) red[threadIdx.x >> 6] = v;
  __syncthreads();
  return red[0] + red[1] + red[2] + red[3];
}

__device__ __forceinline__ ushort h_us(float v) {
  _Float16 h = (_Float16)v;
  return *(ushort*)&h;
}
__device__ __forceinline__ float us_f(ushort u) {
  return (float)*(const _Float16*)&u;
}

// ---------------- RoPE tables ----------------
__global__ void k_rope_tab(float* __restrict__ cosb, float* __restrict__ sinb) {
  int idx = blockIdx.x * 256 + threadIdx.x;
  if (idx >= 197 * 32) return;
  int p = idx >> 5, j = idx & 31;
  float cv, sv;
  if (p == 0) { cv = 1.f; sv = 0.f; }
  else {
    int pp = p - 1;
    int iy = pp / 14, ix = pp - iy * 14;
    int pos = (j < 16) ? iy : ix;
    int f   = (j < 16) ? j  : j - 16;
    float inv = powf(100.f, -(float)f / 16.f);
    float a = (float)pos * inv;
    cv = cosf(a); sv = sinf(a);
  }
  cosb[idx] = cv; sinb[idx] = sv;
}

// ---------------- LDS-tiled transpose f32 [K][N] -> fp16 dst[n][k], zero-pad ----------------
__device__ __forceinline__ void tpose_tile(const float* __restrict__ src, ushort* __restrict__ dst,
                                           int K, int N, int ldd, int imode, int tk, int tn) {
  __shared__ float ts[32][33];
  int t = threadIdx.x;
  int rr = t >> 3, c4 = (t & 7) * 4;
  int k0 = tk * 32, n0 = tn * 32;
  #pragma unroll
  for (int e = 0; e < 4; ++e) {
    int k = k0 + rr, n = n0 + c4 + e;
    ts[rr][c4 + e] = (k < K && n < N) ? src[(size_t)k * N + n] : 0.f;
  }
  __syncthreads();
  int c = n0 + rr;
  int drow = (imode == 0) ? c : (16 * (c >> 3) + (c & 7) + (imode == 2 ? 8 : 0));
  ushort4 o;
  #pragma unroll
  for (int e = 0; e < 4; ++e) {
    _Float16 hv = (_Float16)ts[c4 + e][rr];
    ((ushort*)&o)[e] = *(ushort*)&hv;
  }
  *(ushort4*)&dst[(size_t)drow * ldd + k0 + c4] = o;
}

__global__ __launch_bounds__(256) void k_tpose(const float* __restrict__ src, ushort* __restrict__ dst,
                                               int K, int N, int ktiles, int ldd) {
  int tk = blockIdx.x % ktiles, tn = blockIdx.x / ktiles;
  tpose_tile(src, dst, K, N, ldd, 0, tk, tn);
}

__global__ __launch_bounds__(256) void k_wprep(const float* __restrict__ Wq, const float* __restrict__ Wk,
                                               const float* __restrict__ Wv, const float* __restrict__ Wo,
                                               const float* __restrict__ W1, const float* __restrict__ W2,
                                               const float* __restrict__ W3,
                                               ushort* __restrict__ wqkvt, ushort* __restrict__ wot,
                                               ushort* __restrict__ w12t, ushort* __restrict__ w3t) {
  int tile = blockIdx.x;
  const float* src; ushort* dst;
  int K, N, ktiles, ldd, imode = 0, tl;
  if (tile < 2304) {
    int jb = tile / 576; tl = tile % 576;
    ktiles = 24; ldd = 768;
    if (jb == 0)      { src = Wq; dst = wqkvt;                 K = 767; N = 768; }
    else if (jb == 1) { src = Wk; dst = wqkvt + 768 * 768;     K = 767; N = 768; }
    else if (jb == 2) { src = Wv; dst = wqkvt + 2 * 768 * 768; K = 767; N = 768; }
    else              { src = Wo; dst = wot;                   K = 768; N = 767; }
  } else if (tile < 5376) {
    int jb = (tile - 2304) / 1536; tl = (tile - 2304) % 1536;
    ktiles = 24; ldd = 768; K = 767; N = 2048; dst = w12t;
    src = jb ? W2 : W1; imode = jb ? 2 : 1;
  } else {
    tl = tile - 5376; ktiles = 64; ldd = 2048; K = 2048; N = 767; src = W3; dst = w3t;
  }
  int tk = tl % ktiles, tn = tl / ktiles;
  tpose_tile(src, dst, K, N, ldd, imode, tk, tn);
}

// ---------------- im2col with Lorentz time channel, fp16 ----------------
__global__ __launch_bounds__(256) void k_im2col(const float* __restrict__ x, ushort* __restrict__ ap) {
  int r = blockIdx.x;
  int b = r / 196, pi = r - b * 196;
  int py = pi / 14, px = pi - py * 14;
  int t = threadIdx.x;
  int ph = t >> 4, pw = t & 15;
  int iy = py * 16 + ph, ix = px * 16 + pw;
  size_t base = ((size_t)b * 3 * 224 + iy) * 224 + ix;
  float x0 = x[base];
  float x1 = x[base + 224 * 224];
  float x2 = x[base + 2 * 224 * 224];
  float tv = sqrtf(fmaxf(x0 * x0 + x1 * x1 + x2 * x2 + 1.f, 1e-6f));
  size_t o = (size_t)r * 1024 + t * 4;
  ap[o] = h_us(tv); ap[o + 1] = h_us(x0); ap[o + 2] = h_us(x1); ap[o + 3] = h_us(x2);
}

// ---------------- 128-tile fp16 GEMM (2-barrier). MODE 0: f32 C; 3: fp16 H ----------------
template<int MODE>
__global__ __launch_bounds__(256) void k_gemmh(const ushort* __restrict__ A, const ushort* __restrict__ Bt,
                                               float* __restrict__ C, ushort* __restrict__ H,
                                               int N, int K) {
  __shared__ ushort sA[128 * 64];
  __shared__ ushort sB[128 * 64];
  int m0 = blockIdx.x * 128, n0 = blockIdx.y * 128;
  int t = threadIdx.x;
  int w = t >> 6, l = t & 63;
  int wm = (w >> 1) * 64, wn = (w & 1) * 64;
  int lr = l & 15, hi = l >> 4;
  f32x4 acc[4][4] = {};
  for (int k0 = 0; k0 < K; k0 += 64) {
    #pragma unroll
    for (int i = 0; i < 4; ++i) {
      int fl = i * 256 + t;
      int r = fl >> 3, c = fl & 7;
      int cs = c ^ (r & 7);
      gld16(&A[(size_t)(m0 + r) * K + k0 + cs * 8], &sA[fl * 8]);
      gld16(&Bt[(size_t)(n0 + r) * K + k0 + cs * 8], &sB[fl * 8]);
    }
    __syncthreads();
    f16x8 af[4][2], bfr[4][2];
    #pragma unroll
    for (int q = 0; q < 4; ++q) {
      int ra = wm + q * 16 + lr, rb = wn + q * 16 + lr;
      #pragma unroll
      for (int h = 0; h < 2; ++h) {
        af[q][h]  = *(const f16x8*)&sA[ra * 64 + ((h * 4 + hi) ^ (ra & 7)) * 8];
        bfr[q][h] = *(const f16x8*)&sB[rb * 64 + ((h * 4 + hi) ^ (rb & 7)) * 8];
      }
    }
    #pragma unroll
    for (int mi = 0; mi < 4; ++mi)
      #pragma unroll
      for (int ni = 0; ni < 4; ++ni) {
        acc[mi][ni] = __builtin_amdgcn_mfma_f32_16x16x32_f16(af[mi][0], bfr[ni][0], acc[mi][ni], 0, 0, 0);
        acc[mi][ni] = __builtin_amdgcn_mfma_f32_16x16x32_f16(af[mi][1], bfr[ni][1], acc[mi][ni], 0, 0, 0);
      }
    __syncthreads();
  }
  int rr = hi * 4, cc = lr;
  if (MODE == 3) {
    #pragma unroll
    for (int mi = 0; mi < 4; ++mi)
      #pragma unroll
      for (int ni = 0; ni < 4; ++ni)
        #pragma unroll
        for (int j = 0; j < 4; ++j)
          H[(size_t)(m0 + wm + mi * 16 + rr + j) * N + (n0 + wn + ni * 16 + cc)] = h_us(acc[mi][ni][j]);
  } else {
    #pragma unroll
    for (int mi = 0; mi < 4; ++mi)
      #pragma unroll
      for (int ni = 0; ni < 4; ++ni)
        #pragma unroll
        for (int j = 0; j < 4; ++j)
          C[(size_t)(m0 + wm + mi * 16 + rr + j) * N + (n0 + wn + ni * 16 + cc)] = acc[mi][ni][j];
  }
}

// ---------------- 256-tile 8-phase counted-vmcnt fp16 GEMM. MODE 1: silu->H; MODE 2: QKV epilogue ----------------
// LDS swizzle (64B rows): chunk position = logical ^ ((row>>1)&3); applied to BOTH the
// pre-swizzled global source (linear gld16 dest) and the ds_read — involution, 2 lanes/slot.
template<int MODE>
__global__ __launch_bounds__(512, 2) void k_g256(const ushort* __restrict__ A, const ushort* __restrict__ Bt,
                                                 ushort* __restrict__ H, int N, int K,
                                                 ushort* __restrict__ qbuf, ushort* __restrict__ kbuf,
                                                 ushort* __restrict__ vtb,
                                                 float* __restrict__ qtb, float* __restrict__ ktb,
                                                 const float* __restrict__ cosb, const float* __restrict__ sinb) {
  __shared__ ushort sA[2][2][256 * 32];
  __shared__ ushort sB[2][2][256 * 32];
  const int t = threadIdx.x;
  const int w = t >> 6, l = t & 63;
  const int wr = w >> 2, wc = w & 3;
  const int lr = l & 15, hi4 = l >> 4;
  const int m0 = blockIdx.x * 256, n0 = blockIdx.y * 256;

  auto stageA = [&](int kt, int kh, int buf) {
    #pragma unroll
    for (int ii = 0; ii < 2; ++ii) {
      int q = ii * 512 + t;
      int r = q >> 2, ci = q & 3;
      gld16(&A[(size_t)(m0 + r) * K + kt * 64 + kh * 32 + ((ci ^ ((r >> 1) & 3)) * 8)], &sA[buf][kh][q * 8]);
    }
  };
  auto stageB = [&](int kt, int kh, int buf) {
    #pragma unroll
    for (int ii = 0; ii < 2; ++ii) {
      int q = ii * 512 + t;
      int r = q >> 2, ci = q & 3;
      gld16(&Bt[(size_t)(n0 + r) * K + kt * 64 + kh * 32 + ((ci ^ ((r >> 1) & 3)) * 8)], &sB[buf][kh][q * 8]);
    }
  };

  f32x4 acc[8][4] = {};
  auto ldA = [&](int buf, int ks, int G, f16x8* fr) {
    #pragma unroll
    for (int mi = 0; mi < 4; ++mi) {
      int r = wr * 128 + (G * 4 + mi) * 16 + lr;
      fr[mi] = *(const f16x8*)&sA[buf][ks][(r * 4 + (hi4 ^ ((r >> 1) & 3))) * 8];
    }
  };
  auto ldB = [&](int buf, int ks, f16x8* fr) {
    #pragma unroll
    for (int ni = 0; ni < 4; ++ni) {
      int r = wc * 64 + ni * 16 + lr;
      fr[ni] = *(const f16x8*)&sB[buf][ks][(r * 4 + (hi4 ^ ((r >> 1) & 3))) * 8];
    }
  };
  auto mmaG = [&](int G, f16x8* a, f16x8* b) {
    __builtin_amdgcn_s_setprio(1);
    #pragma unroll
    for (int mi = 0; mi < 4; ++mi)
      #pragma unroll
      for (int ni = 0; ni < 4; ++ni)
        acc[G * 4 + mi][ni] = __builtin_amdgcn_mfma_f32_16x16x32_f16(a[mi], b[ni], acc[G * 4 + mi][ni], 0, 0, 0);
    __builtin_amdgcn_s_setprio(0);
  };

  const int NT = K >> 6;
  const int NI = NT >> 1;
  stageA(0, 0, 0); stageB(0, 0, 0); stageA(0, 1, 0); stageB(0, 1, 0);

  for (int i = 0; i < NI; ++i) {
    const int T1 = 2 * i + 1, T2 = 2 * i + 2;
    const bool last = (i == NI - 1);
    f16x8 a0[4], a1[4], b0[4], b1[4];
    // ---- ph1 ----
    asm volatile("s_waitcnt vmcnt(4)" ::: "memory");
    __builtin_amdgcn_sched_barrier(0);
    __builtin_amdgcn_s_barrier();
    ldA(0, 0, 0, a0); ldB(0, 0, b0);
    stageA(T1, 0, 1);
    mmaG(0, a0, b0);
    // ---- ph2 ----
    ldA(0, 0, 1, a1);
    stageB(T1, 0, 1);
    mmaG(1, a1, b0);
    // ---- ph3 ----
    asm volatile("s_waitcnt vmcnt(4)" ::: "memory");
    __builtin_amdgcn_sched_barrier(0);
    __builtin_amdgcn_s_barrier();
    ldA(0, 1, 0, a0); ldB(0, 1, b1);
    stageA(T1, 1, 1);
    mmaG(0, a0, b1);
    // ---- ph4 ----
    ldA(0, 1, 1, a1);
    stageB(T1, 1, 1);
    mmaG(1, a1, b1);
    // ---- ph5 ----
    asm volatile("s_waitcnt vmcnt(4)" ::: "memory");
    __builtin_amdgcn_sched_barrier(0);
    __builtin_amdgcn_s_barrier();
    ldA(1, 0, 0, a0); ldB(1, 0, b0);
    if (!last) stageA(T2, 0, 0);
    mmaG(0, a0, b0);
    // ---- ph6 ----
    ldA(1, 0, 1, a1);
    if (!last) stageB(T2, 0, 0);
    mmaG(1, a1, b0);
    // ---- ph7 ----
    if (last) { asm volatile("s_waitcnt vmcnt(0)" ::: "memory"); }
    else      { asm volatile("s_waitcnt vmcnt(4)" ::: "memory"); }
    __builtin_amdgcn_sched_barrier(0);
    __builtin_amdgcn_s_barrier();
    ldA(1, 1, 0, a0); ldB(1, 1, b1);
    if (!last) stageA(T2, 1, 0);
    mmaG(0, a0, b1);
    // ---- ph8 ----
    ldA(1, 1, 1, a1);
    if (!last) stageB(T2, 1, 0);
    mmaG(1, a1, b1);
  }

  // -------- epilogues --------
  if (MODE == 1) {
    int cc = lr;
    #pragma unroll
    for (int mi = 0; mi < 8; ++mi)
      #pragma unroll
      for (int ni = 0; ni < 4; ++ni) {
        int g = (n0 + wc * 64 + ni * 16) >> 4;
        #pragma unroll
        for (int j = 0; j < 4; ++j) {
          float v = acc[mi][ni][j];
          float p = __shfl_xor(v, 8);
          float u1 = (cc < 8) ? v : p;
          float u2 = (cc < 8) ? p : v;
          float hv = u1 / (1.f + __expf(-u1)) * u2;
          if (cc < 8)
            H[(size_t)(m0 + wr * 128 + mi * 16 + hi4 * 4 + j) * 2048 + g * 8 + cc] = h_us(hv);
        }
      }
  } else if (MODE == 2) {
    int secBase = n0 + wc * 64;
    int sec = secBase / 768;
    int hh = (secBase - sec * 768) >> 6;
    #pragma unroll
    for (int mi = 0; mi < 8; ++mi) {
      float nrm[4];
      #pragma unroll
      for (int j = 0; j < 4; ++j) {
        float ss = 0.f;
        #pragma unroll
        for (int ni = 0; ni < 4; ++ni) ss += acc[mi][ni][j] * acc[mi][ni][j];
        #pragma unroll
        for (int m = 8; m; m >>= 1) ss += __shfl_xor(ss, m, 64);
        nrm[j] = sqrtf(fmaxf(ss + 1.f, 1e-6f));
      }
      #pragma unroll
      for (int j = 0; j < 4; ++j) {
        int m = m0 + wr * 128 + mi * 16 + hi4 * 4 + j;
        if (m < NTOK) {
          int b = m / 197, nn = m - b * 197;
          int bh = b * 12 + hh;
          if (sec == 2) {
            size_t vo = (size_t)bh * 80 * 232;
            if (lr == 0) vtb[vo + nn] = h_us(nrm[j]);
            #pragma unroll
            for (int ni = 0; ni < 4; ++ni) {
              int e = ni * 16 + lr;
              vtb[vo + (size_t)(1 + e) * 232 + nn] = h_us(acc[mi][ni][j]);
            }
          } else {
            float* tb = (sec == 0) ? qtb : ktb;
            ushort* ob = (sec == 0) ? qbuf : kbuf;
            if (lr == 0) tb[(size_t)bh * 208 + nn] = nrm[j];
            size_t rowb = ((size_t)bh * 208 + nn) * 64;
            #pragma unroll
            for (int ni = 0; ni < 4; ++ni) {
              int d = ni * 16 + lr;
              float v = acc[mi][ni][j];
              float p = __shfl_xor(v, 1);
              int j2 = d >> 1;
              float cz = cosb[nn * 32 + j2], sz = sinb[nn * 32 + j2];
              float rv = ((lr & 1) == 0) ? (v * cz - p * sz) : (p * sz + v * cz);
              ob[rowb + d] = h_us(rv);
            }
          }
        }
      }
    }
  }
}

// ---------------- build tokens ----------------
__global__ __launch_bounds__(256) void k_build_tok(const float* __restrict__ feat, const float* __restrict__ cls,
                                                   float* __restrict__ tok) {
  __shared__ float red[8];
  int r = blockIdx.x;
  int b = r / 197, i = r - b * 197;
  int t = threadIdx.x;
  const float* src = (i == 0) ? cls : (feat + (size_t)(b * 196 + i - 1) * 768);
  float v0 = src[t], v1 = src[256 + t], v2 = (t < 255) ? src[512 + t] : 0.f;
  float qs = bsum(v0 * v0 + v1 * v1 + v2 * v2, red);
  float* tp = tok + (size_t)r * 768;
  if (t == 0) tp[0] = sqrtf(fmaxf(qs + 1.f, 1e-6f));
  tp[1 + t] = v0; tp[257 + t] = v1; if (t < 255) tp[513 + t] = v2;
}

// ---------------- lorentz layernorm -> fp16 (pad col 767 = 0) ----------------
__global__ __launch_bounds__(256) void k_ln(const float* __restrict__ tok, const float* __restrict__ g,
                                            const float* __restrict__ bb, ushort* __restrict__ out) {
  __shared__ float red[8];
  int r = blockIdx.x, t = threadIdx.x;
  const float* xp = tok + (size_t)r * 768;
  float v0 = xp[1 + t], v1 = xp[257 + t], v2 = (t < 255) ? xp[513 + t] : 0.f;
  float s = bsum(v0 + v1 + v2, red);
  float q = bsum(v0 * v0 + v1 * v1 + v2 * v2, red);
  float mu = s * (1.f / 767.f);
  float rstd = rsqrtf(fmaxf(q * (1.f / 767.f) - mu * mu, 0.f) + 1e-6f);
  size_t o = (size_t)r * 768;
  out[o + t]       = h_us((v0 - mu) * rstd * g[t]       + bb[t]);
  out[o + 256 + t] = h_us((v1 - mu) * rstd * g[256 + t] + bb[256 + t]);
  if (t < 255)
    out[o + 512 + t] = h_us((v2 - mu) * rstd * g[512 + t] + bb[512 + t]);
  if (t == 255) out[o + 767] = 0;
}

// ---------------- MFMA attention, fp16 single ----------------
__global__ __launch_bounds__(128) void k_attn(const ushort* __restrict__ qbuf,
                                              const float* __restrict__ qtb,
                                              const ushort* __restrict__ kbuf,
                                              const float* __restrict__ ktb,
                                              const ushort* __restrict__ vtb,
                                              ushort* __restrict__ outa) {
  __shared__ ushort sK[208 * 72];
  __shared__ ushort sP[2][16 * 248];
  __shared__ float  sKt[208];
  int half = blockIdx.x, bh = blockIdx.y;
  int b = bh / 12, hd = bh - b * 12;
  int t = threadIdx.x, w = t >> 6, l = t & 63;
  const ushort* kg = kbuf + (size_t)bh * 208 * 64;
  for (int cks = t; cks < 1664; cks += 128) {
    int r = cks >> 3, c8 = (cks & 7) * 8;
    *(int4*)&sK[r * 72 + c8] = *(const int4*)&kg[r * 64 + c8];
  }
  for (int i = t; i < 208; i += 128) sKt[i] = ktb[(size_t)bh * 208 + i];
  __syncthreads();
  const ushort* qg = qbuf + (size_t)bh * 208 * 64;
  const ushort* vg = vtb + (size_t)bh * 80 * 232;
  const float invs = 0.03608439182435161f;
  int rt0 = half ? 7 : 0, rt1 = half ? 13 : 7;
  int lr = l & 15, hi4 = l >> 4;
  ushort* pw = &sP[w][0];
  for (int rt = rt0 + w; rt < rt1; rt += 2) {
    int qrow = (rt * 16 + lr) * 64 + hi4 * 8;
    f16x8 q0 = *(const f16x8*)&qg[qrow];
    f16x8 q1 = *(const f16x8*)&qg[qrow + 32];
    float qt4[4];
    #pragma unroll
    for (int j = 0; j < 4; ++j) qt4[j] = qtb[(size_t)bh * 208 + rt * 16 + hi4 * 4 + j];
    f32x4 acc[13];
    #pragma unroll
    for (int nt = 0; nt < 13; ++nt) {
      int kr = (nt * 16 + lr) * 72 + hi4 * 8;
      f16x8 k0 = *(const f16x8*)&sK[kr];
      f16x8 k1 = *(const f16x8*)&sK[kr + 32];
      acc[nt] = (f32x4){0.f, 0.f, 0.f, 0.f};
      acc[nt] = __builtin_amdgcn_mfma_f32_16x16x32_f16(q0, k0, acc[nt], 0, 0, 0);
      acc[nt] = __builtin_amdgcn_mfma_f32_16x16x32_f16(q1, k1, acc[nt], 0, 0, 0);
    }
    float mx[4] = {-1e30f, -1e30f, -1e30f, -1e30f};
    #pragma unroll
    for (int nt = 0; nt < 13; ++nt) {
      int cI = nt * 16 + lr;
      float ktc = sKt[cI];
      bool valid = (cI < 197);
      #pragma unroll
      for (int j = 0; j < 4; ++j) {
        float s = (2.f + 2.f * (acc[nt][j] - qt4[j] * ktc)) * invs;
        acc[nt][j] = s;
        if (valid) mx[j] = fmaxf(mx[j], s);
      }
    }
    #pragma unroll
    for (int j = 0; j < 4; ++j)
      #pragma unroll
      for (int m = 8; m; m >>= 1) mx[j] = fmaxf(mx[j], __shfl_xor(mx[j], m, 64));
    #pragma unroll
    for (int nt = 0; nt < 14; ++nt) {
      int cI = nt * 16 + lr;
      #pragma unroll
      for (int j = 0; j < 4; ++j) {
        float p = (nt < 13 && cI < 197) ? __expf(acc[nt][j] - mx[j]) : 0.f;
        pw[(hi4 * 4 + j) * 248 + cI] = h_us(p);
      }
    }
    f32x4 accO[5];
    #pragma unroll
    for (int et = 0; et < 5; ++et) accO[et] = (f32x4){0.f, 0.f, 0.f, 0.f};
    #pragma unroll
    for (int ks = 0; ks < 7; ++ks) {
      f16x8 pa = *(const f16x8*)&pw[lr * 248 + ks * 32 + hi4 * 8];
      #pragma unroll
      for (int et = 0; et < 5; ++et) {
        int er = et * 16 + lr;
        f16x8 bv = *(const f16x8*)&vg[(er > 64 ? 64 : er) * 232 + ks * 32 + hi4 * 8];
        accO[et] = __builtin_amdgcn_mfma_f32_16x16x32_f16(pa, bv, accO[et], 0, 0, 0);
      }
    }
    float ssq[4] = {0.f, 0.f, 0.f, 0.f};
    #pragma unroll
    for (int et = 0; et < 4; ++et)
      #pragma unroll
      for (int j = 0; j < 4; ++j) ssq[j] += accO[et][j] * accO[et][j];
    if (lr == 0) {
      #pragma unroll
      for (int j = 0; j < 4; ++j) ssq[j] += accO[4][j] * accO[4][j];
    }
    #pragma unroll
    for (int j = 0; j < 4; ++j)
      #pragma unroll
      for (int m = 8; m; m >>= 1) ssq[j] += __shfl_xor(ssq[j], m, 64);
    float rf4[4];
    #pragma unroll
    for (int j = 0; j < 4; ++j) {
      float o0 = __shfl(accO[0][j], (l & 48));
      rf4[j] = rsqrtf(fmaxf(2.f * o0 * o0 - ssq[j], 1e-6f));
    }
    #pragma unroll
    for (int et = 0; et < 5; ++et) {
      int e = et * 16 + lr;
      if (e == 0 || e >= 65) continue;
      #pragma unroll
      for (int j = 0; j < 4; ++j) {
        int n = rt * 16 + hi4 * 4 + j;
        if (n < 197)
          outa[((size_t)(b * 197 + n)) * 768 + hd * 64 + (e - 1)] = h_us(accO[et][j] * rf4[j]);
      }
    }
  }
}

// ---------------- fused lresnet + lorentz layernorm (s input fp16) ----------------
template<int FIN>
__global__ __launch_bounds__(256) void k_resnet_ln(float* __restrict__ tok, const ushort* __restrict__ s,
                                                   const float* __restrict__ wyp, int l,
                                                   const float* __restrict__ g, const float* __restrict__ bb,
                                                   ushort* __restrict__ out16, float* __restrict__ out32) {
  __shared__ float red[8];
  __shared__ float bc[1];
  int r = blockIdx.x, t = threadIdx.x;
  float w = wyp[l];
  const ushort* sp = s + (size_t)r * 768;
  float* tp = tok + (size_t)r * 768;
  float s0 = us_f(sp[t]), s1 = us_f(sp[256 + t]), s2 = (t < 255) ? us_f(sp[512 + t]) : 0.f;
  float qs = bsum(s0 * s0 + s1 * s1 + s2 * s2, red);
  float at = sqrtf(fmaxf(qs + 1.f, 1e-6f));
  float z0 = tp[1 + t] + w * s0;
  float z1 = tp[257 + t] + w * s1;
  float z2 = (t < 255) ? (tp[513 + t] + w * s2) : 0.f;
  float zs = bsum(z0 * z0 + z1 * z1 + z2 * z2, red);
  if (t == 0) bc[0] = tp[0] + w * at;
  __syncthreads();
  float zt = bc[0];
  float rf = rsqrtf(fmaxf(zt * zt - zs, 1e-6f));
  float n0 = z0 * rf, n1 = z1 * rf, n2 = z2 * rf;
  tp[1 + t] = n0; tp[257 + t] = n1; if (t < 255) tp[513 + t] = n2;
  if (t == 0) tp[0] = zt * rf;
  float sm = bsum(n0 + n1 + n2, red);
  float sq = bsum(n0 * n0 + n1 * n1 + n2 * n2, red);
  float mu = sm * (1.f / 767.f);
  float rstd = rsqrtf(fmaxf(sq * (1.f / 767.f) - mu * mu, 0.f) + 1e-6f);
  float y0 = (n0 - mu) * rstd * g[t] + bb[t];
  float y1 = (n1 - mu) * rstd * g[256 + t] + bb[256 + t];
  float y2 = (t < 255) ? ((n2 - mu) * rstd * g[512 + t] + bb[512 + t]) : 0.f;
  if (FIN) {
    float qq = bsum(y0 * y0 + y1 * y1 + y2 * y2, red);
    float* op = out32 + (size_t)r * 768;
    op[1 + t] = y0; op[257 + t] = y1; if (t < 255) op[513 + t] = y2;
    if (t == 0) op[0] = sqrtf(fmaxf(qq + 1.f, 1e-6f));
  } else {
    size_t o = (size_t)r * 768;
    out16[o + t] = h_us(y0);
    out16[o + 256 + t] = h_us(y1);
    if (t < 255) out16[o + 512 + t] = h_us(y2);
    if (t == 255) out16[o + 767] = 0;
  }
}

extern "C" void kernel_launch(void* const* d_in, const int* in_sizes, int n_in,
                              void* d_out, int out_size, void* d_ws, size_t ws_size,
                              hipStream_t stream) {
  const float* x     = (const float*)d_in[0];
  const float* cls_s = (const float*)d_in[1];
  const float* Wp    = (const float*)d_in[2];
  const float* ln1g  = (const float*)d_in[3];
  const float* ln1b  = (const float*)d_in[4];
  const float* Wq    = (const float*)d_in[5];
  const float* Wk    = (const float*)d_in[6];
  const float* Wv    = (const float*)d_in[7];
  const float* Wo    = (const float*)d_in[8];
  const float* ln2g  = (const float*)d_in[9];
  const float* ln2b  = (const float*)d_in[10];
  const float* W1    = (const float*)d_in[11];
  const float* W2    = (const float*)d_in[12];
  const float* W3    = (const float*)d_in[13];
  const float* wy1   = (const float*)d_in[14];
  const float* wy2   = (const float*)d_in[15];
  const float* lnfg  = (const float*)d_in[16];
  const float* lnfb  = (const float*)d_in[17];

  if (ws_size < B_END) return;

  char* ws = (char*)d_ws;
  float*  cosb   = (float*)(ws + B_COS);
  float*  sinb   = (float*)(ws + B_SIN);
  ushort* wpt    = (ushort*)(ws + B_WPT);
  ushort* apatch = (ushort*)(ws + B_APATCH);
  ushort* wqkvt  = (ushort*)(ws + B_WQKVT);
  ushort* wot    = (ushort*)(ws + B_WOT);
  ushort* w12t   = (ushort*)(ws + B_W12T);
  ushort* w3t    = (ushort*)(ws + B_W3T);
  float*  tok    = (float*)(ws + B_TOK);
  ushort* acta   = (ushort*)(ws + B_ACTA);
  ushort* actb   = (ushort*)(ws + B_ACTB);
  float*  gout   = (float*)(ws + B_GOUT);
  ushort* gouth  = (ushort*)(ws + B_GOUT);
  ushort* qbuf   = (ushort*)(ws + B_QB);
  ushort* kbuf   = (ushort*)(ws + B_KB);
  ushort* vtb    = (ushort*)(ws + B_VT);
  float*  qtb    = (float*)(ws + B_QTB);
  float*  ktb    = (float*)(ws + B_KTB);

  // only V pads must be zero (P=0 x garbage would still contribute via PV MFMA).
  hipMemsetAsync(vtb, 0, VELE * 2, stream);

  k_rope_tab<<<25, 256, 0, stream>>>(cosb, sinb);
  k_tpose<<<32 * 24, 256, 0, stream>>>(Wp, wpt, 1024, 767, 32, 1024);
  k_im2col<<<CONVM, 256, 0, stream>>>(x, apatch);
  k_gemmh<0><<<dim3(49, 6), 256, 0, stream>>>(apatch, wpt, gout, nullptr, 768, 1024);
  k_build_tok<<<NTOK, 256, 0, stream>>>(gout, cls_s, tok);
  k_ln<<<NTOK, 256, 0, stream>>>(tok, ln1g, ln1b, acta);

  for (int l = 0; l < NLAYER; ++l) {
    k_wprep<<<6912, 256, 0, stream>>>(Wq + (size_t)l * 767 * 768, Wk + (size_t)l * 767 * 768,
                                      Wv + (size_t)l * 767 * 768, Wo + (size_t)l * 768 * 767,
                                      W1 + (size_t)l * 767 * 2048, W2 + (size_t)l * 767 * 2048,
                                      W3 + (size_t)l * 2048 * 767, wqkvt, wot, w12t, w3t);

    k_g256<2><<<dim3(25, 9), 512, 0, stream>>>(acta, wqkvt, nullptr, 2304, 768,
                                               qbuf, kbuf, vtb, qtb, ktb, cosb, sinb);
    k_attn<<<dim3(2, 384), 128, 0, stream>>>(qbuf, qtb, kbuf, ktb, vtb, acta);
    k_gemmh<3><<<dim3(50, 6), 256, 0, stream>>>(acta, wot, nullptr, gouth, 768, 768);
    k_resnet_ln<0><<<NTOK, 256, 0, stream>>>(tok, gouth, wy1, l,
                                             ln2g + (size_t)l * 767, ln2b + (size_t)l * 767, acta, nullptr);

    k_g256<1><<<dim3(25, 16), 512, 0, stream>>>(acta, w12t, actb, 4096, 768,
                                                nullptr, nullptr, nullptr, nullptr, nullptr, nullptr, nullptr);
    k_gemmh<3><<<dim3(50, 6), 256, 0, stream>>>(actb, w3t, nullptr, gouth, 768, 2048);
    if (l < NLAYER - 1)
      k_resnet_ln<0><<<NTOK, 256, 0, stream>>>(tok, gouth, wy2, l,
                                               ln1g + (size_t)(l + 1) * 767, ln1b + (size_t)(l + 1) * 767,
                                               acta, nullptr);
    else
      k_resnet_ln<1><<<NTOK, 256, 0, stream>>>(tok, gouth, wy2, l, lnfg, lnfb, nullptr, (float*)d_out);
  }
}

// Round 10
// 3156.314 us; speedup vs baseline: 7.4058x; 1.0374x over previous
//
#include <hip/hip_runtime.h>
#include <hip/hip_bf16.h>

typedef __attribute__((ext_vector_type(8))) short short8;
typedef __attribute__((ext_vector_type(4))) float f32x4;
typedef _Float16 f16x8 __attribute__((ext_vector_type(8)));

#define NLAYER 12
#define NTOK   6304
#define MPAD   6400
#define CONVM  6272

#define QELE     ((size_t)384*208*64)
#define VELE     ((size_t)384*80*232)

static constexpr size_t AL(size_t x){ return (x + 511) & ~(size_t)511; }
static constexpr size_t B_COS    = 0;
static constexpr size_t B_SIN    = AL(B_COS    + (size_t)197*32*4);
static constexpr size_t B_WPT    = AL(B_SIN    + (size_t)197*32*4);
static constexpr size_t B_APATCH = AL(B_WPT    + (size_t)768*1024*2);
static constexpr size_t B_WQKVT  = AL(B_APATCH + (size_t)CONVM*1024*2);
static constexpr size_t B_WOT    = AL(B_WQKVT  + (size_t)2304*768*2);
static constexpr size_t B_W12T   = AL(B_WOT    + (size_t)768*768*2);
static constexpr size_t B_W3T    = AL(B_W12T   + (size_t)4096*768*2);
static constexpr size_t B_TOK    = AL(B_W3T    + (size_t)768*2048*2);
static constexpr size_t B_ACTA   = AL(B_TOK    + (size_t)NTOK*768*4);
static constexpr size_t B_ACTB   = AL(B_ACTA   + (size_t)MPAD*768*2);
static constexpr size_t B_GOUT   = AL(B_ACTB   + (size_t)MPAD*2048*2);
static constexpr size_t B_QB     = AL(B_GOUT   + (size_t)MPAD*2304*4);
static constexpr size_t B_KB     = AL(B_QB     + QELE*2);
static constexpr size_t B_VT     = AL(B_KB     + QELE*2);
static constexpr size_t B_QTB    = AL(B_VT     + VELE*2);
static constexpr size_t B_KTB    = AL(B_QTB    + (size_t)384*208*4);
static constexpr size_t B_END    = AL(B_KTB    + (size_t)384*208*4);

typedef __attribute__((address_space(1))) unsigned int gu32;
typedef __attribute__((address_space(3))) unsigned int lu32;
__device__ __forceinline__ void gld16(const void* g, void* l) {
  __builtin_amdgcn_global_load_lds((const gu32*)g, (lu32*)l, 16, 0, 0);
}

// ---------------- helpers ----------------
__device__ __forceinline__ float bsum(float v, float* red) {
  #pragma unroll
  for (int m = 32; m; m >>= 1) v += __shfl_xor(v, m, 64);
  __syncthreads();
  if ((threadIdx.x & 63) == 0) red[threadIdx.x >> 6] = v;
  __syncthreads();
  return red[0] + red[1] + red[2] + red[3];
}

__device__ __forceinline__ ushort h_us(float v) {
  _Float16 h = (_Float16)v;
  return *(ushort*)&h;
}
__device__ __forceinline__ float us_f(ushort u) {
  return (float)*(const _Float16*)&u;
}

// bijective XCD-chunked remap (m204): round-robin dispatch id -> contiguous per-XCD chunk.
// Decompose x-major so blocks co-resident on an XCD share the same A-panel (bx).
__device__ __forceinline__ void xcd_remap(int& bx, int& by) {
  int gx = gridDim.x, gy = gridDim.y;
  int nwg = gx * gy;
  int orig = blockIdx.y * gx + blockIdx.x;
  int q = nwg >> 3, r = nwg & 7;
  int xcd = orig & 7, loc = orig >> 3;
  int wg = (xcd < r ? xcd * (q + 1) : r * (q + 1) + (xcd - r) * q) + loc;
  bx = wg / gy;
  by = wg % gy;
}

// ---------------- RoPE tables ----------------
__global__ void k_rope_tab(float* __restrict__ cosb, float* __restrict__ sinb) {
  int idx = blockIdx.x * 256 + threadIdx.x;
  if (idx >= 197 * 32) return;
  int p = idx >> 5, j = idx & 31;
  float cv, sv;
  if (p == 0) { cv = 1.f; sv = 0.f; }
  else {
    int pp = p - 1;
    int iy = pp / 14, ix = pp - iy * 14;
    int pos = (j < 16) ? iy : ix;
    int f   = (j < 16) ? j  : j - 16;
    float inv = powf(100.f, -(float)f / 16.f);
    float a = (float)pos * inv;
    cv = cosf(a); sv = sinf(a);
  }
  cosb[idx] = cv; sinb[idx] = sv;
}

// ---------------- LDS-tiled transpose f32 [K][N] -> fp16 dst[n][k], zero-pad ----------------
__device__ __forceinline__ void tpose_tile(const float* __restrict__ src, ushort* __restrict__ dst,
                                           int K, int N, int ldd, int imode, int tk, int tn) {
  __shared__ float ts[32][33];
  int t = threadIdx.x;
  int rr = t >> 3, c4 = (t & 7) * 4;
  int k0 = tk * 32, n0 = tn * 32;
  #pragma unroll
  for (int e = 0; e < 4; ++e) {
    int k = k0 + rr, n = n0 + c4 + e;
    ts[rr][c4 + e] = (k < K && n < N) ? src[(size_t)k * N + n] : 0.f;
  }
  __syncthreads();
  int c = n0 + rr;
  int drow = (imode == 0) ? c : (16 * (c >> 3) + (c & 7) + (imode == 2 ? 8 : 0));
  ushort4 o;
  #pragma unroll
  for (int e = 0; e < 4; ++e) {
    _Float16 hv = (_Float16)ts[c4 + e][rr];
    ((ushort*)&o)[e] = *(ushort*)&hv;
  }
  *(ushort4*)&dst[(size_t)drow * ldd + k0 + c4] = o;
}

__global__ __launch_bounds__(256) void k_tpose(const float* __restrict__ src, ushort* __restrict__ dst,
                                               int K, int N, int ktiles, int ldd) {
  int tk = blockIdx.x % ktiles, tn = blockIdx.x / ktiles;
  tpose_tile(src, dst, K, N, ldd, 0, tk, tn);
}

__global__ __launch_bounds__(256) void k_wprep(const float* __restrict__ Wq, const float* __restrict__ Wk,
                                               const float* __restrict__ Wv, const float* __restrict__ Wo,
                                               const float* __restrict__ W1, const float* __restrict__ W2,
                                               const float* __restrict__ W3,
                                               ushort* __restrict__ wqkvt, ushort* __restrict__ wot,
                                               ushort* __restrict__ w12t, ushort* __restrict__ w3t) {
  int tile = blockIdx.x;
  const float* src; ushort* dst;
  int K, N, ktiles, ldd, imode = 0, tl;
  if (tile < 2304) {
    int jb = tile / 576; tl = tile % 576;
    ktiles = 24; ldd = 768;
    if (jb == 0)      { src = Wq; dst = wqkvt;                 K = 767; N = 768; }
    else if (jb == 1) { src = Wk; dst = wqkvt + 768 * 768;     K = 767; N = 768; }
    else if (jb == 2) { src = Wv; dst = wqkvt + 2 * 768 * 768; K = 767; N = 768; }
    else              { src = Wo; dst = wot;                   K = 768; N = 767; }
  } else if (tile < 5376) {
    int jb = (tile - 2304) / 1536; tl = (tile - 2304) % 1536;
    ktiles = 24; ldd = 768; K = 767; N = 2048; dst = w12t;
    src = jb ? W2 : W1; imode = jb ? 2 : 1;
  } else {
    tl = tile - 5376; ktiles = 64; ldd = 2048; K = 2048; N = 767; src = W3; dst = w3t;
  }
  int tk = tl % ktiles, tn = tl / ktiles;
  tpose_tile(src, dst, K, N, ldd, imode, tk, tn);
}

// ---------------- im2col with Lorentz time channel, fp16 ----------------
__global__ __launch_bounds__(256) void k_im2col(const float* __restrict__ x, ushort* __restrict__ ap) {
  int r = blockIdx.x;
  int b = r / 196, pi = r - b * 196;
  int py = pi / 14, px = pi - py * 14;
  int t = threadIdx.x;
  int ph = t >> 4, pw = t & 15;
  int iy = py * 16 + ph, ix = px * 16 + pw;
  size_t base = ((size_t)b * 3 * 224 + iy) * 224 + ix;
  float x0 = x[base];
  float x1 = x[base + 224 * 224];
  float x2 = x[base + 2 * 224 * 224];
  float tv = sqrtf(fmaxf(x0 * x0 + x1 * x1 + x2 * x2 + 1.f, 1e-6f));
  size_t o = (size_t)r * 1024 + t * 4;
  ap[o] = h_us(tv); ap[o + 1] = h_us(x0); ap[o + 2] = h_us(x1); ap[o + 3] = h_us(x2);
}

// ---------------- 128-tile fp16 GEMM (2-barrier). MODE 0: f32 C; 1: fused silu -> H; 3: fp16 H ----------------
template<int MODE>
__global__ __launch_bounds__(256) void k_gemmh(const ushort* __restrict__ A, const ushort* __restrict__ Bt,
                                               float* __restrict__ C, ushort* __restrict__ H,
                                               int N, int K) {
  __shared__ ushort sA[128 * 64];
  __shared__ ushort sB[128 * 64];
  int bx, by;
  xcd_remap(bx, by);
  int m0 = bx * 128, n0 = by * 128;
  int t = threadIdx.x;
  int w = t >> 6, l = t & 63;
  int wm = (w >> 1) * 64, wn = (w & 1) * 64;
  int lr = l & 15, hi = l >> 4;
  f32x4 acc[4][4] = {};
  for (int k0 = 0; k0 < K; k0 += 64) {
    #pragma unroll
    for (int i = 0; i < 4; ++i) {
      int fl = i * 256 + t;
      int r = fl >> 3, c = fl & 7;
      int cs = c ^ (r & 7);
      gld16(&A[(size_t)(m0 + r) * K + k0 + cs * 8], &sA[fl * 8]);
      gld16(&Bt[(size_t)(n0 + r) * K + k0 + cs * 8], &sB[fl * 8]);
    }
    __syncthreads();
    f16x8 af[4][2], bfr[4][2];
    #pragma unroll
    for (int q = 0; q < 4; ++q) {
      int ra = wm + q * 16 + lr, rb = wn + q * 16 + lr;
      #pragma unroll
      for (int h = 0; h < 2; ++h) {
        af[q][h]  = *(const f16x8*)&sA[ra * 64 + ((h * 4 + hi) ^ (ra & 7)) * 8];
        bfr[q][h] = *(const f16x8*)&sB[rb * 64 + ((h * 4 + hi) ^ (rb & 7)) * 8];
      }
    }
    #pragma unroll
    for (int mi = 0; mi < 4; ++mi)
      #pragma unroll
      for (int ni = 0; ni < 4; ++ni) {
        acc[mi][ni] = __builtin_amdgcn_mfma_f32_16x16x32_f16(af[mi][0], bfr[ni][0], acc[mi][ni], 0, 0, 0);
        acc[mi][ni] = __builtin_amdgcn_mfma_f32_16x16x32_f16(af[mi][1], bfr[ni][1], acc[mi][ni], 0, 0, 0);
      }
    __syncthreads();
  }
  int rr = hi * 4, cc = lr;
  if (MODE == 1) {
    #pragma unroll
    for (int mi = 0; mi < 4; ++mi)
      #pragma unroll
      for (int ni = 0; ni < 4; ++ni) {
        int g = (n0 + wn + ni * 16) >> 4;
        #pragma unroll
        for (int j = 0; j < 4; ++j) {
          float v = acc[mi][ni][j];
          float p = __shfl_xor(v, 8);
          float u1 = (cc < 8) ? v : p;
          float u2 = (cc < 8) ? p : v;
          float hv = u1 / (1.f + __expf(-u1)) * u2;
          if (cc < 8)
            H[(size_t)(m0 + wm + mi * 16 + rr + j) * 2048 + g * 8 + cc] = h_us(hv);
        }
      }
  } else if (MODE == 3) {
    #pragma unroll
    for (int mi = 0; mi < 4; ++mi)
      #pragma unroll
      for (int ni = 0; ni < 4; ++ni)
        #pragma unroll
        for (int j = 0; j < 4; ++j)
          H[(size_t)(m0 + wm + mi * 16 + rr + j) * N + (n0 + wn + ni * 16 + cc)] = h_us(acc[mi][ni][j]);
  } else {
    #pragma unroll
    for (int mi = 0; mi < 4; ++mi)
      #pragma unroll
      for (int ni = 0; ni < 4; ++ni)
        #pragma unroll
        for (int j = 0; j < 4; ++j)
          C[(size_t)(m0 + wm + mi * 16 + rr + j) * N + (n0 + wn + ni * 16 + cc)] = acc[mi][ni][j];
  }
}

// ---------------- 256-tile 8-phase counted-vmcnt fp16 GEMM. MODE 2: QKV epilogue ----------------
template<int MODE>
__global__ __launch_bounds__(512, 2) void k_g256(const ushort* __restrict__ A, const ushort* __restrict__ Bt,
                                                 ushort* __restrict__ H, int N, int K,
                                                 ushort* __restrict__ qbuf, ushort* __restrict__ kbuf,
                                                 ushort* __restrict__ vtb,
                                                 float* __restrict__ qtb, float* __restrict__ ktb,
                                                 const float* __restrict__ cosb, const float* __restrict__ sinb) {
  __shared__ ushort sA[2][2][256 * 32];
  __shared__ ushort sB[2][2][256 * 32];
  const int t = threadIdx.x;
  const int w = t >> 6, l = t & 63;
  const int wr = w >> 2, wc = w & 3;
  const int lr = l & 15, hi4 = l >> 4;
  int bx, by;
  xcd_remap(bx, by);
  const int m0 = bx * 256, n0 = by * 256;

  auto stageA = [&](int kt, int kh, int buf) {
    #pragma unroll
    for (int ii = 0; ii < 2; ++ii) {
      int q = ii * 512 + t;
      int r = q >> 2, ci = q & 3;
      gld16(&A[(size_t)(m0 + r) * K + kt * 64 + kh * 32 + ((ci ^ ((r >> 1) & 3)) * 8)], &sA[buf][kh][q * 8]);
    }
  };
  auto stageB = [&](int kt, int kh, int buf) {
    #pragma unroll
    for (int ii = 0; ii < 2; ++ii) {
      int q = ii * 512 + t;
      int r = q >> 2, ci = q & 3;
      gld16(&Bt[(size_t)(n0 + r) * K + kt * 64 + kh * 32 + ((ci ^ ((r >> 1) & 3)) * 8)], &sB[buf][kh][q * 8]);
    }
  };

  f32x4 acc[8][4] = {};
  auto ldA = [&](int buf, int ks, int G, f16x8* fr) {
    #pragma unroll
    for (int mi = 0; mi < 4; ++mi) {
      int r = wr * 128 + (G * 4 + mi) * 16 + lr;
      fr[mi] = *(const f16x8*)&sA[buf][ks][(r * 4 + (hi4 ^ ((r >> 1) & 3))) * 8];
    }
  };
  auto ldB = [&](int buf, int ks, f16x8* fr) {
    #pragma unroll
    for (int ni = 0; ni < 4; ++ni) {
      int r = wc * 64 + ni * 16 + lr;
      fr[ni] = *(const f16x8*)&sB[buf][ks][(r * 4 + (hi4 ^ ((r >> 1) & 3))) * 8];
    }
  };
  auto mmaG = [&](int G, f16x8* a, f16x8* b) {
    __builtin_amdgcn_s_setprio(1);
    #pragma unroll
    for (int mi = 0; mi < 4; ++mi)
      #pragma unroll
      for (int ni = 0; ni < 4; ++ni)
        acc[G * 4 + mi][ni] = __builtin_amdgcn_mfma_f32_16x16x32_f16(a[mi], b[ni], acc[G * 4 + mi][ni], 0, 0, 0);
    __builtin_amdgcn_s_setprio(0);
  };

  const int NT = K >> 6;
  const int NI = NT >> 1;
  stageA(0, 0, 0); stageB(0, 0, 0); stageA(0, 1, 0); stageB(0, 1, 0);

  for (int i = 0; i < NI; ++i) {
    const int T1 = 2 * i + 1, T2 = 2 * i + 2;
    const bool last = (i == NI - 1);
    f16x8 a0[4], a1[4], b0[4], b1[4];
    asm volatile("s_waitcnt vmcnt(4)" ::: "memory");
    __builtin_amdgcn_sched_barrier(0);
    __builtin_amdgcn_s_barrier();
    ldA(0, 0, 0, a0); ldB(0, 0, b0);
    stageA(T1, 0, 1);
    mmaG(0, a0, b0);
    ldA(0, 0, 1, a1);
    stageB(T1, 0, 1);
    mmaG(1, a1, b0);
    asm volatile("s_waitcnt vmcnt(4)" ::: "memory");
    __builtin_amdgcn_sched_barrier(0);
    __builtin_amdgcn_s_barrier();
    ldA(0, 1, 0, a0); ldB(0, 1, b1);
    stageA(T1, 1, 1);
    mmaG(0, a0, b1);
    ldA(0, 1, 1, a1);
    stageB(T1, 1, 1);
    mmaG(1, a1, b1);
    asm volatile("s_waitcnt vmcnt(4)" ::: "memory");
    __builtin_amdgcn_sched_barrier(0);
    __builtin_amdgcn_s_barrier();
    ldA(1, 0, 0, a0); ldB(1, 0, b0);
    if (!last) stageA(T2, 0, 0);
    mmaG(0, a0, b0);
    ldA(1, 0, 1, a1);
    if (!last) stageB(T2, 0, 0);
    mmaG(1, a1, b0);
    if (last) { asm volatile("s_waitcnt vmcnt(0)" ::: "memory"); }
    else      { asm volatile("s_waitcnt vmcnt(4)" ::: "memory"); }
    __builtin_amdgcn_sched_barrier(0);
    __builtin_amdgcn_s_barrier();
    ldA(1, 1, 0, a0); ldB(1, 1, b1);
    if (!last) stageA(T2, 1, 0);
    mmaG(0, a0, b1);
    ldA(1, 1, 1, a1);
    if (!last) stageB(T2, 1, 0);
    mmaG(1, a1, b1);
  }

  if (MODE == 2) {
    int secBase = n0 + wc * 64;
    int sec = secBase / 768;
    int hh = (secBase - sec * 768) >> 6;
    #pragma unroll
    for (int mi = 0; mi < 8; ++mi) {
      float nrm[4];
      #pragma unroll
      for (int j = 0; j < 4; ++j) {
        float ss = 0.f;
        #pragma unroll
        for (int ni = 0; ni < 4; ++ni) ss += acc[mi][ni][j] * acc[mi][ni][j];
        #pragma unroll
        for (int m = 8; m; m >>= 1) ss += __shfl_xor(ss, m, 64);
        nrm[j] = sqrtf(fmaxf(ss + 1.f, 1e-6f));
      }
      #pragma unroll
      for (int j = 0; j < 4; ++j) {
        int m = m0 + wr * 128 + mi * 16 + hi4 * 4 + j;
        if (m < NTOK) {
          int b = m / 197, nn = m - b * 197;
          int bh = b * 12 + hh;
          if (sec == 2) {
            size_t vo = (size_t)bh * 80 * 232;
            if (lr == 0) vtb[vo + nn] = h_us(nrm[j]);
            #pragma unroll
            for (int ni = 0; ni < 4; ++ni) {
              int e = ni * 16 + lr;
              vtb[vo + (size_t)(1 + e) * 232 + nn] = h_us(acc[mi][ni][j]);
            }
          } else {
            float* tb = (sec == 0) ? qtb : ktb;
            ushort* ob = (sec == 0) ? qbuf : kbuf;
            if (lr == 0) tb[(size_t)bh * 208 + nn] = nrm[j];
            size_t rowb = ((size_t)bh * 208 + nn) * 64;
            #pragma unroll
            for (int ni = 0; ni < 4; ++ni) {
              int d = ni * 16 + lr;
              float v = acc[mi][ni][j];
              float p = __shfl_xor(v, 1);
              int j2 = d >> 1;
              float cz = cosb[nn * 32 + j2], sz = sinb[nn * 32 + j2];
              float rv = ((lr & 1) == 0) ? (v * cz - p * sz) : (p * sz + v * cz);
              ob[rowb + d] = h_us(rv);
            }
          }
        }
      }
    }
  }
}

// ---------------- build tokens ----------------
__global__ __launch_bounds__(256) void k_build_tok(const float* __restrict__ feat, const float* __restrict__ cls,
                                                   float* __restrict__ tok) {
  __shared__ float red[8];
  int r = blockIdx.x;
  int b = r / 197, i = r - b * 197;
  int t = threadIdx.x;
  const float* src = (i == 0) ? cls : (feat + (size_t)(b * 196 + i - 1) * 768);
  float v0 = src[t], v1 = src[256 + t], v2 = (t < 255) ? src[512 + t] : 0.f;
  float qs = bsum(v0 * v0 + v1 * v1 + v2 * v2, red);
  float* tp = tok + (size_t)r * 768;
  if (t == 0) tp[0] = sqrtf(fmaxf(qs + 1.f, 1e-6f));
  tp[1 + t] = v0; tp[257 + t] = v1; if (t < 255) tp[513 + t] = v2;
}

// ---------------- lorentz layernorm -> fp16 (pad col 767 = 0) ----------------
__global__ __launch_bounds__(256) void k_ln(const float* __restrict__ tok, const float* __restrict__ g,
                                            const float* __restrict__ bb, ushort* __restrict__ out) {
  __shared__ float red[8];
  int r = blockIdx.x, t = threadIdx.x;
  const float* xp = tok + (size_t)r * 768;
  float v0 = xp[1 + t], v1 = xp[257 + t], v2 = (t < 255) ? xp[513 + t] : 0.f;
  float s = bsum(v0 + v1 + v2, red);
  float q = bsum(v0 * v0 + v1 * v1 + v2 * v2, red);
  float mu = s * (1.f / 767.f);
  float rstd = rsqrtf(fmaxf(q * (1.f / 767.f) - mu * mu, 0.f) + 1e-6f);
  size_t o = (size_t)r * 768;
  out[o + t]       = h_us((v0 - mu) * rstd * g[t]       + bb[t]);
  out[o + 256 + t] = h_us((v1 - mu) * rstd * g[256 + t] + bb[256 + t]);
  if (t < 255)
    out[o + 512 + t] = h_us((v2 - mu) * rstd * g[512 + t] + bb[512 + t]);
  if (t == 255) out[o + 767] = 0;
}

// ---------------- MFMA attention, barrier-free: K/kt/V from L2, per-wave P in LDS ----------------
__global__ __launch_bounds__(128) void k_attn(const ushort* __restrict__ qbuf,
                                              const float* __restrict__ qtb,
                                              const ushort* __restrict__ kbuf,
                                              const float* __restrict__ ktb,
                                              const ushort* __restrict__ vtb,
                                              ushort* __restrict__ outa) {
  __shared__ ushort sP[2][16 * 248];
  int bxt = blockIdx.x, bh = blockIdx.y;
  int b = bh / 12, hd = bh - b * 12;
  int t = threadIdx.x, w = t >> 6, l = t & 63;
  int rt = bxt * 2 + w;
  if (rt >= 13) return;                      // wave-uniform, no barriers in kernel
  int lr = l & 15, hi4 = l >> 4;
  const ushort* qg = qbuf + (size_t)bh * 208 * 64;
  const ushort* kg = kbuf + (size_t)bh * 208 * 64;
  const ushort* vg = vtb + (size_t)bh * 80 * 232;
  const float*  ktp = ktb + (size_t)bh * 208;
  const float invs = 0.03608439182435161f;   // 1/sqrt(768)
  ushort* pw = &sP[w][0];

  int qrow = (rt * 16 + lr) * 64 + hi4 * 8;
  f16x8 q0 = *(const f16x8*)&qg[qrow];
  f16x8 q1 = *(const f16x8*)&qg[qrow + 32];
  float qt4[4];
  #pragma unroll
  for (int j = 0; j < 4; ++j) qt4[j] = qtb[(size_t)bh * 208 + rt * 16 + hi4 * 4 + j];
  f32x4 acc[13];
  #pragma unroll
  for (int nt = 0; nt < 13; ++nt) {
    int kr = (nt * 16 + lr) * 64 + hi4 * 8;
    f16x8 k0 = *(const f16x8*)&kg[kr];
    f16x8 k1 = *(const f16x8*)&kg[kr + 32];
    acc[nt] = (f32x4){0.f, 0.f, 0.f, 0.f};
    acc[nt] = __builtin_amdgcn_mfma_f32_16x16x32_f16(q0, k0, acc[nt], 0, 0, 0);
    acc[nt] = __builtin_amdgcn_mfma_f32_16x16x32_f16(q1, k1, acc[nt], 0, 0, 0);
  }
  float mx[4] = {-1e30f, -1e30f, -1e30f, -1e30f};
  #pragma unroll
  for (int nt = 0; nt < 13; ++nt) {
    int cI = nt * 16 + lr;
    float ktc = ktp[cI];
    bool valid = (cI < 197);
    #pragma unroll
    for (int j = 0; j < 4; ++j) {
      float s = (2.f + 2.f * (acc[nt][j] - qt4[j] * ktc)) * invs;
      acc[nt][j] = s;
      if (valid) mx[j] = fmaxf(mx[j], s);
    }
  }
  #pragma unroll
  for (int j = 0; j < 4; ++j)
    #pragma unroll
    for (int m = 8; m; m >>= 1) mx[j] = fmaxf(mx[j], __shfl_xor(mx[j], m, 64));
  #pragma unroll
  for (int nt = 0; nt < 14; ++nt) {
    int cI = nt * 16 + lr;
    #pragma unroll
    for (int j = 0; j < 4; ++j) {
      float p = (nt < 13 && cI < 197) ? __expf(acc[nt][j] - mx[j]) : 0.f;
      pw[(hi4 * 4 + j) * 248 + cI] = h_us(p);
    }
  }
  f32x4 accO[5];
  #pragma unroll
  for (int et = 0; et < 5; ++et) accO[et] = (f32x4){0.f, 0.f, 0.f, 0.f};
  #pragma unroll
  for (int ks = 0; ks < 7; ++ks) {
    f16x8 pa = *(const f16x8*)&pw[lr * 248 + ks * 32 + hi4 * 8];
    #pragma unroll
    for (int et = 0; et < 5; ++et) {
      int er = et * 16 + lr;
      f16x8 bv = *(const f16x8*)&vg[(er > 64 ? 64 : er) * 232 + ks * 32 + hi4 * 8];
      accO[et] = __builtin_amdgcn_mfma_f32_16x16x32_f16(pa, bv, accO[et], 0, 0, 0);
    }
  }
  float ssq[4] = {0.f, 0.f, 0.f, 0.f};
  #pragma unroll
  for (int et = 0; et < 4; ++et)
    #pragma unroll
    for (int j = 0; j < 4; ++j) ssq[j] += accO[et][j] * accO[et][j];
  if (lr == 0) {
    #pragma unroll
    for (int j = 0; j < 4; ++j) ssq[j] += accO[4][j] * accO[4][j];
  }
  #pragma unroll
  for (int j = 0; j < 4; ++j)
    #pragma unroll
    for (int m = 8; m; m >>= 1) ssq[j] += __shfl_xor(ssq[j], m, 64);
  float rf4[4];
  #pragma unroll
  for (int j = 0; j < 4; ++j) {
    float o0 = __shfl(accO[0][j], (l & 48));
    rf4[j] = rsqrtf(fmaxf(2.f * o0 * o0 - ssq[j], 1e-6f));
  }
  #pragma unroll
  for (int et = 0; et < 5; ++et) {
    int e = et * 16 + lr;
    if (e == 0 || e >= 65) continue;
    #pragma unroll
    for (int j = 0; j < 4; ++j) {
      int n = rt * 16 + hi4 * 4 + j;
      if (n < 197)
        outa[((size_t)(b * 197 + n)) * 768 + hd * 64 + (e - 1)] = h_us(accO[et][j] * rf4[j]);
    }
  }
}

// ---------------- fused lresnet + lorentz layernorm (s input fp16) ----------------
template<int FIN>
__global__ __launch_bounds__(256) void k_resnet_ln(float* __restrict__ tok, const ushort* __restrict__ s,
                                                   const float* __restrict__ wyp, int l,
                                                   const float* __restrict__ g, const float* __restrict__ bb,
                                                   ushort* __restrict__ out16, float* __restrict__ out32) {
  __shared__ float red[8];
  __shared__ float bc[1];
  int r = blockIdx.x, t = threadIdx.x;
  float w = wyp[l];
  const ushort* sp = s + (size_t)r * 768;
  float* tp = tok + (size_t)r * 768;
  float s0 = us_f(sp[t]), s1 = us_f(sp[256 + t]), s2 = (t < 255) ? us_f(sp[512 + t]) : 0.f;
  float qs = bsum(s0 * s0 + s1 * s1 + s2 * s2, red);
  float at = sqrtf(fmaxf(qs + 1.f, 1e-6f));
  float z0 = tp[1 + t] + w * s0;
  float z1 = tp[257 + t] + w * s1;
  float z2 = (t < 255) ? (tp[513 + t] + w * s2) : 0.f;
  float zs = bsum(z0 * z0 + z1 * z1 + z2 * z2, red);
  if (t == 0) bc[0] = tp[0] + w * at;
  __syncthreads();
  float zt = bc[0];
  float rf = rsqrtf(fmaxf(zt * zt - zs, 1e-6f));
  float n0 = z0 * rf, n1 = z1 * rf, n2 = z2 * rf;
  tp[1 + t] = n0; tp[257 + t] = n1; if (t < 255) tp[513 + t] = n2;
  if (t == 0) tp[0] = zt * rf;
  float sm = bsum(n0 + n1 + n2, red);
  float sq = bsum(n0 * n0 + n1 * n1 + n2 * n2, red);
  float mu = sm * (1.f / 767.f);
  float rstd = rsqrtf(fmaxf(sq * (1.f / 767.f) - mu * mu, 0.f) + 1e-6f);
  float y0 = (n0 - mu) * rstd * g[t] + bb[t];
  float y1 = (n1 - mu) * rstd * g[256 + t] + bb[256 + t];
  float y2 = (t < 255) ? ((n2 - mu) * rstd * g[512 + t] + bb[512 + t]) : 0.f;
  if (FIN) {
    float qq = bsum(y0 * y0 + y1 * y1 + y2 * y2, red);
    float* op = out32 + (size_t)r * 768;
    op[1 + t] = y0; op[257 + t] = y1; if (t < 255) op[513 + t] = y2;
    if (t == 0) op[0] = sqrtf(fmaxf(qq + 1.f, 1e-6f));
  } else {
    size_t o = (size_t)r * 768;
    out16[o + t] = h_us(y0);
    out16[o + 256 + t] = h_us(y1);
    if (t < 255) out16[o + 512 + t] = h_us(y2);
    if (t == 255) out16[o + 767] = 0;
  }
}

extern "C" void kernel_launch(void* const* d_in, const int* in_sizes, int n_in,
                              void* d_out, int out_size, void* d_ws, size_t ws_size,
                              hipStream_t stream) {
  const float* x     = (const float*)d_in[0];
  const float* cls_s = (const float*)d_in[1];
  const float* Wp    = (const float*)d_in[2];
  const float* ln1g  = (const float*)d_in[3];
  const float* ln1b  = (const float*)d_in[4];
  const float* Wq    = (const float*)d_in[5];
  const float* Wk    = (const float*)d_in[6];
  const float* Wv    = (const float*)d_in[7];
  const float* Wo    = (const float*)d_in[8];
  const float* ln2g  = (const float*)d_in[9];
  const float* ln2b  = (const float*)d_in[10];
  const float* W1    = (const float*)d_in[11];
  const float* W2    = (const float*)d_in[12];
  const float* W3    = (const float*)d_in[13];
  const float* wy1   = (const float*)d_in[14];
  const float* wy2   = (const float*)d_in[15];
  const float* lnfg  = (const float*)d_in[16];
  const float* lnfb  = (const float*)d_in[17];

  if (ws_size < B_END) return;

  char* ws = (char*)d_ws;
  float*  cosb   = (float*)(ws + B_COS);
  float*  sinb   = (float*)(ws + B_SIN);
  ushort* wpt    = (ushort*)(ws + B_WPT);
  ushort* apatch = (ushort*)(ws + B_APATCH);
  ushort* wqkvt  = (ushort*)(ws + B_WQKVT);
  ushort* wot    = (ushort*)(ws + B_WOT);
  ushort* w12t   = (ushort*)(ws + B_W12T);
  ushort* w3t    = (ushort*)(ws + B_W3T);
  float*  tok    = (float*)(ws + B_TOK);
  ushort* acta   = (ushort*)(ws + B_ACTA);
  ushort* actb   = (ushort*)(ws + B_ACTB);
  float*  gout   = (float*)(ws + B_GOUT);
  ushort* gouth  = (ushort*)(ws + B_GOUT);
  ushort* qbuf   = (ushort*)(ws + B_QB);
  ushort* kbuf   = (ushort*)(ws + B_KB);
  ushort* vtb    = (ushort*)(ws + B_VT);
  float*  qtb    = (float*)(ws + B_QTB);
  float*  ktb    = (float*)(ws + B_KTB);

  // only V pads must be zero (P=0 x garbage would still contribute via PV MFMA).
  hipMemsetAsync(vtb, 0, VELE * 2, stream);

  k_rope_tab<<<25, 256, 0, stream>>>(cosb, sinb);
  k_tpose<<<32 * 24, 256, 0, stream>>>(Wp, wpt, 1024, 767, 32, 1024);
  k_im2col<<<CONVM, 256, 0, stream>>>(x, apatch);
  k_gemmh<0><<<dim3(49, 6), 256, 0, stream>>>(apatch, wpt, gout, nullptr, 768, 1024);
  k_build_tok<<<NTOK, 256, 0, stream>>>(gout, cls_s, tok);
  k_ln<<<NTOK, 256, 0, stream>>>(tok, ln1g, ln1b, acta);

  for (int l = 0; l < NLAYER; ++l) {
    k_wprep<<<6912, 256, 0, stream>>>(Wq + (size_t)l * 767 * 768, Wk + (size_t)l * 767 * 768,
                                      Wv + (size_t)l * 767 * 768, Wo + (size_t)l * 768 * 767,
                                      W1 + (size_t)l * 767 * 2048, W2 + (size_t)l * 767 * 2048,
                                      W3 + (size_t)l * 2048 * 767, wqkvt, wot, w12t, w3t);

    k_g256<2><<<dim3(25, 9), 512, 0, stream>>>(acta, wqkvt, nullptr, 2304, 768,
                                               qbuf, kbuf, vtb, qtb, ktb, cosb, sinb);
    k_attn<<<dim3(7, 384), 128, 0, stream>>>(qbuf, qtb, kbuf, ktb, vtb, acta);
    k_gemmh<3><<<dim3(50, 6), 256, 0, stream>>>(acta, wot, nullptr, gouth, 768, 768);
    k_resnet_ln<0><<<NTOK, 256, 0, stream>>>(tok, gouth, wy1, l,
                                             ln2g + (size_t)l * 767, ln2b + (size_t)l * 767, acta, nullptr);

    k_gemmh<1><<<dim3(50, 32), 256, 0, stream>>>(acta, w12t, nullptr, actb, 4096, 768);
    k_gemmh<3><<<dim3(50, 6), 256, 0, stream>>>(actb, w3t, nullptr, gouth, 768, 2048);
    if (l < NLAYER - 1)
      k_resnet_ln<0><<<NTOK, 256, 0, stream>>>(tok, gouth, wy2, l,
                                               ln1g + (size_t)(l + 1) * 767, ln1b + (size_t)(l + 1) * 767,
                                               acta, nullptr);
    else
      k_resnet_ln<1><<<NTOK, 256, 0, stream>>>(tok, gouth, wy2, l, lnfg, lnfb, nullptr, (float*)d_out);
  }
}